// Round 1
// baseline (1347.191 us; speedup 1.0000x reference)
//
#include <hip/hip_runtime.h>
#include <math.h>

// Problem constants
#define T_    1024
#define H_    2048
#define HK_   8
#define HV_   16
#define DK_   128
#define DV_   128
#define KD_   1024
#define VD_   2048
#define CD_   4096
#define QN_   6144   // 2*KD + 2*VD

// ---------------------------------------------------------------------------
// f32 tiled GEMM: C[M,N] = A[M,K] @ B[K,N]   (all row-major, dims % 128 == 0,
// K % 16 == 0). 256 threads, 128x128 tile, 8x8 per-thread microtile, BK=16.
// ---------------------------------------------------------------------------
__global__ __launch_bounds__(256) void gemm128_f32(
    const float* __restrict__ A, const float* __restrict__ B,
    float* __restrict__ C, int M, int N, int K) {
  __shared__ float As[16][128];   // [k][m]
  __shared__ float Bs[16][128];   // [k][n]
  const int tid  = threadIdx.x;
  const int tm   = tid & 15;      // 0..15 row subtile
  const int tn   = tid >> 4;      // 0..15 col subtile
  const int row0 = blockIdx.x * 128;
  const int col0 = blockIdx.y * 128;
  const int ar = tid >> 1, ac = (tid & 1) * 8;   // A-tile load coords
  const int br = tid >> 4, bc = (tid & 15) * 8;  // B-tile load coords

  float acc[8][8];
#pragma unroll
  for (int i = 0; i < 8; ++i)
#pragma unroll
    for (int j = 0; j < 8; ++j) acc[i][j] = 0.f;

  for (int k0 = 0; k0 < K; k0 += 16) {
    float4 a0 = *(const float4*)&A[(size_t)(row0 + ar) * K + k0 + ac];
    float4 a1 = *(const float4*)&A[(size_t)(row0 + ar) * K + k0 + ac + 4];
    float4 b0 = *(const float4*)&B[(size_t)(k0 + br) * N + col0 + bc];
    float4 b1 = *(const float4*)&B[(size_t)(k0 + br) * N + col0 + bc + 4];
    __syncthreads();  // previous iter's LDS reads done before overwrite
    As[ac + 0][ar] = a0.x; As[ac + 1][ar] = a0.y;
    As[ac + 2][ar] = a0.z; As[ac + 3][ar] = a0.w;
    As[ac + 4][ar] = a1.x; As[ac + 5][ar] = a1.y;
    As[ac + 6][ar] = a1.z; As[ac + 7][ar] = a1.w;
    *(float4*)&Bs[br][bc]     = b0;
    *(float4*)&Bs[br][bc + 4] = b1;
    __syncthreads();
#pragma unroll
    for (int kk = 0; kk < 16; ++kk) {
      float4 x0 = *(const float4*)&As[kk][tm * 8];
      float4 x1 = *(const float4*)&As[kk][tm * 8 + 4];
      float4 y0 = *(const float4*)&Bs[kk][tn * 8];
      float4 y1 = *(const float4*)&Bs[kk][tn * 8 + 4];
      float av[8] = {x0.x, x0.y, x0.z, x0.w, x1.x, x1.y, x1.z, x1.w};
      float bv[8] = {y0.x, y0.y, y0.z, y0.w, y1.x, y1.y, y1.z, y1.w};
#pragma unroll
      for (int i = 0; i < 8; ++i)
#pragma unroll
        for (int j = 0; j < 8; ++j) acc[i][j] = fmaf(av[i], bv[j], acc[i][j]);
    }
  }
#pragma unroll
  for (int i = 0; i < 8; ++i) {
    float4 c0 = {acc[i][0], acc[i][1], acc[i][2], acc[i][3]};
    float4 c1 = {acc[i][4], acc[i][5], acc[i][6], acc[i][7]};
    size_t off = (size_t)(row0 + tm * 8 + i) * N + col0 + tn * 8;
    *(float4*)&C[off]     = c0;
    *(float4*)&C[off + 4] = c1;
  }
}

// ---------------------------------------------------------------------------
// ba = x @ w_ba  ->  beta = sigmoid(b), g = -exp(a_log)*softplus(a+dt_bias)
// one block (128 thr) per row t
// ---------------------------------------------------------------------------
__global__ void ba_gbeta(const float* __restrict__ x,
                         const float* __restrict__ w_ba,
                         const float* __restrict__ a_log,
                         const float* __restrict__ dt_bias,
                         float* __restrict__ g, float* __restrict__ beta) {
  const int t = blockIdx.x;
  const int tid = threadIdx.x;      // 128
  const int c = tid & 31;           // output col 0..31
  const int chunk = tid >> 5;       // 0..3 (512 k each)
  const float* xr = x + (size_t)t * H_;
  float p = 0.f;
  const int kb = chunk * 512;
  for (int k = kb; k < kb + 512; ++k) p = fmaf(xr[k], w_ba[k * 32 + c], p);
  __shared__ float red[4][32];
  red[chunk][c] = p;
  __syncthreads();
  if (tid < 32) {
    float s = red[0][c] + red[1][c] + red[2][c] + red[3][c];
    if (c < 16) {
      beta[t * 16 + c] = 1.f / (1.f + expf(-s));
    } else {
      int h = c - 16;
      float xx = s + dt_bias[h];
      float sp = xx > 20.f ? xx : log1pf(expf(xx));
      g[t * 16 + h] = -expf(a_log[h]) * sp;
    }
  }
}

// ---------------------------------------------------------------------------
// causal depthwise conv1d (K=4) over first CD=4096 cols of qkvz, + SiLU
// ---------------------------------------------------------------------------
__global__ void conv_silu(const float* __restrict__ qkvz,
                          const float* __restrict__ conv_w,
                          const float* __restrict__ conv_b,
                          float* __restrict__ qkvc) {
  const int c = blockIdx.x * 256 + threadIdx.x;  // 0..4095
  const int t = blockIdx.y;
  float acc = conv_b[c];
#pragma unroll
  for (int j = 0; j < 4; ++j) {
    int tt = t - 3 + j;
    if (tt >= 0) acc = fmaf(qkvz[(size_t)tt * QN_ + c], conv_w[c * 4 + j], acc);
  }
  float sg = 1.f / (1.f + expf(-acc));
  qkvc[(size_t)t * CD_ + c] = acc * sg;
}

// ---------------------------------------------------------------------------
// q/k L2 norm per (t, hk); q scaled by DK^-0.5. 128 threads per block.
// ---------------------------------------------------------------------------
__global__ void qk_prep(const float* __restrict__ qkvc,
                        float* __restrict__ qhat, float* __restrict__ khat) {
  const int t = blockIdx.x, hk = blockIdx.y, d = threadIdx.x;
  float qv = qkvc[(size_t)t * CD_ + hk * 128 + d];
  float kv = qkvc[(size_t)t * CD_ + KD_ + hk * 128 + d];
  float sq = qv * qv, sk = kv * kv;
#pragma unroll
  for (int off = 32; off >= 1; off >>= 1) {
    sq += __shfl_xor(sq, off);
    sk += __shfl_xor(sk, off);
  }
  __shared__ float s2[2][2];
  if ((d & 63) == 0) { s2[d >> 6][0] = sq; s2[d >> 6][1] = sk; }
  __syncthreads();
  float ssq = s2[0][0] + s2[1][0];
  float ssk = s2[0][1] + s2[1][1];
  float qn = qv * rsqrtf(ssq + 1e-6f) * 0.08838834764831845f;  // DK^-0.5
  float kn = kv * rsqrtf(ssk + 1e-6f);
  qhat[((size_t)t * HK_ + hk) * 128 + d] = qn;
  khat[((size_t)t * HK_ + hk) * 128 + d] = kn;
}

// ---------------------------------------------------------------------------
// gated delta rule recurrence.
// grid (HV=16, 4 v-blocks), 256 threads: col = vb*32 + tid>>3 (32 v-cols),
// sub = tid&7 owns k in [sub*16, sub*16+16). State S[16] in registers.
// ---------------------------------------------------------------------------
union V16 { float4 v[4]; float f[16]; };

__global__ __launch_bounds__(256) void recurrence(
    const float* __restrict__ qhat, const float* __restrict__ khat,
    const float* __restrict__ qkvc, const float* __restrict__ g,
    const float* __restrict__ beta, float* __restrict__ o) {
  const int hv  = blockIdx.x;
  const int vb  = blockIdx.y;
  const int hk  = hv >> 1;
  const int tid = threadIdx.x;
  const int col = vb * 32 + (tid >> 3);
  const int sub = tid & 7;
  const float* qp = qhat + hk * 128 + sub * 16;   // +t*1024 per step
  const float* kp = khat + hk * 128 + sub * 16;
  const float* vp = qkvc + 2 * KD_ + hv * 128 + col;  // +t*4096 per step

  float S[16];
#pragma unroll
  for (int i = 0; i < 16; ++i) S[i] = 0.f;

  V16 kc, qc;
#pragma unroll
  for (int i = 0; i < 4; ++i) {
    kc.v[i] = *(const float4*)(kp + 4 * i);
    qc.v[i] = *(const float4*)(qp + 4 * i);
  }
  float gt = g[hv], bt = beta[hv], vt = vp[0];

  for (int t = 0; t < T_; ++t) {
    // prefetch next step
    const int tn = (t + 1 < T_) ? t + 1 : t;
    V16 kn, qn;
#pragma unroll
    for (int i = 0; i < 4; ++i) {
      kn.v[i] = *(const float4*)(kp + (size_t)tn * 1024 + 4 * i);
      qn.v[i] = *(const float4*)(qp + (size_t)tn * 1024 + 4 * i);
    }
    float gn = g[tn * 16 + hv];
    float bn = beta[tn * 16 + hv];
    float vn = vp[(size_t)tn * CD_];

    // compute current step
    float eg = expf(gt);
    float pred = 0.f;
#pragma unroll
    for (int i = 0; i < 16; ++i) {
      S[i] *= eg;
      pred = fmaf(kc.f[i], S[i], pred);
    }
    pred += __shfl_xor(pred, 1);
    pred += __shfl_xor(pred, 2);
    pred += __shfl_xor(pred, 4);
    float delta = (vt - pred) * bt;
    float oa = 0.f;
#pragma unroll
    for (int i = 0; i < 16; ++i) {
      S[i] = fmaf(kc.f[i], delta, S[i]);
      oa = fmaf(qc.f[i], S[i], oa);
    }
    oa += __shfl_xor(oa, 1);
    oa += __shfl_xor(oa, 2);
    oa += __shfl_xor(oa, 4);
    if (sub == 0) o[((size_t)t * HV_ + hv) * 128 + col] = oa;

    kc = kn; qc = qn; gt = gn; bt = bn; vt = vn;
  }
}

// ---------------------------------------------------------------------------
// h = o * silu(z); h *= rsqrt(mean(h^2)+eps); h *= norm_w
// ---------------------------------------------------------------------------
__global__ void gated_rmsnorm(const float* __restrict__ o,
                              const float* __restrict__ qkvz,
                              const float* __restrict__ norm_w,
                              float* __restrict__ h) {
  const int t = blockIdx.x, hv = blockIdx.y, d = threadIdx.x;
  float ov = o[((size_t)t * HV_ + hv) * 128 + d];
  float zv = qkvz[(size_t)t * QN_ + 2 * KD_ + VD_ + hv * 128 + d];
  float hc = ov * (zv / (1.f + expf(-zv)));
  float ss = hc * hc;
#pragma unroll
  for (int off = 32; off >= 1; off >>= 1) ss += __shfl_xor(ss, off);
  __shared__ float s2[2];
  if ((d & 63) == 0) s2[d >> 6] = ss;
  __syncthreads();
  float tot = s2[0] + s2[1];
  float r = rsqrtf(tot * (1.f / 128.f) + 1e-6f);
  h[(size_t)t * VD_ + hv * 128 + d] = hc * r * norm_w[d];
}

// ---------------------------------------------------------------------------
extern "C" void kernel_launch(void* const* d_in, const int* in_sizes, int n_in,
                              void* d_out, int out_size, void* d_ws, size_t ws_size,
                              hipStream_t stream) {
  const float* x       = (const float*)d_in[0];
  const float* w_qkvz  = (const float*)d_in[1];
  const float* w_ba    = (const float*)d_in[2];
  const float* conv_w  = (const float*)d_in[3];
  const float* conv_b  = (const float*)d_in[4];
  const float* a_log   = (const float*)d_in[5];
  const float* dt_bias = (const float*)d_in[6];
  const float* norm_w  = (const float*)d_in[7];
  const float* w_o     = (const float*)d_in[8];
  float* out = (float*)d_out;

  float* ws = (float*)d_ws;
  float* qkvz = ws;                       // 1024*6144   = 6291456
  float* qkvc = qkvz + 6291456;           // 1024*4096   = 4194304
  float* qhat = qkvc + 4194304;           // 1024*8*128  = 1048576
  float* khat = qhat + 1048576;           // 1048576
  float* gbuf = khat + 1048576;           // 16384
  float* bbuf = gbuf + 16384;             // 16384
  float* obuf = bbuf + 16384;             // 1024*16*128 = 2097152
  float* hbuf = obuf + 2097152;           // 1024*2048   = 2097152

  // 1) qkvz = x @ w_qkvz
  gemm128_f32<<<dim3(T_ / 128, QN_ / 128), 256, 0, stream>>>(
      x, w_qkvz, qkvz, T_, QN_, H_);
  // 2) beta / g
  ba_gbeta<<<T_, 128, 0, stream>>>(x, w_ba, a_log, dt_bias, gbuf, bbuf);
  // 3) conv + silu on q|k|v
  conv_silu<<<dim3(CD_ / 256, T_), 256, 0, stream>>>(qkvz, conv_w, conv_b, qkvc);
  // 4) q/k l2norm + scale
  qk_prep<<<dim3(T_, HK_), 128, 0, stream>>>(qkvc, qhat, khat);
  // 5) recurrence
  recurrence<<<dim3(HV_, 4), 256, 0, stream>>>(qhat, khat, qkvc, gbuf, bbuf, obuf);
  // 6) gated rmsnorm
  gated_rmsnorm<<<dim3(T_, HV_), 128, 0, stream>>>(obuf, qkvz, norm_w, hbuf);
  // 7) out = h @ w_o
  gemm128_f32<<<dim3(T_ / 128, VD_ / 128), 256, 0, stream>>>(
      hbuf, w_o, out, T_, H_, VD_);
}

// Round 2
// 942.355 us; speedup vs baseline: 1.4296x; 1.4296x over previous
//
#include <hip/hip_runtime.h>
#include <math.h>

// Problem constants
#define T_    1024
#define H_    2048
#define HK_   8
#define HV_   16
#define KD_   1024
#define VD_   2048
#define CD_   4096
#define QN_   6144   // 2*KD + 2*VD
#define NC_   16     // number of chunks
#define C_    64     // chunk length

// ---------------------------------------------------------------------------
// f32 tiled GEMM: C[M,N] = A[M,K] @ B[K,N]
// ---------------------------------------------------------------------------
__global__ __launch_bounds__(256) void gemm128_f32(
    const float* __restrict__ A, const float* __restrict__ B,
    float* __restrict__ C, int M, int N, int K) {
  __shared__ float As[16][128];   // [k][m]
  __shared__ float Bs[16][128];   // [k][n]
  const int tid  = threadIdx.x;
  const int tm   = tid & 15;
  const int tn   = tid >> 4;
  const int row0 = blockIdx.x * 128;
  const int col0 = blockIdx.y * 128;
  const int ar = tid >> 1, ac = (tid & 1) * 8;
  const int br = tid >> 4, bc = (tid & 15) * 8;

  float acc[8][8];
#pragma unroll
  for (int i = 0; i < 8; ++i)
#pragma unroll
    for (int j = 0; j < 8; ++j) acc[i][j] = 0.f;

  for (int k0 = 0; k0 < K; k0 += 16) {
    float4 a0 = *(const float4*)&A[(size_t)(row0 + ar) * K + k0 + ac];
    float4 a1 = *(const float4*)&A[(size_t)(row0 + ar) * K + k0 + ac + 4];
    float4 b0 = *(const float4*)&B[(size_t)(k0 + br) * N + col0 + bc];
    float4 b1 = *(const float4*)&B[(size_t)(k0 + br) * N + col0 + bc + 4];
    __syncthreads();
    As[ac + 0][ar] = a0.x; As[ac + 1][ar] = a0.y;
    As[ac + 2][ar] = a0.z; As[ac + 3][ar] = a0.w;
    As[ac + 4][ar] = a1.x; As[ac + 5][ar] = a1.y;
    As[ac + 6][ar] = a1.z; As[ac + 7][ar] = a1.w;
    *(float4*)&Bs[br][bc]     = b0;
    *(float4*)&Bs[br][bc + 4] = b1;
    __syncthreads();
#pragma unroll
    for (int kk = 0; kk < 16; ++kk) {
      float4 x0 = *(const float4*)&As[kk][tm * 8];
      float4 x1 = *(const float4*)&As[kk][tm * 8 + 4];
      float4 y0 = *(const float4*)&Bs[kk][tn * 8];
      float4 y1 = *(const float4*)&Bs[kk][tn * 8 + 4];
      float av[8] = {x0.x, x0.y, x0.z, x0.w, x1.x, x1.y, x1.z, x1.w};
      float bv[8] = {y0.x, y0.y, y0.z, y0.w, y1.x, y1.y, y1.z, y1.w};
#pragma unroll
      for (int i = 0; i < 8; ++i)
#pragma unroll
        for (int j = 0; j < 8; ++j) acc[i][j] = fmaf(av[i], bv[j], acc[i][j]);
    }
  }
#pragma unroll
  for (int i = 0; i < 8; ++i) {
    float4 c0 = {acc[i][0], acc[i][1], acc[i][2], acc[i][3]};
    float4 c1 = {acc[i][4], acc[i][5], acc[i][6], acc[i][7]};
    size_t off = (size_t)(row0 + tm * 8 + i) * N + col0 + tn * 8;
    *(float4*)&C[off]     = c0;
    *(float4*)&C[off + 4] = c1;
  }
}

// ---------------------------------------------------------------------------
// ba = x @ w_ba -> beta = sigmoid(b), g = -exp(a_log)*softplus(a+dt_bias)
// ---------------------------------------------------------------------------
__global__ void ba_gbeta(const float* __restrict__ x,
                         const float* __restrict__ w_ba,
                         const float* __restrict__ a_log,
                         const float* __restrict__ dt_bias,
                         float* __restrict__ g, float* __restrict__ beta) {
  const int t = blockIdx.x;
  const int tid = threadIdx.x;      // 128
  const int c = tid & 31;
  const int chunk = tid >> 5;
  const float* xr = x + (size_t)t * H_;
  float p = 0.f;
  const int kb = chunk * 512;
  for (int k = kb; k < kb + 512; ++k) p = fmaf(xr[k], w_ba[k * 32 + c], p);
  __shared__ float red[4][32];
  red[chunk][c] = p;
  __syncthreads();
  if (tid < 32) {
    float s = red[0][c] + red[1][c] + red[2][c] + red[3][c];
    if (c < 16) {
      beta[t * 16 + c] = 1.f / (1.f + expf(-s));
    } else {
      int h = c - 16;
      float xx = s + dt_bias[h];
      float sp = xx > 20.f ? xx : log1pf(expf(xx));
      g[t * 16 + h] = -expf(a_log[h]) * sp;
    }
  }
}

// ---------------------------------------------------------------------------
// causal depthwise conv1d (K=4) + SiLU
// ---------------------------------------------------------------------------
__global__ void conv_silu(const float* __restrict__ qkvz,
                          const float* __restrict__ conv_w,
                          const float* __restrict__ conv_b,
                          float* __restrict__ qkvc) {
  const int c = blockIdx.x * 256 + threadIdx.x;
  const int t = blockIdx.y;
  float acc = conv_b[c];
#pragma unroll
  for (int j = 0; j < 4; ++j) {
    int tt = t - 3 + j;
    if (tt >= 0) acc = fmaf(qkvz[(size_t)tt * QN_ + c], conv_w[c * 4 + j], acc);
  }
  float sg = 1.f / (1.f + expf(-acc));
  qkvc[(size_t)t * CD_ + c] = acc * sg;
}

// ---------------------------------------------------------------------------
// k L2 norm per (t, hk) (q handled inside chunk_prep)
// ---------------------------------------------------------------------------
__global__ void k_prep(const float* __restrict__ qkvc,
                       float* __restrict__ khat) {
  const int t = blockIdx.x, hk = blockIdx.y, d = threadIdx.x;
  float kv = qkvc[(size_t)t * CD_ + KD_ + hk * 128 + d];
  float sk = kv * kv;
#pragma unroll
  for (int off = 32; off >= 1; off >>= 1) sk += __shfl_xor(sk, off);
  __shared__ float s2[2];
  if ((d & 63) == 0) s2[d >> 6] = sk;
  __syncthreads();
  float ssk = s2[0] + s2[1];
  khat[((size_t)t * HK_ + hk) * 128 + d] = kv * rsqrtf(ssk + 1e-6f);
}

// ---------------------------------------------------------------------------
// Chunked gated delta rule, phase A (parallel over 16 chunks x 16 heads).
// Computes per chunk-head:
//   cg[i]  = inclusive prefix of g
//   A[i][j]= beta_i e^{cg_i-cg_j} (k_i.k_j), j<i (stored negated, transposed)
//   Mq[j][i]= e^{cg_i-cg_j} rs_i (qraw_i.k_j), j<=i   (rs = l2norm*DK^-0.5)
//   X=[W|U] = (I+A)^{-1} [ diag(beta*e^{cg}) K  |  beta (*) V ]  (fwd subst,
//             each thread owns one of 256 columns in registers)
// Stores: Wt[d][j] (transposed W), U[j][m], Mq[j][i], pQ[d][i]=e^{cg_i}rs_i q_i[d]
// ---------------------------------------------------------------------------
#define SWZ(r) (((r) >> 2) & 7)

__device__ __forceinline__ float4 ldsw4(const float* base, int r, int dblk) {
  return *(const float4*)&base[r * 128 + ((dblk ^ SWZ(r)) << 2)];
}
__device__ __forceinline__ float ldsw1(const float* base, int r, int d) {
  return base[r * 128 + ((((d) >> 2) ^ SWZ(r)) << 2) + ((d) & 3)];
}

__global__ __launch_bounds__(256) void chunk_prep(
    const float* __restrict__ qkvc, const float* __restrict__ khat,
    const float* __restrict__ g, const float* __restrict__ beta,
    float* __restrict__ cgbuf, float* __restrict__ Wtg, float* __restrict__ Ug,
    float* __restrict__ Mqg, float* __restrict__ pQg) {
  const int c = blockIdx.x, hv = blockIdx.y, hk = hv >> 1;
  const int cid = c * 16 + hv;
  const int tid = threadIdx.x;
  __shared__ float Kl[8192], Ql[8192];   // swizzled [64][128]
  __shared__ float AM[8320];             // At[64][65] | Mq[64][65]; later Utr[64][128]
  __shared__ float cgl[64], bl[64], bp[64], rsl[64];
  float* At = AM;
  float* Mq = AM + 4160;

  // stage K (normalized) and Qraw into swizzled LDS
#pragma unroll
  for (int it = 0; it < 8; ++it) {
    int flat = it * 1024 + tid * 4;
    int row = flat >> 7, d = flat & 127;
    int pb = ((d >> 2) ^ SWZ(row)) << 2;
    int gt = c * 64 + row;
    float4 kv = *(const float4*)&khat[((size_t)gt * HK_ + hk) * 128 + d];
    float4 qv = *(const float4*)&qkvc[(size_t)gt * CD_ + hk * 128 + d];
    *(float4*)&Kl[row * 128 + pb] = kv;
    *(float4*)&Ql[row * 128 + pb] = qv;
  }
  // prefix sum of g over the chunk (wave 0)
  if (tid < 64) {
    float s = g[(size_t)(c * 64 + tid) * HV_ + hv];
#pragma unroll
    for (int off = 1; off < 64; off <<= 1) {
      float t = __shfl_up(s, off);
      if (tid >= off) s += t;
    }
    cgl[tid] = s;
    cgbuf[cid * 64 + tid] = s;
    bl[tid] = beta[(size_t)(c * 64 + tid) * HV_ + hv];
  }
  __syncthreads();
  if (tid < 64) {
    float sq = 0.f;
#pragma unroll
    for (int dblk = 0; dblk < 32; ++dblk) {
      float4 q4 = ldsw4(Ql, tid, dblk);
      sq = fmaf(q4.x, q4.x, sq); sq = fmaf(q4.y, q4.y, sq);
      sq = fmaf(q4.z, q4.z, sq); sq = fmaf(q4.w, q4.w, sq);
    }
    rsl[tid] = rsqrtf(sq + 1e-6f) * 0.08838834764831845f;  // * DK^-0.5
    bp[tid] = bl[tid] * expf(cgl[tid]);
  }
  __syncthreads();

  // dot phase: 4x4 tile of (i,j) pairs per thread
  const int i0 = (tid >> 4) * 4, j0 = (tid & 15) * 4;
  float kk[4][4], qk[4][4];
#pragma unroll
  for (int a = 0; a < 4; ++a)
#pragma unroll
    for (int b = 0; b < 4; ++b) { kk[a][b] = 0.f; qk[a][b] = 0.f; }
  for (int dblk = 0; dblk < 32; ++dblk) {
    float4 ka[4], qa[4], kb[4];
#pragma unroll
    for (int a = 0; a < 4; ++a) {
      ka[a] = ldsw4(Kl, i0 + a, dblk);
      qa[a] = ldsw4(Ql, i0 + a, dblk);
    }
#pragma unroll
    for (int b = 0; b < 4; ++b) kb[b] = ldsw4(Kl, j0 + b, dblk);
#pragma unroll
    for (int a = 0; a < 4; ++a)
#pragma unroll
      for (int b = 0; b < 4; ++b) {
        kk[a][b] = fmaf(ka[a].x, kb[b].x, kk[a][b]);
        kk[a][b] = fmaf(ka[a].y, kb[b].y, kk[a][b]);
        kk[a][b] = fmaf(ka[a].z, kb[b].z, kk[a][b]);
        kk[a][b] = fmaf(ka[a].w, kb[b].w, kk[a][b]);
        qk[a][b] = fmaf(qa[a].x, kb[b].x, qk[a][b]);
        qk[a][b] = fmaf(qa[a].y, kb[b].y, qk[a][b]);
        qk[a][b] = fmaf(qa[a].z, kb[b].z, qk[a][b]);
        qk[a][b] = fmaf(qa[a].w, kb[b].w, qk[a][b]);
      }
  }
#pragma unroll
  for (int a = 0; a < 4; ++a)
#pragma unroll
    for (int b = 0; b < 4; ++b) {
      int i = i0 + a, j = j0 + b;
      float e = expf(cgl[i] - cgl[j]);
      At[j * 65 + i] = (j < i) ? (-bl[i] * e * kk[a][b]) : 0.f;
      Mq[j * 65 + i] = (j <= i) ? (rsl[i] * e * qk[a][b]) : 0.f;
    }
  __syncthreads();

  // X init (thread owns column: n<128 -> W col (k-dim), n>=128 -> U col (v-dim))
  float X[64];
  if (tid < 128) {
#pragma unroll
    for (int j = 0; j < 64; ++j) X[j] = bp[j] * ldsw1(Kl, j, tid);
  } else {
    const int m = tid - 128;
#pragma unroll
    for (int j = 0; j < 64; ++j)
      X[j] = bl[j] * qkvc[(size_t)(c * 64 + j) * CD_ + 2 * KD_ + hv * 128 + m];
  }
  // store Mq to global
#pragma unroll
  for (int it = 0; it < 16; ++it) {
    int f = it * 256 + tid;   // f = j*64 + i
    int j = f >> 6, i = f & 63;
    Mqg[(size_t)cid * 4096 + f] = Mq[j * 65 + i];
  }
  // forward substitution (At pre-negated)
#pragma unroll
  for (int j = 0; j < 63; ++j) {
    float xj = X[j];
#pragma unroll
    for (int i = j + 1; i < 64; ++i) X[i] = fmaf(At[j * 65 + i], xj, X[i]);
  }
  __syncthreads();  // done reading At/Mq; AM region reusable

  if (tid < 128) {
    // Wt[d=tid][j] rows, coalesced-per-thread f4 stores
    size_t baseo = ((size_t)cid * 128 + tid) * 64;
#pragma unroll
    for (int j4 = 0; j4 < 16; ++j4) {
      float4 v = {X[j4 * 4], X[j4 * 4 + 1], X[j4 * 4 + 2], X[j4 * 4 + 3]};
      *(float4*)&Wtg[baseo + j4 * 4] = v;
    }
  } else {
    const int m = tid - 128;
    float* Utr = AM;
#pragma unroll
    for (int j = 0; j < 64; ++j) Utr[j * 128 + m] = X[j];
  }
  __syncthreads();
  {
    const float* Utr = AM;
#pragma unroll
    for (int it = 0; it < 8; ++it) {
      int flat = it * 1024 + tid * 4;
      *(float4*)&Ug[(size_t)cid * 8192 + flat] = *(const float4*)&Utr[flat];
    }
    const int i = tid & 63;
    const float ei = expf(cgl[i]) * rsl[i];
#pragma unroll
    for (int it = 0; it < 32; ++it) {
      int d = it * 4 + (tid >> 6);
      pQg[(size_t)cid * 8192 + d * 64 + i] = ei * ldsw1(Ql, i, d);
    }
  }
}

// ---------------------------------------------------------------------------
// Phase B: sequential scan over 16 chunks. Grid (HV=16, VS=4), 512 threads.
// Block owns head hv and v-columns [vs*32, vs*32+32). S[128][32] lives in LDS.
// Per chunk: u = U - W@S ; o = Mq@u + pQ^T.. (o_i = sum_j Mq[j][i] u_j
//            + sum_d pQ[d][i] S[d]) ; S = pC*S + sum_j e^{cgC-cg_j} k_j u_j
// ---------------------------------------------------------------------------
__global__ __launch_bounds__(512) void chunk_scan(
    const float* __restrict__ Wtg, const float* __restrict__ Ug,
    const float* __restrict__ Mqg, const float* __restrict__ pQg,
    const float* __restrict__ khat, const float* __restrict__ cgbuf,
    float* __restrict__ o) {
  const int hv = blockIdx.x, vs = blockIdx.y, hk = hv >> 1;
  const int tid = threadIdx.x;
  __shared__ float S[128 * 32];
  __shared__ float u[64 * 32];
  __shared__ float Wt[128 * 64];
  __shared__ float Mq[64 * 64];
  __shared__ float Kc[64 * 128];
  __shared__ float esc[64];
  __shared__ float pCl;

  for (int it = tid; it < 4096; it += 512) S[it] = 0.f;
  const int mloc = tid & 31;
  const int grp = tid >> 5;   // 0..15

  for (int c = 0; c < NC_; ++c) {
    const int cid = c * 16 + hv;
    __syncthreads();  // prior chunk fully done (incl. S writes) before restage
    // stage W^T, Mq, K rows
#pragma unroll
    for (int it = 0; it < 4; ++it) {
      int f = it * 2048 + tid * 4;
      *(float4*)&Wt[f] = *(const float4*)&Wtg[(size_t)cid * 8192 + f];
      int row = f >> 7, d = f & 127;
      *(float4*)&Kc[f] =
          *(const float4*)&khat[((size_t)(c * 64 + row) * HK_ + hk) * 128 + d];
    }
#pragma unroll
    for (int it = 0; it < 2; ++it) {
      int f = it * 2048 + tid * 4;
      *(float4*)&Mq[f] = *(const float4*)&Mqg[(size_t)cid * 4096 + f];
    }
    if (tid < 64) {
      float cj = cgbuf[cid * 64 + tid];
      float c63 = cgbuf[cid * 64 + 63];
      esc[tid] = expf(c63 - cj);
      if (tid == 0) pCl = expf(c63);
    }
    __syncthreads();

    // ---- u = U - W @ S  (thread: j0=grp*4 rows, col mloc) ----
    {
      const int j0 = grp * 4;
      size_t ub = (size_t)cid * 8192 + vs * 32 + mloc;
      float a0 = Ug[ub + (size_t)(j0 + 0) * 128];
      float a1 = Ug[ub + (size_t)(j0 + 1) * 128];
      float a2 = Ug[ub + (size_t)(j0 + 2) * 128];
      float a3 = Ug[ub + (size_t)(j0 + 3) * 128];
      for (int d = 0; d < 128; ++d) {
        float s = S[d * 32 + mloc];
        float4 w = *(const float4*)&Wt[d * 64 + j0];
        a0 = fmaf(-w.x, s, a0); a1 = fmaf(-w.y, s, a1);
        a2 = fmaf(-w.z, s, a2); a3 = fmaf(-w.w, s, a3);
      }
      u[(j0 + 0) * 32 + mloc] = a0; u[(j0 + 1) * 32 + mloc] = a1;
      u[(j0 + 2) * 32 + mloc] = a2; u[(j0 + 3) * 32 + mloc] = a3;
    }
    __syncthreads();

    // ---- o rows i0..i0+3 (reads S, u; writes global) ----
    {
      const int i0 = grp * 4;
      float o0 = 0.f, o1 = 0.f, o2 = 0.f, o3 = 0.f;
      for (int j = 0; j < 64; ++j) {
        float uu = u[j * 32 + mloc];
        float4 m4 = *(const float4*)&Mq[j * 64 + i0];
        o0 = fmaf(m4.x, uu, o0); o1 = fmaf(m4.y, uu, o1);
        o2 = fmaf(m4.z, uu, o2); o3 = fmaf(m4.w, uu, o3);
      }
      const float* pQc = pQg + (size_t)cid * 8192;
      for (int d = 0; d < 128; ++d) {
        float s = S[d * 32 + mloc];
        float4 p4 = *(const float4*)&pQc[d * 64 + i0];
        o0 = fmaf(p4.x, s, o0); o1 = fmaf(p4.y, s, o1);
        o2 = fmaf(p4.z, s, o2); o3 = fmaf(p4.w, s, o3);
      }
      size_t ob = ((size_t)(c * 64 + i0) * HV_ + hv) * 128 + vs * 32 + mloc;
      o[ob]               = o0;
      o[ob + (size_t)HV_ * 128]     = o1;
      o[ob + (size_t)HV_ * 256]     = o2;
      o[ob + (size_t)HV_ * 384]     = o3;
    }
    // ---- S update: rows d0..d0+7 (read S/u/Kc into regs) ----
    {
      const int d0 = grp * 8;
      const float pC = pCl;
      float sa[8];
#pragma unroll
      for (int dd = 0; dd < 8; ++dd) sa[dd] = pC * S[(d0 + dd) * 32 + mloc];
      for (int j = 0; j < 64; ++j) {
        float t = esc[j] * u[j * 32 + mloc];
        float4 k0 = *(const float4*)&Kc[j * 128 + d0];
        float4 k1 = *(const float4*)&Kc[j * 128 + d0 + 4];
        sa[0] = fmaf(k0.x, t, sa[0]); sa[1] = fmaf(k0.y, t, sa[1]);
        sa[2] = fmaf(k0.z, t, sa[2]); sa[3] = fmaf(k0.w, t, sa[3]);
        sa[4] = fmaf(k1.x, t, sa[4]); sa[5] = fmaf(k1.y, t, sa[5]);
        sa[6] = fmaf(k1.z, t, sa[6]); sa[7] = fmaf(k1.w, t, sa[7]);
      }
      __syncthreads();  // all reads of S complete
#pragma unroll
      for (int dd = 0; dd < 8; ++dd) S[(d0 + dd) * 32 + mloc] = sa[dd];
    }
  }
}

// ---------------------------------------------------------------------------
// h = o * silu(z); h *= rsqrt(mean(h^2)+eps); h *= norm_w
// ---------------------------------------------------------------------------
__global__ void gated_rmsnorm(const float* __restrict__ o,
                              const float* __restrict__ qkvz,
                              const float* __restrict__ norm_w,
                              float* __restrict__ h) {
  const int t = blockIdx.x, hv = blockIdx.y, d = threadIdx.x;
  float ov = o[((size_t)t * HV_ + hv) * 128 + d];
  float zv = qkvz[(size_t)t * QN_ + 2 * KD_ + VD_ + hv * 128 + d];
  float hc = ov * (zv / (1.f + expf(-zv)));
  float ss = hc * hc;
#pragma unroll
  for (int off = 32; off >= 1; off >>= 1) ss += __shfl_xor(ss, off);
  __shared__ float s2[2];
  if ((d & 63) == 0) s2[d >> 6] = ss;
  __syncthreads();
  float tot = s2[0] + s2[1];
  float r = rsqrtf(tot * (1.f / 128.f) + 1e-6f);
  h[(size_t)t * VD_ + hv * 128 + d] = hc * r * norm_w[d];
}

// ---------------------------------------------------------------------------
extern "C" void kernel_launch(void* const* d_in, const int* in_sizes, int n_in,
                              void* d_out, int out_size, void* d_ws, size_t ws_size,
                              hipStream_t stream) {
  const float* x       = (const float*)d_in[0];
  const float* w_qkvz  = (const float*)d_in[1];
  const float* w_ba    = (const float*)d_in[2];
  const float* conv_w  = (const float*)d_in[3];
  const float* conv_b  = (const float*)d_in[4];
  const float* a_log   = (const float*)d_in[5];
  const float* dt_bias = (const float*)d_in[6];
  const float* norm_w  = (const float*)d_in[7];
  const float* w_o     = (const float*)d_in[8];
  float* out = (float*)d_out;

  float* ws = (float*)d_ws;
  float* qkvz  = ws;                        // 6,291,456
  float* qkvc  = qkvz + 6291456;            // 4,194,304
  float* khat  = qkvc + 4194304;            // 1,048,576
  float* gbuf  = khat + 1048576;            // 16,384
  float* bbuf  = gbuf + 16384;              // 16,384
  float* obuf  = bbuf + 16384;              // 2,097,152
  float* cgbuf = obuf + 2097152;            // 16,384
  float* Wtg   = cgbuf + 16384;             // 2,097,152  (aliased by hbuf later)
  float* Ug    = Wtg + 2097152;             // 2,097,152
  float* Mqg   = Ug + 2097152;              // 1,048,576
  float* pQg   = Mqg + 1048576;             // 2,097,152
  float* hbuf  = Wtg;  // reuse: Wtg dead after chunk_scan, hbuf written after

  // 1) qkvz = x @ w_qkvz
  gemm128_f32<<<dim3(T_ / 128, QN_ / 128), 256, 0, stream>>>(
      x, w_qkvz, qkvz, T_, QN_, H_);
  // 2) beta / g
  ba_gbeta<<<T_, 128, 0, stream>>>(x, w_ba, a_log, dt_bias, gbuf, bbuf);
  // 3) conv + silu on q|k|v
  conv_silu<<<dim3(CD_ / 256, T_), 256, 0, stream>>>(qkvz, conv_w, conv_b, qkvc);
  // 4) k l2norm
  k_prep<<<dim3(T_, HK_), 128, 0, stream>>>(qkvc, khat);
  // 5a) chunk-local precompute (parallel)
  chunk_prep<<<dim3(NC_, HV_), 256, 0, stream>>>(
      qkvc, khat, gbuf, bbuf, cgbuf, Wtg, Ug, Mqg, pQg);
  // 5b) cross-chunk scan (16 sequential chunk-steps inside kernel)
  chunk_scan<<<dim3(HV_, 4), 512, 0, stream>>>(
      Wtg, Ug, Mqg, pQg, khat, cgbuf, obuf);
  // 6) gated rmsnorm
  gated_rmsnorm<<<dim3(T_, HV_), 128, 0, stream>>>(obuf, qkvz, norm_w, hbuf);
  // 7) out = h @ w_o
  gemm128_f32<<<dim3(T_ / 128, VD_ / 128), 256, 0, stream>>>(
      hbuf, w_o, out, T_, H_, VD_);
}

// Round 3
// 470.852 us; speedup vs baseline: 2.8612x; 2.0014x over previous
//
#include <hip/hip_runtime.h>
#include <math.h>

typedef unsigned short u16;
using us4  = __attribute__((ext_vector_type(4))) unsigned short;
using us8  = __attribute__((ext_vector_type(8))) unsigned short;
using bf16x8 = __attribute__((ext_vector_type(8))) __bf16;
using f32x4v = __attribute__((ext_vector_type(4))) float;

// Problem constants
#define T_    1024
#define H_    2048
#define HK_   8
#define HV_   16
#define KD_   1024
#define VD_   2048
#define CD_   4096
#define QN_   6144   // 2*KD + 2*VD
#define NC_   16     // number of chunks
#define C_    64     // chunk length

__device__ __forceinline__ u16 f2bf(float f) {
  unsigned u = __float_as_uint(f);
  u += 0x7fffu + ((u >> 16) & 1u);   // RNE
  return (u16)(u >> 16);
}

// ---------------------------------------------------------------------------
// elementwise f32 -> bf16 (8 elems/thread)
// ---------------------------------------------------------------------------
__global__ void cast_bf16(const float* __restrict__ in, u16* __restrict__ out,
                          int n8) {
  int i = blockIdx.x * 256 + threadIdx.x;
  if (i >= n8) return;
  float4 a = ((const float4*)in)[i * 2];
  float4 b = ((const float4*)in)[i * 2 + 1];
  us8 r = {f2bf(a.x), f2bf(a.y), f2bf(a.z), f2bf(a.w),
           f2bf(b.x), f2bf(b.y), f2bf(b.z), f2bf(b.w)};
  *(us8*)&out[(size_t)i * 8] = r;
}

// ---------------------------------------------------------------------------
// f32 [R][C] -> bf16 [C][R] (transpose + cast), 64x64 tiles
// ---------------------------------------------------------------------------
__global__ __launch_bounds__(256) void transpose_bf16(
    const float* __restrict__ in, u16* __restrict__ out, int R, int C) {
  __shared__ float tile[64][65];
  const int r0 = blockIdx.x * 64, c0 = blockIdx.y * 64;
  const int t = threadIdx.x;
  const int tr = t >> 4, tc4 = (t & 15) * 4;
#pragma unroll
  for (int i = 0; i < 4; ++i) {
    float4 v = *(const float4*)&in[(size_t)(r0 + tr + i * 16) * C + c0 + tc4];
    tile[tr + i * 16][tc4 + 0] = v.x;
    tile[tr + i * 16][tc4 + 1] = v.y;
    tile[tr + i * 16][tc4 + 2] = v.z;
    tile[tr + i * 16][tc4 + 3] = v.w;
  }
  __syncthreads();
#pragma unroll
  for (int i = 0; i < 4; ++i) {
    int oc = tr + i * 16;
    us4 w = {f2bf(tile[tc4 + 0][oc]), f2bf(tile[tc4 + 1][oc]),
             f2bf(tile[tc4 + 2][oc]), f2bf(tile[tc4 + 3][oc])};
    *(us4*)&out[(size_t)(c0 + oc) * R + r0 + tc4] = w;
  }
}

// ---------------------------------------------------------------------------
// bf16 MFMA GEMM (m97 structure): C[M,N] = A[M,K] @ Bt[N,K]^T, f32 out.
// 128x128 tile, BK=32, 4 waves (2x2 of 64x64), 16x16x32 MFMA, 4x4 frags/wave,
// global_load_lds width-16 staging into linear LDS.
// ---------------------------------------------------------------------------
__device__ __forceinline__ void gload_lds16(const void* g, void* l) {
  __builtin_amdgcn_global_load_lds(
      (const __attribute__((address_space(1))) void*)g,
      (__attribute__((address_space(3))) void*)l, 16, 0, 0);
}

__global__ __launch_bounds__(256) void gemm_bf16(
    const u16* __restrict__ A, const u16* __restrict__ Bt,
    float* __restrict__ C, int M, int N, int K) {
  __shared__ __align__(16) u16 As[4096];   // [128][32]
  __shared__ __align__(16) u16 Bs[4096];
  const int tid  = threadIdx.x;
  const int wave = tid >> 6, lane = tid & 63;
  const int row0 = blockIdx.x * 128, col0 = blockIdx.y * 128;
  const int wr = wave >> 1, wc = wave & 1;
  const int fr = lane & 15, fq = lane >> 4;

  // staging coords: call covers 64 rows; wave w -> rows w*16+(lane>>2),
  // cols (lane&3)*8 (8 bf16 = 16 B per lane)
  const int srow = wave * 16 + (lane >> 2);
  const int scol = (lane & 3) * 8;
  const u16* gA0 = A  + (size_t)(row0 + srow) * K + scol;
  const u16* gA1 = gA0 + (size_t)64 * K;
  const u16* gB0 = Bt + (size_t)(col0 + srow) * K + scol;
  const u16* gB1 = gB0 + (size_t)64 * K;
  u16* lA0 = &As[wave * 512];
  u16* lA1 = &As[2048 + wave * 512];
  u16* lB0 = &Bs[wave * 512];
  u16* lB1 = &Bs[2048 + wave * 512];

  f32x4v acc[4][4] = {};

  for (int k0 = 0; k0 < K; k0 += 32) {
    __syncthreads();                 // prior iter's LDS reads complete
    gload_lds16(gA0 + k0, lA0);
    gload_lds16(gA1 + k0, lA1);
    gload_lds16(gB0 + k0, lB0);
    gload_lds16(gB1 + k0, lB1);
    asm volatile("s_waitcnt vmcnt(0)" ::: "memory");
    __syncthreads();

    bf16x8 af[4], bf[4];
#pragma unroll
    for (int mi = 0; mi < 4; ++mi)
      af[mi] = *(const bf16x8*)&As[(wr * 64 + mi * 16 + fr) * 32 + fq * 8];
#pragma unroll
    for (int ni = 0; ni < 4; ++ni)
      bf[ni] = *(const bf16x8*)&Bs[(wc * 64 + ni * 16 + fr) * 32 + fq * 8];
#pragma unroll
    for (int mi = 0; mi < 4; ++mi)
#pragma unroll
      for (int ni = 0; ni < 4; ++ni)
        acc[mi][ni] = __builtin_amdgcn_mfma_f32_16x16x32_bf16(
            af[mi], bf[ni], acc[mi][ni], 0, 0, 0);
  }

  // C/D layout: col = lane&15 (fr), row = fq*4 + reg
#pragma unroll
  for (int mi = 0; mi < 4; ++mi)
#pragma unroll
    for (int ni = 0; ni < 4; ++ni) {
      const int r  = row0 + wr * 64 + mi * 16 + fq * 4;
      const int cc = col0 + wc * 64 + ni * 16 + fr;
#pragma unroll
      for (int j = 0; j < 4; ++j)
        C[(size_t)(r + j) * N + cc] = acc[mi][ni][j];
    }
}

// ---------------------------------------------------------------------------
// ba = x @ w_ba -> beta = sigmoid(b), g = -exp(a_log)*softplus(a+dt_bias)
// ---------------------------------------------------------------------------
__global__ void ba_gbeta(const float* __restrict__ x,
                         const float* __restrict__ w_ba,
                         const float* __restrict__ a_log,
                         const float* __restrict__ dt_bias,
                         float* __restrict__ g, float* __restrict__ beta) {
  const int t = blockIdx.x;
  const int tid = threadIdx.x;      // 128
  const int c = tid & 31;
  const int chunk = tid >> 5;
  const float* xr = x + (size_t)t * H_;
  float p = 0.f;
  const int kb = chunk * 512;
  for (int k = kb; k < kb + 512; ++k) p = fmaf(xr[k], w_ba[k * 32 + c], p);
  __shared__ float red[4][32];
  red[chunk][c] = p;
  __syncthreads();
  if (tid < 32) {
    float s = red[0][c] + red[1][c] + red[2][c] + red[3][c];
    if (c < 16) {
      beta[t * 16 + c] = 1.f / (1.f + expf(-s));
    } else {
      int h = c - 16;
      float xx = s + dt_bias[h];
      float sp = xx > 20.f ? xx : log1pf(expf(xx));
      g[t * 16 + h] = -expf(a_log[h]) * sp;
    }
  }
}

// ---------------------------------------------------------------------------
// causal depthwise conv1d (K=4) + SiLU
// ---------------------------------------------------------------------------
__global__ void conv_silu(const float* __restrict__ qkvz,
                          const float* __restrict__ conv_w,
                          const float* __restrict__ conv_b,
                          float* __restrict__ qkvc) {
  const int c = blockIdx.x * 256 + threadIdx.x;
  const int t = blockIdx.y;
  float acc = conv_b[c];
#pragma unroll
  for (int j = 0; j < 4; ++j) {
    int tt = t - 3 + j;
    if (tt >= 0) acc = fmaf(qkvz[(size_t)tt * QN_ + c], conv_w[c * 4 + j], acc);
  }
  float sg = 1.f / (1.f + expf(-acc));
  qkvc[(size_t)t * CD_ + c] = acc * sg;
}

// ---------------------------------------------------------------------------
// k L2 norm per (t, hk)
// ---------------------------------------------------------------------------
__global__ void k_prep(const float* __restrict__ qkvc,
                       float* __restrict__ khat) {
  const int t = blockIdx.x, hk = blockIdx.y, d = threadIdx.x;
  float kv = qkvc[(size_t)t * CD_ + KD_ + hk * 128 + d];
  float sk = kv * kv;
#pragma unroll
  for (int off = 32; off >= 1; off >>= 1) sk += __shfl_xor(sk, off);
  __shared__ float s2[2];
  if ((d & 63) == 0) s2[d >> 6] = sk;
  __syncthreads();
  float ssk = s2[0] + s2[1];
  khat[((size_t)t * HK_ + hk) * 128 + d] = kv * rsqrtf(ssk + 1e-6f);
}

// ---------------------------------------------------------------------------
// Chunked gated delta rule, phase A (parallel over 16 chunks x 16 heads).
// ---------------------------------------------------------------------------
#define SWZ(r) (((r) >> 2) & 7)

__device__ __forceinline__ float4 ldsw4(const float* base, int r, int dblk) {
  return *(const float4*)&base[r * 128 + ((dblk ^ SWZ(r)) << 2)];
}
__device__ __forceinline__ float ldsw1(const float* base, int r, int d) {
  return base[r * 128 + ((((d) >> 2) ^ SWZ(r)) << 2) + ((d) & 3)];
}

__global__ __launch_bounds__(256) void chunk_prep(
    const float* __restrict__ qkvc, const float* __restrict__ khat,
    const float* __restrict__ g, const float* __restrict__ beta,
    float* __restrict__ cgbuf, float* __restrict__ Wtg, float* __restrict__ Ug,
    float* __restrict__ Mqg, float* __restrict__ pQg) {
  const int c = blockIdx.x, hv = blockIdx.y, hk = hv >> 1;
  const int cid = c * 16 + hv;
  const int tid = threadIdx.x;
  __shared__ float Kl[8192], Ql[8192];   // swizzled [64][128]
  __shared__ float AM[8320];             // At[64][65] | Mq[64][65]; later Utr
  __shared__ float cgl[64], bl[64], bp[64], rsl[64];
  float* At = AM;
  float* Mq = AM + 4160;

#pragma unroll
  for (int it = 0; it < 8; ++it) {
    int flat = it * 1024 + tid * 4;
    int row = flat >> 7, d = flat & 127;
    int pb = ((d >> 2) ^ SWZ(row)) << 2;
    int gt = c * 64 + row;
    float4 kv = *(const float4*)&khat[((size_t)gt * HK_ + hk) * 128 + d];
    float4 qv = *(const float4*)&qkvc[(size_t)gt * CD_ + hk * 128 + d];
    *(float4*)&Kl[row * 128 + pb] = kv;
    *(float4*)&Ql[row * 128 + pb] = qv;
  }
  if (tid < 64) {
    float s = g[(size_t)(c * 64 + tid) * HV_ + hv];
#pragma unroll
    for (int off = 1; off < 64; off <<= 1) {
      float t = __shfl_up(s, off);
      if (tid >= off) s += t;
    }
    cgl[tid] = s;
    cgbuf[cid * 64 + tid] = s;
    bl[tid] = beta[(size_t)(c * 64 + tid) * HV_ + hv];
  }
  __syncthreads();
  if (tid < 64) {
    float sq = 0.f;
#pragma unroll
    for (int dblk = 0; dblk < 32; ++dblk) {
      float4 q4 = ldsw4(Ql, tid, dblk);
      sq = fmaf(q4.x, q4.x, sq); sq = fmaf(q4.y, q4.y, sq);
      sq = fmaf(q4.z, q4.z, sq); sq = fmaf(q4.w, q4.w, sq);
    }
    rsl[tid] = rsqrtf(sq + 1e-6f) * 0.08838834764831845f;
    bp[tid] = bl[tid] * expf(cgl[tid]);
  }
  __syncthreads();

  const int i0 = (tid >> 4) * 4, j0 = (tid & 15) * 4;
  float kk[4][4], qk[4][4];
#pragma unroll
  for (int a = 0; a < 4; ++a)
#pragma unroll
    for (int b = 0; b < 4; ++b) { kk[a][b] = 0.f; qk[a][b] = 0.f; }
  for (int dblk = 0; dblk < 32; ++dblk) {
    float4 ka[4], qa[4], kb[4];
#pragma unroll
    for (int a = 0; a < 4; ++a) {
      ka[a] = ldsw4(Kl, i0 + a, dblk);
      qa[a] = ldsw4(Ql, i0 + a, dblk);
    }
#pragma unroll
    for (int b = 0; b < 4; ++b) kb[b] = ldsw4(Kl, j0 + b, dblk);
#pragma unroll
    for (int a = 0; a < 4; ++a)
#pragma unroll
      for (int b = 0; b < 4; ++b) {
        kk[a][b] = fmaf(ka[a].x, kb[b].x, kk[a][b]);
        kk[a][b] = fmaf(ka[a].y, kb[b].y, kk[a][b]);
        kk[a][b] = fmaf(ka[a].z, kb[b].z, kk[a][b]);
        kk[a][b] = fmaf(ka[a].w, kb[b].w, kk[a][b]);
        qk[a][b] = fmaf(qa[a].x, kb[b].x, qk[a][b]);
        qk[a][b] = fmaf(qa[a].y, kb[b].y, qk[a][b]);
        qk[a][b] = fmaf(qa[a].z, kb[b].z, qk[a][b]);
        qk[a][b] = fmaf(qa[a].w, kb[b].w, qk[a][b]);
      }
  }
#pragma unroll
  for (int a = 0; a < 4; ++a)
#pragma unroll
    for (int b = 0; b < 4; ++b) {
      int i = i0 + a, j = j0 + b;
      float e = expf(cgl[i] - cgl[j]);
      At[j * 65 + i] = (j < i) ? (-bl[i] * e * kk[a][b]) : 0.f;
      Mq[j * 65 + i] = (j <= i) ? (rsl[i] * e * qk[a][b]) : 0.f;
    }
  __syncthreads();

  float X[64];
  if (tid < 128) {
#pragma unroll
    for (int j = 0; j < 64; ++j) X[j] = bp[j] * ldsw1(Kl, j, tid);
  } else {
    const int m = tid - 128;
#pragma unroll
    for (int j = 0; j < 64; ++j)
      X[j] = bl[j] * qkvc[(size_t)(c * 64 + j) * CD_ + 2 * KD_ + hv * 128 + m];
  }
#pragma unroll
  for (int it = 0; it < 16; ++it) {
    int f = it * 256 + tid;
    int j = f >> 6, i = f & 63;
    Mqg[(size_t)cid * 4096 + f] = Mq[j * 65 + i];
  }
#pragma unroll
  for (int j = 0; j < 63; ++j) {
    float xj = X[j];
#pragma unroll
    for (int i = j + 1; i < 64; ++i) X[i] = fmaf(At[j * 65 + i], xj, X[i]);
  }
  __syncthreads();

  if (tid < 128) {
    size_t baseo = ((size_t)cid * 128 + tid) * 64;
#pragma unroll
    for (int j4 = 0; j4 < 16; ++j4) {
      float4 v = {X[j4 * 4], X[j4 * 4 + 1], X[j4 * 4 + 2], X[j4 * 4 + 3]};
      *(float4*)&Wtg[baseo + j4 * 4] = v;
    }
  } else {
    const int m = tid - 128;
    float* Utr = AM;
#pragma unroll
    for (int j = 0; j < 64; ++j) Utr[j * 128 + m] = X[j];
  }
  __syncthreads();
  {
    const float* Utr = AM;
#pragma unroll
    for (int it = 0; it < 8; ++it) {
      int flat = it * 1024 + tid * 4;
      *(float4*)&Ug[(size_t)cid * 8192 + flat] = *(const float4*)&Utr[flat];
    }
    const int i = tid & 63;
    const float ei = expf(cgl[i]) * rsl[i];
#pragma unroll
    for (int it = 0; it < 32; ++it) {
      int d = it * 4 + (tid >> 6);
      pQg[(size_t)cid * 8192 + d * 64 + i] = ei * ldsw1(Ql, i, d);
    }
  }
}

// ---------------------------------------------------------------------------
// Phase B: sequential scan over 16 chunks.
// ---------------------------------------------------------------------------
__global__ __launch_bounds__(512) void chunk_scan(
    const float* __restrict__ Wtg, const float* __restrict__ Ug,
    const float* __restrict__ Mqg, const float* __restrict__ pQg,
    const float* __restrict__ khat, const float* __restrict__ cgbuf,
    float* __restrict__ o) {
  const int hv = blockIdx.x, vs = blockIdx.y, hk = hv >> 1;
  const int tid = threadIdx.x;
  __shared__ float S[128 * 32];
  __shared__ float u[64 * 32];
  __shared__ float Wt[128 * 64];
  __shared__ float Mq[64 * 64];
  __shared__ float Kc[64 * 128];
  __shared__ float esc[64];
  __shared__ float pCl;

  for (int it = tid; it < 4096; it += 512) S[it] = 0.f;
  const int mloc = tid & 31;
  const int grp = tid >> 5;

  for (int c = 0; c < NC_; ++c) {
    const int cid = c * 16 + hv;
    __syncthreads();
#pragma unroll
    for (int it = 0; it < 4; ++it) {
      int f = it * 2048 + tid * 4;
      *(float4*)&Wt[f] = *(const float4*)&Wtg[(size_t)cid * 8192 + f];
      int row = f >> 7, d = f & 127;
      *(float4*)&Kc[f] =
          *(const float4*)&khat[((size_t)(c * 64 + row) * HK_ + hk) * 128 + d];
    }
#pragma unroll
    for (int it = 0; it < 2; ++it) {
      int f = it * 2048 + tid * 4;
      *(float4*)&Mq[f] = *(const float4*)&Mqg[(size_t)cid * 4096 + f];
    }
    if (tid < 64) {
      float cj = cgbuf[cid * 64 + tid];
      float c63 = cgbuf[cid * 64 + 63];
      esc[tid] = expf(c63 - cj);
      if (tid == 0) pCl = expf(c63);
    }
    __syncthreads();

    {
      const int j0 = grp * 4;
      size_t ub = (size_t)cid * 8192 + vs * 32 + mloc;
      float a0 = Ug[ub + (size_t)(j0 + 0) * 128];
      float a1 = Ug[ub + (size_t)(j0 + 1) * 128];
      float a2 = Ug[ub + (size_t)(j0 + 2) * 128];
      float a3 = Ug[ub + (size_t)(j0 + 3) * 128];
      for (int d = 0; d < 128; ++d) {
        float s = S[d * 32 + mloc];
        float4 w = *(const float4*)&Wt[d * 64 + j0];
        a0 = fmaf(-w.x, s, a0); a1 = fmaf(-w.y, s, a1);
        a2 = fmaf(-w.z, s, a2); a3 = fmaf(-w.w, s, a3);
      }
      u[(j0 + 0) * 32 + mloc] = a0; u[(j0 + 1) * 32 + mloc] = a1;
      u[(j0 + 2) * 32 + mloc] = a2; u[(j0 + 3) * 32 + mloc] = a3;
    }
    __syncthreads();

    {
      const int i0 = grp * 4;
      float o0 = 0.f, o1 = 0.f, o2 = 0.f, o3 = 0.f;
      for (int j = 0; j < 64; ++j) {
        float uu = u[j * 32 + mloc];
        float4 m4 = *(const float4*)&Mq[j * 64 + i0];
        o0 = fmaf(m4.x, uu, o0); o1 = fmaf(m4.y, uu, o1);
        o2 = fmaf(m4.z, uu, o2); o3 = fmaf(m4.w, uu, o3);
      }
      const float* pQc = pQg + (size_t)cid * 8192;
      for (int d = 0; d < 128; ++d) {
        float s = S[d * 32 + mloc];
        float4 p4 = *(const float4*)&pQc[d * 64 + i0];
        o0 = fmaf(p4.x, s, o0); o1 = fmaf(p4.y, s, o1);
        o2 = fmaf(p4.z, s, o2); o3 = fmaf(p4.w, s, o3);
      }
      size_t ob = ((size_t)(c * 64 + i0) * HV_ + hv) * 128 + vs * 32 + mloc;
      o[ob]                     = o0;
      o[ob + (size_t)HV_ * 128] = o1;
      o[ob + (size_t)HV_ * 256] = o2;
      o[ob + (size_t)HV_ * 384] = o3;
    }
    {
      const int d0 = grp * 8;
      const float pC = pCl;
      float sa[8];
#pragma unroll
      for (int dd = 0; dd < 8; ++dd) sa[dd] = pC * S[(d0 + dd) * 32 + mloc];
      for (int j = 0; j < 64; ++j) {
        float t = esc[j] * u[j * 32 + mloc];
        float4 k0 = *(const float4*)&Kc[j * 128 + d0];
        float4 k1 = *(const float4*)&Kc[j * 128 + d0 + 4];
        sa[0] = fmaf(k0.x, t, sa[0]); sa[1] = fmaf(k0.y, t, sa[1]);
        sa[2] = fmaf(k0.z, t, sa[2]); sa[3] = fmaf(k0.w, t, sa[3]);
        sa[4] = fmaf(k1.x, t, sa[4]); sa[5] = fmaf(k1.y, t, sa[5]);
        sa[6] = fmaf(k1.z, t, sa[6]); sa[7] = fmaf(k1.w, t, sa[7]);
      }
      __syncthreads();
#pragma unroll
      for (int dd = 0; dd < 8; ++dd) S[(d0 + dd) * 32 + mloc] = sa[dd];
    }
  }
}

// ---------------------------------------------------------------------------
// h = o * silu(z); h *= rsqrt(mean(h^2)+eps); h *= norm_w  -> bf16 out
// ---------------------------------------------------------------------------
__global__ void gated_rmsnorm(const float* __restrict__ o,
                              const float* __restrict__ qkvz,
                              const float* __restrict__ norm_w,
                              u16* __restrict__ h) {
  const int t = blockIdx.x, hv = blockIdx.y, d = threadIdx.x;
  float ov = o[((size_t)t * HV_ + hv) * 128 + d];
  float zv = qkvz[(size_t)t * QN_ + 2 * KD_ + VD_ + hv * 128 + d];
  float hc = ov * (zv / (1.f + expf(-zv)));
  float ss = hc * hc;
#pragma unroll
  for (int off = 32; off >= 1; off >>= 1) ss += __shfl_xor(ss, off);
  __shared__ float s2[2];
  if ((d & 63) == 0) s2[d >> 6] = ss;
  __syncthreads();
  float tot = s2[0] + s2[1];
  float r = rsqrtf(tot * (1.f / 128.f) + 1e-6f);
  h[(size_t)t * VD_ + hv * 128 + d] = f2bf(hc * r * norm_w[d]);
}

// ---------------------------------------------------------------------------
extern "C" void kernel_launch(void* const* d_in, const int* in_sizes, int n_in,
                              void* d_out, int out_size, void* d_ws, size_t ws_size,
                              hipStream_t stream) {
  const float* x       = (const float*)d_in[0];
  const float* w_qkvz  = (const float*)d_in[1];
  const float* w_ba    = (const float*)d_in[2];
  const float* conv_w  = (const float*)d_in[3];
  const float* conv_b  = (const float*)d_in[4];
  const float* a_log   = (const float*)d_in[5];
  const float* dt_bias = (const float*)d_in[6];
  const float* norm_w  = (const float*)d_in[7];
  const float* w_o     = (const float*)d_in[8];
  float* out = (float*)d_out;

  float* ws = (float*)d_ws;
  float* qkvz  = ws;                        // 6,291,456
  float* qkvc  = qkvz + 6291456;            // 4,194,304
  float* khat  = qkvc + 4194304;            // 1,048,576
  float* gbuf  = khat + 1048576;            // 16,384
  float* bbuf  = gbuf + 16384;              // 16,384
  float* obuf  = bbuf + 16384;              // 2,097,152
  float* cgbuf = obuf + 2097152;            // 16,384
  float* Wtg   = cgbuf + 16384;             // 2,097,152
  float* Ug    = Wtg + 2097152;             // 2,097,152
  float* Mqg   = Ug + 2097152;              // 1,048,576
  float* pQg   = Mqg + 1048576;             // 2,097,152
  // bf16 aliases into dead regions:
  u16* xb  = (u16*)obuf;   // x bf16 [1024][2048]; dead before chunk_scan writes obuf
  u16* wqt = (u16*)Wtg;    // w_qkvz^T bf16 [6144][2048]; dead before chunk_prep
  u16* wot = (u16*)qkvc;   // w_o^T bf16 [2048][2048]; qkvc dead after chunk_prep
  u16* hb  = (u16*)khat;   // h bf16 [1024][2048]; khat dead after chunk_scan

  // 0) casts for GEMM1
  cast_bf16<<<1024, 256, 0, stream>>>(x, xb, 262144);
  transpose_bf16<<<dim3(32, 96), 256, 0, stream>>>(w_qkvz, wqt, H_, QN_);
  // 1) qkvz = x @ w_qkvz   (bf16 MFMA)
  gemm_bf16<<<dim3(8, 48), 256, 0, stream>>>(xb, wqt, qkvz, T_, QN_, H_);
  // 2) beta / g
  ba_gbeta<<<T_, 128, 0, stream>>>(x, w_ba, a_log, dt_bias, gbuf, bbuf);
  // 3) conv + silu on q|k|v
  conv_silu<<<dim3(CD_ / 256, T_), 256, 0, stream>>>(qkvz, conv_w, conv_b, qkvc);
  // 4) k l2norm
  k_prep<<<dim3(T_, HK_), 128, 0, stream>>>(qkvc, khat);
  // 5a) chunk-local precompute (parallel)
  chunk_prep<<<dim3(NC_, HV_), 256, 0, stream>>>(
      qkvc, khat, gbuf, bbuf, cgbuf, Wtg, Ug, Mqg, pQg);
  // 5b) cross-chunk scan
  chunk_scan<<<dim3(HV_, 4), 512, 0, stream>>>(
      Wtg, Ug, Mqg, pQg, khat, cgbuf, obuf);
  // 6) w_o^T cast (qkvc now dead)
  transpose_bf16<<<dim3(32, 32), 256, 0, stream>>>(w_o, wot, VD_, H_);
  // 7) gated rmsnorm -> bf16 h
  gated_rmsnorm<<<dim3(T_, HV_), 128, 0, stream>>>(obuf, qkvz, norm_w, hb);
  // 8) out = h @ w_o  (bf16 MFMA)
  gemm_bf16<<<dim3(8, 16), 256, 0, stream>>>(hb, wot, out, T_, VD_, H_);
}

// Round 4
// 439.564 us; speedup vs baseline: 3.0648x; 1.0712x over previous
//
#include <hip/hip_runtime.h>
#include <math.h>

typedef unsigned short u16;
using us4  = __attribute__((ext_vector_type(4))) unsigned short;
using us8  = __attribute__((ext_vector_type(8))) unsigned short;
using bf16x8 = __attribute__((ext_vector_type(8))) __bf16;
using f32x4v = __attribute__((ext_vector_type(4))) float;

// Problem constants
#define T_    1024
#define H_    2048
#define HK_   8
#define HV_   16
#define KD_   1024
#define VD_   2048
#define CD_   4096
#define QN_   6144   // 2*KD + 2*VD
#define NC_   16     // number of chunks
#define C_    64     // chunk length

__device__ __forceinline__ u16 f2bf(float f) {
  unsigned u = __float_as_uint(f);
  u += 0x7fffu + ((u >> 16) & 1u);   // RNE
  return (u16)(u >> 16);
}
__device__ __forceinline__ float bf2f(u16 h) {
  return __uint_as_float(((unsigned)h) << 16);
}

// ---------------------------------------------------------------------------
// elementwise f32 -> bf16 (8 elems/thread)
// ---------------------------------------------------------------------------
__global__ void cast_bf16(const float* __restrict__ in, u16* __restrict__ out,
                          int n8) {
  int i = blockIdx.x * 256 + threadIdx.x;
  if (i >= n8) return;
  float4 a = ((const float4*)in)[i * 2];
  float4 b = ((const float4*)in)[i * 2 + 1];
  us8 r = {f2bf(a.x), f2bf(a.y), f2bf(a.z), f2bf(a.w),
           f2bf(b.x), f2bf(b.y), f2bf(b.z), f2bf(b.w)};
  *(us8*)&out[(size_t)i * 8] = r;
}

// ---------------------------------------------------------------------------
// f32 [R][C] -> bf16 [C][R] (transpose + cast), 64x64 tiles
// ---------------------------------------------------------------------------
__global__ __launch_bounds__(256) void transpose_bf16(
    const float* __restrict__ in, u16* __restrict__ out, int R, int C) {
  __shared__ float tile[64][65];
  const int r0 = blockIdx.x * 64, c0 = blockIdx.y * 64;
  const int t = threadIdx.x;
  const int tr = t >> 4, tc4 = (t & 15) * 4;
#pragma unroll
  for (int i = 0; i < 4; ++i) {
    float4 v = *(const float4*)&in[(size_t)(r0 + tr + i * 16) * C + c0 + tc4];
    tile[tr + i * 16][tc4 + 0] = v.x;
    tile[tr + i * 16][tc4 + 1] = v.y;
    tile[tr + i * 16][tc4 + 2] = v.z;
    tile[tr + i * 16][tc4 + 3] = v.w;
  }
  __syncthreads();
#pragma unroll
  for (int i = 0; i < 4; ++i) {
    int oc = tr + i * 16;
    us4 w = {f2bf(tile[tc4 + 0][oc]), f2bf(tile[tc4 + 1][oc]),
             f2bf(tile[tc4 + 2][oc]), f2bf(tile[tc4 + 3][oc])};
    *(us4*)&out[(size_t)(c0 + oc) * R + r0 + tc4] = w;
  }
}

// ---------------------------------------------------------------------------
// bf16 MFMA GEMM: C = A[M,K] @ Bt[N,K]^T, f32 out. Output is routed to Cq
// (cols < zsplit, leading dim ldq) or Cz (cols >= zsplit, leading dim ldz).
// ---------------------------------------------------------------------------
__device__ __forceinline__ void gload_lds16(const void* g, void* l) {
  __builtin_amdgcn_global_load_lds(
      (const __attribute__((address_space(1))) void*)g,
      (__attribute__((address_space(3))) void*)l, 16, 0, 0);
}

__global__ __launch_bounds__(256) void gemm_bf16(
    const u16* __restrict__ A, const u16* __restrict__ Bt,
    float* __restrict__ Cq, int ldq, float* __restrict__ Cz, int ldz,
    int zsplit, int M, int N, int K) {
  __shared__ __align__(16) u16 As[4096];   // [128][32]
  __shared__ __align__(16) u16 Bs[4096];
  const int tid  = threadIdx.x;
  const int wave = tid >> 6, lane = tid & 63;
  const int row0 = blockIdx.x * 128, col0 = blockIdx.y * 128;
  const int wr = wave >> 1, wc = wave & 1;
  const int fr = lane & 15, fq = lane >> 4;

  const int srow = wave * 16 + (lane >> 2);
  const int scol = (lane & 3) * 8;
  const u16* gA0 = A  + (size_t)(row0 + srow) * K + scol;
  const u16* gA1 = gA0 + (size_t)64 * K;
  const u16* gB0 = Bt + (size_t)(col0 + srow) * K + scol;
  const u16* gB1 = gB0 + (size_t)64 * K;
  u16* lA0 = &As[wave * 512];
  u16* lA1 = &As[2048 + wave * 512];
  u16* lB0 = &Bs[wave * 512];
  u16* lB1 = &Bs[2048 + wave * 512];

  f32x4v acc[4][4] = {};

  for (int k0 = 0; k0 < K; k0 += 32) {
    __syncthreads();
    gload_lds16(gA0 + k0, lA0);
    gload_lds16(gA1 + k0, lA1);
    gload_lds16(gB0 + k0, lB0);
    gload_lds16(gB1 + k0, lB1);
    asm volatile("s_waitcnt vmcnt(0)" ::: "memory");
    __syncthreads();

    bf16x8 af[4], bff[4];
#pragma unroll
    for (int mi = 0; mi < 4; ++mi)
      af[mi] = *(const bf16x8*)&As[(wr * 64 + mi * 16 + fr) * 32 + fq * 8];
#pragma unroll
    for (int ni = 0; ni < 4; ++ni)
      bff[ni] = *(const bf16x8*)&Bs[(wc * 64 + ni * 16 + fr) * 32 + fq * 8];
#pragma unroll
    for (int mi = 0; mi < 4; ++mi)
#pragma unroll
      for (int ni = 0; ni < 4; ++ni)
        acc[mi][ni] = __builtin_amdgcn_mfma_f32_16x16x32_bf16(
            af[mi], bff[ni], acc[mi][ni], 0, 0, 0);
  }

  float* Cp; int ldc, cb;
  if (col0 < zsplit) { Cp = Cq; ldc = ldq; cb = col0; }
  else               { Cp = Cz; ldc = ldz; cb = col0 - zsplit; }
#pragma unroll
  for (int mi = 0; mi < 4; ++mi)
#pragma unroll
    for (int ni = 0; ni < 4; ++ni) {
      const int r  = row0 + wr * 64 + mi * 16 + fq * 4;
      const int cc = cb + wc * 64 + ni * 16 + fr;
#pragma unroll
      for (int j = 0; j < 4; ++j)
        Cp[(size_t)(r + j) * ldc + cc] = acc[mi][ni][j];
    }
}

// ---------------------------------------------------------------------------
// ba = x @ w_ba -> beta = sigmoid(b), g = -exp(a_log)*softplus(a+dt_bias)
// ---------------------------------------------------------------------------
__global__ void ba_gbeta(const float* __restrict__ x,
                         const float* __restrict__ w_ba,
                         const float* __restrict__ a_log,
                         const float* __restrict__ dt_bias,
                         float* __restrict__ g, float* __restrict__ beta) {
  const int t = blockIdx.x;
  const int tid = threadIdx.x;      // 128
  const int c = tid & 31;
  const int chunk = tid >> 5;
  const float* xr = x + (size_t)t * H_;
  float p = 0.f;
  const int kb = chunk * 512;
  for (int k = kb; k < kb + 512; ++k) p = fmaf(xr[k], w_ba[k * 32 + c], p);
  __shared__ float red[4][32];
  red[chunk][c] = p;
  __syncthreads();
  if (tid < 32) {
    float s = red[0][c] + red[1][c] + red[2][c] + red[3][c];
    if (c < 16) {
      beta[t * 16 + c] = 1.f / (1.f + expf(-s));
    } else {
      int h = c - 16;
      float xx = s + dt_bias[h];
      float sp = xx > 20.f ? xx : log1pf(expf(xx));
      g[t * 16 + h] = -expf(a_log[h]) * sp;
    }
  }
}

// ---------------------------------------------------------------------------
// causal depthwise conv1d (K=4) + SiLU.  input qkvraw [T][4096]
// ---------------------------------------------------------------------------
__global__ void conv_silu(const float* __restrict__ qkvraw,
                          const float* __restrict__ conv_w,
                          const float* __restrict__ conv_b,
                          float* __restrict__ qkvc) {
  const int c = blockIdx.x * 256 + threadIdx.x;
  const int t = blockIdx.y;
  float acc = conv_b[c];
#pragma unroll
  for (int j = 0; j < 4; ++j) {
    int tt = t - 3 + j;
    if (tt >= 0) acc = fmaf(qkvraw[(size_t)tt * CD_ + c], conv_w[c * 4 + j], acc);
  }
  float sg = 1.f / (1.f + expf(-acc));
  qkvc[(size_t)t * CD_ + c] = acc * sg;
}

// ---------------------------------------------------------------------------
// k L2 norm per (t, hk)
// ---------------------------------------------------------------------------
__global__ void k_prep(const float* __restrict__ qkvc,
                       float* __restrict__ khat) {
  const int t = blockIdx.x, hk = blockIdx.y, d = threadIdx.x;
  float kv = qkvc[(size_t)t * CD_ + KD_ + hk * 128 + d];
  float sk = kv * kv;
#pragma unroll
  for (int off = 32; off >= 1; off >>= 1) sk += __shfl_xor(sk, off);
  __shared__ float s2[2];
  if ((d & 63) == 0) s2[d >> 6] = sk;
  __syncthreads();
  float ssk = s2[0] + s2[1];
  khat[((size_t)t * HK_ + hk) * 128 + d] = kv * rsqrtf(ssk + 1e-6f);
}

// ---------------------------------------------------------------------------
// Chunked gated delta rule, phase A (parallel over 16 chunks x 16 heads).
// ---------------------------------------------------------------------------
#define SWZ(r) (((r) >> 2) & 7)

__device__ __forceinline__ float4 ldsw4(const float* base, int r, int dblk) {
  return *(const float4*)&base[r * 128 + ((dblk ^ SWZ(r)) << 2)];
}
__device__ __forceinline__ float ldsw1(const float* base, int r, int d) {
  return base[r * 128 + ((((d) >> 2) ^ SWZ(r)) << 2) + ((d) & 3)];
}

__global__ __launch_bounds__(256) void chunk_prep(
    const float* __restrict__ qkvc, const float* __restrict__ khat,
    const float* __restrict__ g, const float* __restrict__ beta,
    float* __restrict__ cgbuf, float* __restrict__ Wtg, float* __restrict__ Ug,
    float* __restrict__ Mqg, float* __restrict__ pQg) {
  const int c = blockIdx.x, hv = blockIdx.y, hk = hv >> 1;
  const int cid = c * 16 + hv;
  const int tid = threadIdx.x;
  __shared__ float Kl[8192], Ql[8192];   // swizzled [64][128]
  __shared__ float AM[8320];             // At[64][65] | Mq[64][65]; later Utr
  __shared__ float cgl[64], bl[64], bp[64], rsl[64];
  float* At = AM;
  float* Mq = AM + 4160;

#pragma unroll
  for (int it = 0; it < 8; ++it) {
    int flat = it * 1024 + tid * 4;
    int row = flat >> 7, d = flat & 127;
    int pb = ((d >> 2) ^ SWZ(row)) << 2;
    int gt = c * 64 + row;
    float4 kv = *(const float4*)&khat[((size_t)gt * HK_ + hk) * 128 + d];
    float4 qv = *(const float4*)&qkvc[(size_t)gt * CD_ + hk * 128 + d];
    *(float4*)&Kl[row * 128 + pb] = kv;
    *(float4*)&Ql[row * 128 + pb] = qv;
  }
  if (tid < 64) {
    float s = g[(size_t)(c * 64 + tid) * HV_ + hv];
#pragma unroll
    for (int off = 1; off < 64; off <<= 1) {
      float t = __shfl_up(s, off);
      if (tid >= off) s += t;
    }
    cgl[tid] = s;
    cgbuf[cid * 64 + tid] = s;
    bl[tid] = beta[(size_t)(c * 64 + tid) * HV_ + hv];
  }
  __syncthreads();
  if (tid < 64) {
    float sq = 0.f;
#pragma unroll
    for (int dblk = 0; dblk < 32; ++dblk) {
      float4 q4 = ldsw4(Ql, tid, dblk);
      sq = fmaf(q4.x, q4.x, sq); sq = fmaf(q4.y, q4.y, sq);
      sq = fmaf(q4.z, q4.z, sq); sq = fmaf(q4.w, q4.w, sq);
    }
    rsl[tid] = rsqrtf(sq + 1e-6f) * 0.08838834764831845f;
    bp[tid] = bl[tid] * expf(cgl[tid]);
  }
  __syncthreads();

  const int i0 = (tid >> 4) * 4, j0 = (tid & 15) * 4;
  float kk[4][4], qk[4][4];
#pragma unroll
  for (int a = 0; a < 4; ++a)
#pragma unroll
    for (int b = 0; b < 4; ++b) { kk[a][b] = 0.f; qk[a][b] = 0.f; }
  for (int dblk = 0; dblk < 32; ++dblk) {
    float4 ka[4], qa[4], kb[4];
#pragma unroll
    for (int a = 0; a < 4; ++a) {
      ka[a] = ldsw4(Kl, i0 + a, dblk);
      qa[a] = ldsw4(Ql, i0 + a, dblk);
    }
#pragma unroll
    for (int b = 0; b < 4; ++b) kb[b] = ldsw4(Kl, j0 + b, dblk);
#pragma unroll
    for (int a = 0; a < 4; ++a)
#pragma unroll
      for (int b = 0; b < 4; ++b) {
        kk[a][b] = fmaf(ka[a].x, kb[b].x, kk[a][b]);
        kk[a][b] = fmaf(ka[a].y, kb[b].y, kk[a][b]);
        kk[a][b] = fmaf(ka[a].z, kb[b].z, kk[a][b]);
        kk[a][b] = fmaf(ka[a].w, kb[b].w, kk[a][b]);
        qk[a][b] = fmaf(qa[a].x, kb[b].x, qk[a][b]);
        qk[a][b] = fmaf(qa[a].y, kb[b].y, qk[a][b]);
        qk[a][b] = fmaf(qa[a].z, kb[b].z, qk[a][b]);
        qk[a][b] = fmaf(qa[a].w, kb[b].w, qk[a][b]);
      }
  }
#pragma unroll
  for (int a = 0; a < 4; ++a)
#pragma unroll
    for (int b = 0; b < 4; ++b) {
      int i = i0 + a, j = j0 + b;
      float e = expf(cgl[i] - cgl[j]);
      At[j * 65 + i] = (j < i) ? (-bl[i] * e * kk[a][b]) : 0.f;
      Mq[j * 65 + i] = (j <= i) ? (rsl[i] * e * qk[a][b]) : 0.f;
    }
  __syncthreads();

  float X[64];
  if (tid < 128) {
#pragma unroll
    for (int j = 0; j < 64; ++j) X[j] = bp[j] * ldsw1(Kl, j, tid);
  } else {
    const int m = tid - 128;
#pragma unroll
    for (int j = 0; j < 64; ++j)
      X[j] = bl[j] * qkvc[(size_t)(c * 64 + j) * CD_ + 2 * KD_ + hv * 128 + m];
  }
#pragma unroll
  for (int it = 0; it < 16; ++it) {
    int f = it * 256 + tid;
    int j = f >> 6, i = f & 63;
    Mqg[(size_t)cid * 4096 + f] = Mq[j * 65 + i];
  }
#pragma unroll
  for (int j = 0; j < 63; ++j) {
    float xj = X[j];
#pragma unroll
    for (int i = j + 1; i < 64; ++i) X[i] = fmaf(At[j * 65 + i], xj, X[i]);
  }
  __syncthreads();

  if (tid < 128) {
    size_t baseo = ((size_t)cid * 128 + tid) * 64;
#pragma unroll
    for (int j4 = 0; j4 < 16; ++j4) {
      float4 v = {X[j4 * 4], X[j4 * 4 + 1], X[j4 * 4 + 2], X[j4 * 4 + 3]};
      *(float4*)&Wtg[baseo + j4 * 4] = v;
    }
  } else {
    const int m = tid - 128;
    float* Utr = AM;
#pragma unroll
    for (int j = 0; j < 64; ++j) Utr[j * 128 + m] = X[j];
  }
  __syncthreads();
  {
    const float* Utr = AM;
#pragma unroll
    for (int it = 0; it < 8; ++it) {
      int flat = it * 1024 + tid * 4;
      *(float4*)&Ug[(size_t)cid * 8192 + flat] = *(const float4*)&Utr[flat];
    }
    const int i = tid & 63;
    const float ei = expf(cgl[i]) * rsl[i];
#pragma unroll
    for (int it = 0; it < 32; ++it) {
      int d = it * 4 + (tid >> 6);
      pQg[(size_t)cid * 8192 + d * 64 + i] = ei * ldsw1(Ql, i, d);
    }
  }
}

// ---------------------------------------------------------------------------
// make_MBG (parallel, 256 blocks): per chunk-head
//   M[d][d'] = pC*delta - sum_j esc_j*khat_j[d]*W[j][d']   -> Mhi/Mlo bf16
//   B[d][m]  = sum_j esc_j*khat_j[d]*U[j][m]               -> f32
//   Gt[d][i] = pQ[d][i] - sum_j W[j][d]*Mq[j][i]           -> f32
// ---------------------------------------------------------------------------
__global__ __launch_bounds__(256) void make_MBG(
    const float* __restrict__ Wtg, const float* __restrict__ pQg,
    const float* __restrict__ Ug, const float* __restrict__ Mqg,
    const float* __restrict__ khat, const float* __restrict__ cgbuf,
    u16* __restrict__ Mhi, u16* __restrict__ Mlo,
    float* __restrict__ Bg, float* __restrict__ Gtg) {
  const int c = blockIdx.x, hv = blockIdx.y, hk = hv >> 1;
  const int cid = c * 16 + hv;
  const int tid = threadIdx.x;
  __shared__ float Wl[64 * 128];   // W[j][d]
  __shared__ float Kel[64 * 128];  // esc_j * khat_j[d]
  __shared__ float Ul[64 * 128];
  __shared__ float Mql[64 * 64];
  const float cg63 = cgbuf[cid * 64 + 63];
  const float pC = expf(cg63);
  // stage W (transpose from Wtg [d][j])
#pragma unroll
  for (int it = 0; it < 8; ++it) {
    int f = it * 1024 + tid * 4;       // f = d*64 + j
    int d = f >> 6, j = f & 63;
    float4 w = *(const float4*)&Wtg[(size_t)cid * 8192 + f];
    Wl[(j + 0) * 128 + d] = w.x;
    Wl[(j + 1) * 128 + d] = w.y;
    Wl[(j + 2) * 128 + d] = w.z;
    Wl[(j + 3) * 128 + d] = w.w;
  }
#pragma unroll
  for (int it = 0; it < 8; ++it) {
    int f = it * 1024 + tid * 4;       // f = j*128 + d
    int j = f >> 7, d = f & 127;
    float esc = expf(cg63 - cgbuf[cid * 64 + j]);
    float4 kv = *(const float4*)&khat[((size_t)(c * 64 + j) * HK_ + hk) * 128 + d];
    float4 uv = *(const float4*)&Ug[(size_t)cid * 8192 + f];
    kv.x *= esc; kv.y *= esc; kv.z *= esc; kv.w *= esc;
    *(float4*)&Kel[f] = kv;
    *(float4*)&Ul[f] = uv;
  }
#pragma unroll
  for (int it = 0; it < 4; ++it) {
    int f = it * 1024 + tid * 4;
    *(float4*)&Mql[f] = *(const float4*)&Mqg[(size_t)cid * 4096 + f];
  }
  __syncthreads();

  // fused M+B: tile rows d0..d0+7, cols n0..n0+7
  const int d0 = (tid & 15) * 8, n0 = (tid >> 4) * 8;
  float ma[8][8] = {}, ba[8][8] = {};
  for (int j = 0; j < 64; ++j) {
    float4 k0 = *(const float4*)&Kel[j * 128 + d0];
    float4 k1 = *(const float4*)&Kel[j * 128 + d0 + 4];
    float4 w0 = *(const float4*)&Wl[j * 128 + n0];
    float4 w1 = *(const float4*)&Wl[j * 128 + n0 + 4];
    float4 u0 = *(const float4*)&Ul[j * 128 + n0];
    float4 u1 = *(const float4*)&Ul[j * 128 + n0 + 4];
    float ke[8] = {k0.x, k0.y, k0.z, k0.w, k1.x, k1.y, k1.z, k1.w};
    float wv[8] = {w0.x, w0.y, w0.z, w0.w, w1.x, w1.y, w1.z, w1.w};
    float uv[8] = {u0.x, u0.y, u0.z, u0.w, u1.x, u1.y, u1.z, u1.w};
#pragma unroll
    for (int a = 0; a < 8; ++a)
#pragma unroll
      for (int b = 0; b < 8; ++b) {
        ma[a][b] = fmaf(ke[a], wv[b], ma[a][b]);
        ba[a][b] = fmaf(ke[a], uv[b], ba[a][b]);
      }
  }
#pragma unroll
  for (int a = 0; a < 8; ++a) {
    const int d = d0 + a;
    us8 hi, lo;
#pragma unroll
    for (int b = 0; b < 8; ++b) {
      float m = ((d == n0 + b) ? pC : 0.f) - ma[a][b];
      u16 h = f2bf(m);
      hi[b] = h;
      lo[b] = f2bf(m - bf2f(h));
    }
    *(us8*)&Mhi[(size_t)cid * 16384 + d * 128 + n0] = hi;
    *(us8*)&Mlo[(size_t)cid * 16384 + d * 128 + n0] = lo;
    float4 b0 = {ba[a][0], ba[a][1], ba[a][2], ba[a][3]};
    float4 b1 = {ba[a][4], ba[a][5], ba[a][6], ba[a][7]};
    *(float4*)&Bg[(size_t)cid * 16384 + d * 128 + n0]     = b0;
    *(float4*)&Bg[(size_t)cid * 16384 + d * 128 + n0 + 4] = b1;
  }

  // G phase: Gt[d][i] tile 4d x 8i
  const int dg = (tid & 31) * 4, ig = (tid >> 5) * 8;
  float ga[4][8] = {};
  for (int j = 0; j < 64; ++j) {
    float4 w4 = *(const float4*)&Wl[j * 128 + dg];
    float4 m0 = *(const float4*)&Mql[j * 64 + ig];
    float4 m1 = *(const float4*)&Mql[j * 64 + ig + 4];
    float wv[4] = {w4.x, w4.y, w4.z, w4.w};
    float mv[8] = {m0.x, m0.y, m0.z, m0.w, m1.x, m1.y, m1.z, m1.w};
#pragma unroll
    for (int a = 0; a < 4; ++a)
#pragma unroll
      for (int b = 0; b < 8; ++b) ga[a][b] = fmaf(wv[a], mv[b], ga[a][b]);
  }
#pragma unroll
  for (int a = 0; a < 4; ++a) {
    const int d = dg + a;
    float4 p0 = *(const float4*)&pQg[(size_t)cid * 8192 + d * 64 + ig];
    float4 p1 = *(const float4*)&pQg[(size_t)cid * 8192 + d * 64 + ig + 4];
    float4 g0 = {p0.x - ga[a][0], p0.y - ga[a][1], p0.z - ga[a][2], p0.w - ga[a][3]};
    float4 g1 = {p1.x - ga[a][4], p1.y - ga[a][5], p1.z - ga[a][6], p1.w - ga[a][7]};
    *(float4*)&Gtg[(size_t)cid * 8192 + d * 64 + ig]     = g0;
    *(float4*)&Gtg[(size_t)cid * 8192 + d * 64 + ig + 4] = g1;
  }
}

// ---------------------------------------------------------------------------
// scan_S: 16 blocks (one per head), 256 threads (4 waves).
// Sequential over chunks: Sg[c] = S ; S = M_c*S + B_c  via bf16x3 MFMA.
// S kept in LDS transposed: St[col m][k d] bf16 (hi/lo), padded stride 136.
// ---------------------------------------------------------------------------
__global__ __launch_bounds__(256) void scan_S(
    const u16* __restrict__ Mhi, const u16* __restrict__ Mlo,
    const float* __restrict__ Bg, float* __restrict__ Sg) {
  const int hv = blockIdx.x;
  const int tid = threadIdx.x;
  const int wave = tid >> 6, lane = tid & 63;
  const int fr = lane & 15, fq = lane >> 4;
  const int wr = (wave & 1) * 64;    // row block (new-S d)
  const int wc = (wave >> 1) * 64;   // col block (m)
  __shared__ u16 Shi[128 * 136];
  __shared__ u16 Slo[128 * 136];

  for (int i = tid; i < 128 * 136; i += 256) { Shi[i] = 0; Slo[i] = 0; }
  // Sg[chunk 0] = 0
  {
    float4 z4 = {0.f, 0.f, 0.f, 0.f};
    float* s0 = Sg + (size_t)hv * 16384;
#pragma unroll
    for (int it = 0; it < 16; ++it)
      *(float4*)&s0[it * 1024 + tid * 4] = z4;
  }
  __syncthreads();

  for (int c = 0; c < NC_ - 1; ++c) {
    const u16* Mh = Mhi + (size_t)(c * 16 + hv) * 16384;
    const u16* Ml = Mlo + (size_t)(c * 16 + hv) * 16384;
    const float* Bc = Bg + (size_t)(c * 16 + hv) * 16384;
    float* Sn = Sg + (size_t)((c + 1) * 16 + hv) * 16384;

    f32x4v acc[4][4] = {};
#pragma unroll
    for (int kt = 0; kt < 4; ++kt) {
      bf16x8 Ah[4], Al[4], Bh[4], Bl[4];
#pragma unroll
      for (int a = 0; a < 4; ++a) {
        const size_t ro = (size_t)(wr + a * 16 + fr) * 128 + kt * 32 + fq * 8;
        Ah[a] = *(const bf16x8*)&Mh[ro];
        Al[a] = *(const bf16x8*)&Ml[ro];
      }
#pragma unroll
      for (int b = 0; b < 4; ++b) {
        const int co = (wc + b * 16 + fr) * 136 + kt * 32 + fq * 8;
        Bh[b] = *(const bf16x8*)&Shi[co];
        Bl[b] = *(const bf16x8*)&Slo[co];
      }
#pragma unroll
      for (int a = 0; a < 4; ++a)
#pragma unroll
        for (int b = 0; b < 4; ++b) {
          acc[a][b] = __builtin_amdgcn_mfma_f32_16x16x32_bf16(
              Al[a], Bh[b], acc[a][b], 0, 0, 0);
          acc[a][b] = __builtin_amdgcn_mfma_f32_16x16x32_bf16(
              Ah[a], Bl[b], acc[a][b], 0, 0, 0);
          acc[a][b] = __builtin_amdgcn_mfma_f32_16x16x32_bf16(
              Ah[a], Bh[b], acc[a][b], 0, 0, 0);
        }
    }
    __syncthreads();   // all reads of Shi/Slo complete
#pragma unroll
    for (int a = 0; a < 4; ++a)
#pragma unroll
      for (int b = 0; b < 4; ++b) {
        const int row0 = wr + a * 16 + fq * 4;
        const int colg = wc + b * 16 + fr;
        float v[4];
        us4 h4, l4;
#pragma unroll
        for (int j = 0; j < 4; ++j) {
          v[j] = acc[a][b][j] + Bc[(size_t)(row0 + j) * 128 + colg];
          Sn[(size_t)(row0 + j) * 128 + colg] = v[j];
          u16 h = f2bf(v[j]);
          h4[j] = h;
          l4[j] = f2bf(v[j] - bf2f(h));
        }
        *(us4*)&Shi[colg * 136 + row0] = h4;
        *(us4*)&Slo[colg * 136 + row0] = l4;
      }
    __syncthreads();
  }
}

// ---------------------------------------------------------------------------
// chunk_out (parallel, 256 blocks): o = Mq^T U + G*S
//   o_i[m] = sum_j Mq[j][i] U[j][m] + sum_d Gt[d][i] S[d][m]
// ---------------------------------------------------------------------------
__global__ __launch_bounds__(256) void chunk_out(
    const float* __restrict__ Mqg, const float* __restrict__ Ug,
    const float* __restrict__ Gtg, const float* __restrict__ Sg,
    float* __restrict__ o) {
  const int c = blockIdx.x, hv = blockIdx.y;
  const int cid = c * 16 + hv;
  const int tid = threadIdx.x;
  __shared__ float Mql[64 * 64];
  __shared__ float Ul[64 * 128];
  __shared__ float Gtl[128 * 64];
  __shared__ float Sl[128 * 128];
#pragma unroll
  for (int it = 0; it < 4; ++it) {
    int f = it * 1024 + tid * 4;
    *(float4*)&Mql[f] = *(const float4*)&Mqg[(size_t)cid * 4096 + f];
  }
#pragma unroll
  for (int it = 0; it < 8; ++it) {
    int f = it * 1024 + tid * 4;
    *(float4*)&Ul[f]  = *(const float4*)&Ug[(size_t)cid * 8192 + f];
    *(float4*)&Gtl[f] = *(const float4*)&Gtg[(size_t)cid * 8192 + f];
  }
#pragma unroll
  for (int it = 0; it < 16; ++it) {
    int f = it * 1024 + tid * 4;
    *(float4*)&Sl[f] = *(const float4*)&Sg[(size_t)cid * 16384 + f];
  }
  __syncthreads();

  const int i0 = (tid & 15) * 4, m0 = (tid >> 4) * 8;
  float oa[4][8] = {};
  for (int j = 0; j < 64; ++j) {
    float4 mq = *(const float4*)&Mql[j * 64 + i0];
    float4 u0 = *(const float4*)&Ul[j * 128 + m0];
    float4 u1 = *(const float4*)&Ul[j * 128 + m0 + 4];
    float mv[4] = {mq.x, mq.y, mq.z, mq.w};
    float uv[8] = {u0.x, u0.y, u0.z, u0.w, u1.x, u1.y, u1.z, u1.w};
#pragma unroll
    for (int a = 0; a < 4; ++a)
#pragma unroll
      for (int b = 0; b < 8; ++b) oa[a][b] = fmaf(mv[a], uv[b], oa[a][b]);
  }
  for (int d = 0; d < 128; ++d) {
    float4 gt = *(const float4*)&Gtl[d * 64 + i0];
    float4 s0 = *(const float4*)&Sl[d * 128 + m0];
    float4 s1 = *(const float4*)&Sl[d * 128 + m0 + 4];
    float gv[4] = {gt.x, gt.y, gt.z, gt.w};
    float sv[8] = {s0.x, s0.y, s0.z, s0.w, s1.x, s1.y, s1.z, s1.w};
#pragma unroll
    for (int a = 0; a < 4; ++a)
#pragma unroll
      for (int b = 0; b < 8; ++b) oa[a][b] = fmaf(gv[a], sv[b], oa[a][b]);
  }
#pragma unroll
  for (int a = 0; a < 4; ++a) {
    const int t = c * 64 + i0 + a;
    float4 o0 = {oa[a][0], oa[a][1], oa[a][2], oa[a][3]};
    float4 o1 = {oa[a][4], oa[a][5], oa[a][6], oa[a][7]};
    *(float4*)&o[((size_t)t * HV_ + hv) * 128 + m0]     = o0;
    *(float4*)&o[((size_t)t * HV_ + hv) * 128 + m0 + 4] = o1;
  }
}

// ---------------------------------------------------------------------------
// h = o * silu(z); h *= rsqrt(mean(h^2)+eps); h *= norm_w  -> bf16 out
// ---------------------------------------------------------------------------
__global__ void gated_rmsnorm(const float* __restrict__ o,
                              const float* __restrict__ zbuf,
                              const float* __restrict__ norm_w,
                              u16* __restrict__ h) {
  const int t = blockIdx.x, hv = blockIdx.y, d = threadIdx.x;
  float ov = o[((size_t)t * HV_ + hv) * 128 + d];
  float zv = zbuf[(size_t)t * VD_ + hv * 128 + d];
  float hc = ov * (zv / (1.f + expf(-zv)));
  float ss = hc * hc;
#pragma unroll
  for (int off = 32; off >= 1; off >>= 1) ss += __shfl_xor(ss, off);
  __shared__ float s2[2];
  if ((d & 63) == 0) s2[d >> 6] = ss;
  __syncthreads();
  float tot = s2[0] + s2[1];
  float r = rsqrtf(tot * (1.f / 128.f) + 1e-6f);
  h[(size_t)t * VD_ + hv * 128 + d] = f2bf(hc * r * norm_w[d]);
}

// ---------------------------------------------------------------------------
extern "C" void kernel_launch(void* const* d_in, const int* in_sizes, int n_in,
                              void* d_out, int out_size, void* d_ws, size_t ws_size,
                              hipStream_t stream) {
  const float* x       = (const float*)d_in[0];
  const float* w_qkvz  = (const float*)d_in[1];
  const float* w_ba    = (const float*)d_in[2];
  const float* conv_w  = (const float*)d_in[3];
  const float* conv_b  = (const float*)d_in[4];
  const float* a_log   = (const float*)d_in[5];
  const float* dt_bias = (const float*)d_in[6];
  const float* norm_w  = (const float*)d_in[7];
  const float* w_o     = (const float*)d_in[8];
  float* out = (float*)d_out;

  float* ws = (float*)d_ws;
  float* qkvraw = ws;                  // 4,194,304  (-> Bg)
  float* zbuf   = ws + 4194304;        // 2,097,152
  float* qkvc   = ws + 6291456;        // 4,194,304  (-> Mhi|Mlo, -> wot)
  float* khat   = ws + 10485760;       // 1,048,576  (-> hb)
  float* gbuf   = ws + 11534336;       // 16,384
  float* bbuf   = ws + 11550720;       // 16,384
  float* cgbuf  = ws + 11567104;       // 16,384
  float* obuf   = ws + 11583488;       // 2,097,152  (xb early)
  float* Wtg    = ws + 13680640;       // 2,097,152 ┐ -> Sg (4,194,304)
  float* pQg    = ws + 15777792;       // 2,097,152 ┘
  float* Ug     = ws + 17874944;       // 2,097,152
  float* Mqg    = ws + 19972096;       // 1,048,576
  float* Gtg    = ws + 21020672;       // 2,097,152
  // total 23,117,824 f32 = 92.5 MB

  u16* xb   = (u16*)obuf;      // x bf16 (dead after gemm1)
  u16* wqt  = (u16*)Wtg;       // w_qkvz^T bf16, spans Wtg..Mqg (dead after gemm1)
  u16* Mhi  = (u16*)qkvc;      // 4,194,304 u16
  u16* Mlo  = (u16*)(qkvc + 2097152);
  float* Bg = qkvraw;
  float* Sg = Wtg;             // spans Wtg+pQg
  u16* wot  = (u16*)qkvc;      // after scan_S (Mhi dead)
  u16* hb   = (u16*)khat;      // after make_MBG (khat dead)

  // 0) casts
  cast_bf16<<<1024, 256, 0, stream>>>(x, xb, 262144);
  transpose_bf16<<<dim3(32, 96), 256, 0, stream>>>(w_qkvz, wqt, H_, QN_);
  // 1) qkv|z = x @ w_qkvz   (split outputs)
  gemm_bf16<<<dim3(8, 48), 256, 0, stream>>>(xb, wqt, qkvraw, CD_, zbuf, VD_,
                                             CD_, T_, QN_, H_);
  // 2) beta / g
  ba_gbeta<<<T_, 128, 0, stream>>>(x, w_ba, a_log, dt_bias, gbuf, bbuf);
  // 3) conv + silu on q|k|v
  conv_silu<<<dim3(CD_ / 256, T_), 256, 0, stream>>>(qkvraw, conv_w, conv_b, qkvc);
  // 4) k l2norm
  k_prep<<<dim3(T_, HK_), 128, 0, stream>>>(qkvc, khat);
  // 5) chunk-local precompute (parallel)
  chunk_prep<<<dim3(NC_, HV_), 256, 0, stream>>>(
      qkvc, khat, gbuf, bbuf, cgbuf, Wtg, Ug, Mqg, pQg);
  // 6) per-chunk transition/output operators (parallel)
  make_MBG<<<dim3(NC_, HV_), 256, 0, stream>>>(
      Wtg, pQg, Ug, Mqg, khat, cgbuf, Mhi, Mlo, Bg, Gtg);
  // 7) sequential state scan (bf16x3 MFMA)
  scan_S<<<16, 256, 0, stream>>>(Mhi, Mlo, Bg, Sg);
  // 8) w_o^T cast (Mhi region now dead)
  transpose_bf16<<<dim3(32, 32), 256, 0, stream>>>(w_o, wot, VD_, H_);
  // 9) per-chunk outputs (parallel)
  chunk_out<<<dim3(NC_, HV_), 256, 0, stream>>>(Mqg, Ug, Gtg, Sg, obuf);
  // 10) gated rmsnorm -> bf16 h
  gated_rmsnorm<<<dim3(T_, HV_), 128, 0, stream>>>(obuf, zbuf, norm_w, hb);
  // 11) out = h @ w_o
  gemm_bf16<<<dim3(8, 16), 256, 0, stream>>>(hb, wot, out, VD_, out, VD_,
                                             VD_, T_, VD_, H_);
}

// Round 5
// 311.147 us; speedup vs baseline: 4.3298x; 1.4127x over previous
//
#include <hip/hip_runtime.h>
#include <math.h>

typedef unsigned short u16;
using us4  = __attribute__((ext_vector_type(4))) unsigned short;
using us8  = __attribute__((ext_vector_type(8))) unsigned short;
using bf16x8 = __attribute__((ext_vector_type(8))) __bf16;
using f32x4v = __attribute__((ext_vector_type(4))) float;

// Problem constants
#define T_    1024
#define H_    2048
#define HK_   8
#define HV_   16
#define KD_   1024
#define VD_   2048
#define CD_   4096
#define QN_   6144   // 2*KD + 2*VD
#define NC_   16     // number of chunks
#define C_    64     // chunk length

__device__ __forceinline__ u16 f2bf(float f) {
  unsigned u = __float_as_uint(f);
  u += 0x7fffu + ((u >> 16) & 1u);   // RNE
  return (u16)(u >> 16);
}
__device__ __forceinline__ float bf2f(u16 h) {
  return __uint_as_float(((unsigned)h) << 16);
}

// ---------------------------------------------------------------------------
// elementwise f32 -> bf16 (8 elems/thread)
// ---------------------------------------------------------------------------
__global__ void cast_bf16(const float* __restrict__ in, u16* __restrict__ out,
                          int n8) {
  int i = blockIdx.x * 256 + threadIdx.x;
  if (i >= n8) return;
  float4 a = ((const float4*)in)[i * 2];
  float4 b = ((const float4*)in)[i * 2 + 1];
  us8 r = {f2bf(a.x), f2bf(a.y), f2bf(a.z), f2bf(a.w),
           f2bf(b.x), f2bf(b.y), f2bf(b.z), f2bf(b.w)};
  *(us8*)&out[(size_t)i * 8] = r;
}

// ---------------------------------------------------------------------------
// f32 [R][C] -> bf16 [C][R] (transpose + cast), 64x64 tiles
// ---------------------------------------------------------------------------
__global__ __launch_bounds__(256) void transpose_bf16(
    const float* __restrict__ in, u16* __restrict__ out, int R, int C) {
  __shared__ float tile[64][65];
  const int r0 = blockIdx.x * 64, c0 = blockIdx.y * 64;
  const int t = threadIdx.x;
  const int tr = t >> 4, tc4 = (t & 15) * 4;
#pragma unroll
  for (int i = 0; i < 4; ++i) {
    float4 v = *(const float4*)&in[(size_t)(r0 + tr + i * 16) * C + c0 + tc4];
    tile[tr + i * 16][tc4 + 0] = v.x;
    tile[tr + i * 16][tc4 + 1] = v.y;
    tile[tr + i * 16][tc4 + 2] = v.z;
    tile[tr + i * 16][tc4 + 3] = v.w;
  }
  __syncthreads();
#pragma unroll
  for (int i = 0; i < 4; ++i) {
    int oc = tr + i * 16;
    us4 w = {f2bf(tile[tc4 + 0][oc]), f2bf(tile[tc4 + 1][oc]),
             f2bf(tile[tc4 + 2][oc]), f2bf(tile[tc4 + 3][oc])};
    *(us4*)&out[(size_t)(c0 + oc) * R + r0 + tc4] = w;
  }
}

// ---------------------------------------------------------------------------
// bf16 MFMA GEMM: C = A[M,K] @ Bt[N,K]^T, f32 out. Output is routed to Cq
// (cols < zsplit, leading dim ldq) or Cz (cols >= zsplit, leading dim ldz).
// ---------------------------------------------------------------------------
__device__ __forceinline__ void gload_lds16(const void* g, void* l) {
  __builtin_amdgcn_global_load_lds(
      (const __attribute__((address_space(1))) void*)g,
      (__attribute__((address_space(3))) void*)l, 16, 0, 0);
}

__global__ __launch_bounds__(256) void gemm_bf16(
    const u16* __restrict__ A, const u16* __restrict__ Bt,
    float* __restrict__ Cq, int ldq, float* __restrict__ Cz, int ldz,
    int zsplit, int M, int N, int K) {
  __shared__ __align__(16) u16 As[4096];   // [128][32]
  __shared__ __align__(16) u16 Bs[4096];
  const int tid  = threadIdx.x;
  const int wave = tid >> 6, lane = tid & 63;
  const int row0 = blockIdx.x * 128, col0 = blockIdx.y * 128;
  const int wr = wave >> 1, wc = wave & 1;
  const int fr = lane & 15, fq = lane >> 4;

  const int srow = wave * 16 + (lane >> 2);
  const int scol = (lane & 3) * 8;
  const u16* gA0 = A  + (size_t)(row0 + srow) * K + scol;
  const u16* gA1 = gA0 + (size_t)64 * K;
  const u16* gB0 = Bt + (size_t)(col0 + srow) * K + scol;
  const u16* gB1 = gB0 + (size_t)64 * K;
  u16* lA0 = &As[wave * 512];
  u16* lA1 = &As[2048 + wave * 512];
  u16* lB0 = &Bs[wave * 512];
  u16* lB1 = &Bs[2048 + wave * 512];

  f32x4v acc[4][4] = {};

  for (int k0 = 0; k0 < K; k0 += 32) {
    __syncthreads();
    gload_lds16(gA0 + k0, lA0);
    gload_lds16(gA1 + k0, lA1);
    gload_lds16(gB0 + k0, lB0);
    gload_lds16(gB1 + k0, lB1);
    asm volatile("s_waitcnt vmcnt(0)" ::: "memory");
    __syncthreads();

    bf16x8 af[4], bff[4];
#pragma unroll
    for (int mi = 0; mi < 4; ++mi)
      af[mi] = *(const bf16x8*)&As[(wr * 64 + mi * 16 + fr) * 32 + fq * 8];
#pragma unroll
    for (int ni = 0; ni < 4; ++ni)
      bff[ni] = *(const bf16x8*)&Bs[(wc * 64 + ni * 16 + fr) * 32 + fq * 8];
#pragma unroll
    for (int mi = 0; mi < 4; ++mi)
#pragma unroll
      for (int ni = 0; ni < 4; ++ni)
        acc[mi][ni] = __builtin_amdgcn_mfma_f32_16x16x32_bf16(
            af[mi], bff[ni], acc[mi][ni], 0, 0, 0);
  }

  float* Cp; int ldc, cb;
  if (col0 < zsplit) { Cp = Cq; ldc = ldq; cb = col0; }
  else               { Cp = Cz; ldc = ldz; cb = col0 - zsplit; }
#pragma unroll
  for (int mi = 0; mi < 4; ++mi)
#pragma unroll
    for (int ni = 0; ni < 4; ++ni) {
      const int r  = row0 + wr * 64 + mi * 16 + fq * 4;
      const int cc = cb + wc * 64 + ni * 16 + fr;
#pragma unroll
      for (int j = 0; j < 4; ++j)
        Cp[(size_t)(r + j) * ldc + cc] = acc[mi][ni][j];
    }
}

// ---------------------------------------------------------------------------
// ba = x @ w_ba -> beta = sigmoid(b), g = -exp(a_log)*softplus(a+dt_bias)
// ---------------------------------------------------------------------------
__global__ void ba_gbeta(const float* __restrict__ x,
                         const float* __restrict__ w_ba,
                         const float* __restrict__ a_log,
                         const float* __restrict__ dt_bias,
                         float* __restrict__ g, float* __restrict__ beta) {
  const int t = blockIdx.x;
  const int tid = threadIdx.x;      // 128
  const int c = tid & 31;
  const int chunk = tid >> 5;
  const float* xr = x + (size_t)t * H_;
  float p = 0.f;
  const int kb = chunk * 512;
  for (int k = kb; k < kb + 512; ++k) p = fmaf(xr[k], w_ba[k * 32 + c], p);
  __shared__ float red[4][32];
  red[chunk][c] = p;
  __syncthreads();
  if (tid < 32) {
    float s = red[0][c] + red[1][c] + red[2][c] + red[3][c];
    if (c < 16) {
      beta[t * 16 + c] = 1.f / (1.f + expf(-s));
    } else {
      int h = c - 16;
      float xx = s + dt_bias[h];
      float sp = xx > 20.f ? xx : log1pf(expf(xx));
      g[t * 16 + h] = -expf(a_log[h]) * sp;
    }
  }
}

// ---------------------------------------------------------------------------
// causal depthwise conv1d (K=4) + SiLU.  input qkvraw [T][4096]
// ---------------------------------------------------------------------------
__global__ void conv_silu(const float* __restrict__ qkvraw,
                          const float* __restrict__ conv_w,
                          const float* __restrict__ conv_b,
                          float* __restrict__ qkvc) {
  const int c = blockIdx.x * 256 + threadIdx.x;
  const int t = blockIdx.y;
  float acc = conv_b[c];
#pragma unroll
  for (int j = 0; j < 4; ++j) {
    int tt = t - 3 + j;
    if (tt >= 0) acc = fmaf(qkvraw[(size_t)tt * CD_ + c], conv_w[c * 4 + j], acc);
  }
  float sg = 1.f / (1.f + expf(-acc));
  qkvc[(size_t)t * CD_ + c] = acc * sg;
}

// ---------------------------------------------------------------------------
// k L2 norm per (t, hk)
// ---------------------------------------------------------------------------
__global__ void k_prep(const float* __restrict__ qkvc,
                       float* __restrict__ khat) {
  const int t = blockIdx.x, hk = blockIdx.y, d = threadIdx.x;
  float kv = qkvc[(size_t)t * CD_ + KD_ + hk * 128 + d];
  float sk = kv * kv;
#pragma unroll
  for (int off = 32; off >= 1; off >>= 1) sk += __shfl_xor(sk, off);
  __shared__ float s2[2];
  if ((d & 63) == 0) s2[d >> 6] = sk;
  __syncthreads();
  float ssk = s2[0] + s2[1];
  khat[((size_t)t * HK_ + hk) * 128 + d] = kv * rsqrtf(ssk + 1e-6f);
}

// ---------------------------------------------------------------------------
// Chunked gated delta rule, phase A (parallel over 16 chunks x 16 heads).
// ---------------------------------------------------------------------------
#define SWZ(r) (((r) >> 2) & 7)

__device__ __forceinline__ float4 ldsw4(const float* base, int r, int dblk) {
  return *(const float4*)&base[r * 128 + ((dblk ^ SWZ(r)) << 2)];
}
__device__ __forceinline__ float ldsw1(const float* base, int r, int d) {
  return base[r * 128 + ((((d) >> 2) ^ SWZ(r)) << 2) + ((d) & 3)];
}

__global__ __launch_bounds__(256) void chunk_prep(
    const float* __restrict__ qkvc, const float* __restrict__ khat,
    const float* __restrict__ g, const float* __restrict__ beta,
    float* __restrict__ cgbuf, float* __restrict__ Wtg, float* __restrict__ Ug,
    float* __restrict__ Mqg, float* __restrict__ pQg) {
  const int c = blockIdx.x, hv = blockIdx.y, hk = hv >> 1;
  const int cid = c * 16 + hv;
  const int tid = threadIdx.x;
  __shared__ float Kl[8192], Ql[8192];   // swizzled [64][128]
  __shared__ float AM[8320];             // At[64][65] | Mq[64][65]; later Utr
  __shared__ float cgl[64], bl[64], bp[64], rsl[64];
  float* At = AM;
  float* Mq = AM + 4160;

#pragma unroll
  for (int it = 0; it < 8; ++it) {
    int flat = it * 1024 + tid * 4;
    int row = flat >> 7, d = flat & 127;
    int pb = ((d >> 2) ^ SWZ(row)) << 2;
    int gt = c * 64 + row;
    float4 kv = *(const float4*)&khat[((size_t)gt * HK_ + hk) * 128 + d];
    float4 qv = *(const float4*)&qkvc[(size_t)gt * CD_ + hk * 128 + d];
    *(float4*)&Kl[row * 128 + pb] = kv;
    *(float4*)&Ql[row * 128 + pb] = qv;
  }
  if (tid < 64) {
    float s = g[(size_t)(c * 64 + tid) * HV_ + hv];
#pragma unroll
    for (int off = 1; off < 64; off <<= 1) {
      float t = __shfl_up(s, off);
      if (tid >= off) s += t;
    }
    cgl[tid] = s;
    cgbuf[cid * 64 + tid] = s;
    bl[tid] = beta[(size_t)(c * 64 + tid) * HV_ + hv];
  }
  __syncthreads();
  if (tid < 64) {
    float sq = 0.f;
#pragma unroll
    for (int dblk = 0; dblk < 32; ++dblk) {
      float4 q4 = ldsw4(Ql, tid, dblk);
      sq = fmaf(q4.x, q4.x, sq); sq = fmaf(q4.y, q4.y, sq);
      sq = fmaf(q4.z, q4.z, sq); sq = fmaf(q4.w, q4.w, sq);
    }
    rsl[tid] = rsqrtf(sq + 1e-6f) * 0.08838834764831845f;
    bp[tid] = bl[tid] * expf(cgl[tid]);
  }
  __syncthreads();

  const int i0 = (tid >> 4) * 4, j0 = (tid & 15) * 4;
  float kk[4][4], qk[4][4];
#pragma unroll
  for (int a = 0; a < 4; ++a)
#pragma unroll
    for (int b = 0; b < 4; ++b) { kk[a][b] = 0.f; qk[a][b] = 0.f; }
  for (int dblk = 0; dblk < 32; ++dblk) {
    float4 ka[4], qa[4], kb[4];
#pragma unroll
    for (int a = 0; a < 4; ++a) {
      ka[a] = ldsw4(Kl, i0 + a, dblk);
      qa[a] = ldsw4(Ql, i0 + a, dblk);
    }
#pragma unroll
    for (int b = 0; b < 4; ++b) kb[b] = ldsw4(Kl, j0 + b, dblk);
#pragma unroll
    for (int a = 0; a < 4; ++a)
#pragma unroll
      for (int b = 0; b < 4; ++b) {
        kk[a][b] = fmaf(ka[a].x, kb[b].x, kk[a][b]);
        kk[a][b] = fmaf(ka[a].y, kb[b].y, kk[a][b]);
        kk[a][b] = fmaf(ka[a].z, kb[b].z, kk[a][b]);
        kk[a][b] = fmaf(ka[a].w, kb[b].w, kk[a][b]);
        qk[a][b] = fmaf(qa[a].x, kb[b].x, qk[a][b]);
        qk[a][b] = fmaf(qa[a].y, kb[b].y, qk[a][b]);
        qk[a][b] = fmaf(qa[a].z, kb[b].z, qk[a][b]);
        qk[a][b] = fmaf(qa[a].w, kb[b].w, qk[a][b]);
      }
  }
#pragma unroll
  for (int a = 0; a < 4; ++a)
#pragma unroll
    for (int b = 0; b < 4; ++b) {
      int i = i0 + a, j = j0 + b;
      float e = expf(cgl[i] - cgl[j]);
      At[j * 65 + i] = (j < i) ? (-bl[i] * e * kk[a][b]) : 0.f;
      Mq[j * 65 + i] = (j <= i) ? (rsl[i] * e * qk[a][b]) : 0.f;
    }
  __syncthreads();

  float X[64];
  if (tid < 128) {
#pragma unroll
    for (int j = 0; j < 64; ++j) X[j] = bp[j] * ldsw1(Kl, j, tid);
  } else {
    const int m = tid - 128;
#pragma unroll
    for (int j = 0; j < 64; ++j)
      X[j] = bl[j] * qkvc[(size_t)(c * 64 + j) * CD_ + 2 * KD_ + hv * 128 + m];
  }
#pragma unroll
  for (int it = 0; it < 16; ++it) {
    int f = it * 256 + tid;
    int j = f >> 6, i = f & 63;
    Mqg[(size_t)cid * 4096 + f] = Mq[j * 65 + i];
  }
#pragma unroll
  for (int j = 0; j < 63; ++j) {
    float xj = X[j];
#pragma unroll
    for (int i = j + 1; i < 64; ++i) X[i] = fmaf(At[j * 65 + i], xj, X[i]);
  }
  __syncthreads();

  if (tid < 128) {
    size_t baseo = ((size_t)cid * 128 + tid) * 64;
#pragma unroll
    for (int j4 = 0; j4 < 16; ++j4) {
      float4 v = {X[j4 * 4], X[j4 * 4 + 1], X[j4 * 4 + 2], X[j4 * 4 + 3]};
      *(float4*)&Wtg[baseo + j4 * 4] = v;
    }
  } else {
    const int m = tid - 128;
    float* Utr = AM;
#pragma unroll
    for (int j = 0; j < 64; ++j) Utr[j * 128 + m] = X[j];
  }
  __syncthreads();
  {
    const float* Utr = AM;
#pragma unroll
    for (int it = 0; it < 8; ++it) {
      int flat = it * 1024 + tid * 4;
      *(float4*)&Ug[(size_t)cid * 8192 + flat] = *(const float4*)&Utr[flat];
    }
    const int i = tid & 63;
    const float ei = expf(cgl[i]) * rsl[i];
#pragma unroll
    for (int it = 0; it < 32; ++it) {
      int d = it * 4 + (tid >> 6);
      pQg[(size_t)cid * 8192 + d * 64 + i] = ei * ldsw1(Ql, i, d);
    }
  }
}

// ---------------------------------------------------------------------------
// make_MBG (parallel, 256 blocks): per chunk-head
//   M[d][d'] = pC*delta - sum_j esc_j*khat_j[d]*W[j][d']   -> Mhi/Mlo bf16
//   B[d][m]  = sum_j esc_j*khat_j[d]*U[j][m]               -> f32
//   Gt[d][i] = pQ[d][i] - sum_j W[j][d]*Mq[j][i]           -> f32
// ---------------------------------------------------------------------------
__global__ __launch_bounds__(256) void make_MBG(
    const float* __restrict__ Wtg, const float* __restrict__ pQg,
    const float* __restrict__ Ug, const float* __restrict__ Mqg,
    const float* __restrict__ khat, const float* __restrict__ cgbuf,
    u16* __restrict__ Mhi, u16* __restrict__ Mlo,
    float* __restrict__ Bg, float* __restrict__ Gtg) {
  const int c = blockIdx.x, hv = blockIdx.y, hk = hv >> 1;
  const int cid = c * 16 + hv;
  const int tid = threadIdx.x;
  __shared__ float Wl[64 * 128];   // W[j][d]
  __shared__ float Kel[64 * 128];  // esc_j * khat_j[d]
  __shared__ float Ul[64 * 128];
  __shared__ float Mql[64 * 64];
  const float cg63 = cgbuf[cid * 64 + 63];
  const float pC = expf(cg63);
  // stage W (transpose from Wtg [d][j])
#pragma unroll
  for (int it = 0; it < 8; ++it) {
    int f = it * 1024 + tid * 4;       // f = d*64 + j
    int d = f >> 6, j = f & 63;
    float4 w = *(const float4*)&Wtg[(size_t)cid * 8192 + f];
    Wl[(j + 0) * 128 + d] = w.x;
    Wl[(j + 1) * 128 + d] = w.y;
    Wl[(j + 2) * 128 + d] = w.z;
    Wl[(j + 3) * 128 + d] = w.w;
  }
#pragma unroll
  for (int it = 0; it < 8; ++it) {
    int f = it * 1024 + tid * 4;       // f = j*128 + d
    int j = f >> 7, d = f & 127;
    float esc = expf(cg63 - cgbuf[cid * 64 + j]);
    float4 kv = *(const float4*)&khat[((size_t)(c * 64 + j) * HK_ + hk) * 128 + d];
    float4 uv = *(const float4*)&Ug[(size_t)cid * 8192 + f];
    kv.x *= esc; kv.y *= esc; kv.z *= esc; kv.w *= esc;
    *(float4*)&Kel[f] = kv;
    *(float4*)&Ul[f] = uv;
  }
#pragma unroll
  for (int it = 0; it < 4; ++it) {
    int f = it * 1024 + tid * 4;
    *(float4*)&Mql[f] = *(const float4*)&Mqg[(size_t)cid * 4096 + f];
  }
  __syncthreads();

  // fused M+B: tile rows d0..d0+7, cols n0..n0+7
  const int d0 = (tid & 15) * 8, n0 = (tid >> 4) * 8;
  float ma[8][8] = {}, ba[8][8] = {};
  for (int j = 0; j < 64; ++j) {
    float4 k0 = *(const float4*)&Kel[j * 128 + d0];
    float4 k1 = *(const float4*)&Kel[j * 128 + d0 + 4];
    float4 w0 = *(const float4*)&Wl[j * 128 + n0];
    float4 w1 = *(const float4*)&Wl[j * 128 + n0 + 4];
    float4 u0 = *(const float4*)&Ul[j * 128 + n0];
    float4 u1 = *(const float4*)&Ul[j * 128 + n0 + 4];
    float ke[8] = {k0.x, k0.y, k0.z, k0.w, k1.x, k1.y, k1.z, k1.w};
    float wv[8] = {w0.x, w0.y, w0.z, w0.w, w1.x, w1.y, w1.z, w1.w};
    float uv[8] = {u0.x, u0.y, u0.z, u0.w, u1.x, u1.y, u1.z, u1.w};
#pragma unroll
    for (int a = 0; a < 8; ++a)
#pragma unroll
      for (int b = 0; b < 8; ++b) {
        ma[a][b] = fmaf(ke[a], wv[b], ma[a][b]);
        ba[a][b] = fmaf(ke[a], uv[b], ba[a][b]);
      }
  }
#pragma unroll
  for (int a = 0; a < 8; ++a) {
    const int d = d0 + a;
    us8 hi, lo;
#pragma unroll
    for (int b = 0; b < 8; ++b) {
      float m = ((d == n0 + b) ? pC : 0.f) - ma[a][b];
      u16 h = f2bf(m);
      hi[b] = h;
      lo[b] = f2bf(m - bf2f(h));
    }
    *(us8*)&Mhi[(size_t)cid * 16384 + d * 128 + n0] = hi;
    *(us8*)&Mlo[(size_t)cid * 16384 + d * 128 + n0] = lo;
    float4 b0 = {ba[a][0], ba[a][1], ba[a][2], ba[a][3]};
    float4 b1 = {ba[a][4], ba[a][5], ba[a][6], ba[a][7]};
    *(float4*)&Bg[(size_t)cid * 16384 + d * 128 + n0]     = b0;
    *(float4*)&Bg[(size_t)cid * 16384 + d * 128 + n0 + 4] = b1;
  }

  // G phase: Gt[d][i] tile 4d x 8i
  const int dg = (tid & 31) * 4, ig = (tid >> 5) * 8;
  float ga[4][8] = {};
  for (int j = 0; j < 64; ++j) {
    float4 w4 = *(const float4*)&Wl[j * 128 + dg];
    float4 m0 = *(const float4*)&Mql[j * 64 + ig];
    float4 m1 = *(const float4*)&Mql[j * 64 + ig + 4];
    float wv[4] = {w4.x, w4.y, w4.z, w4.w};
    float mv[8] = {m0.x, m0.y, m0.z, m0.w, m1.x, m1.y, m1.z, m1.w};
#pragma unroll
    for (int a = 0; a < 4; ++a)
#pragma unroll
      for (int b = 0; b < 8; ++b) ga[a][b] = fmaf(wv[a], mv[b], ga[a][b]);
  }
#pragma unroll
  for (int a = 0; a < 4; ++a) {
    const int d = dg + a;
    float4 p0 = *(const float4*)&pQg[(size_t)cid * 8192 + d * 64 + ig];
    float4 p1 = *(const float4*)&pQg[(size_t)cid * 8192 + d * 64 + ig + 4];
    float4 g0 = {p0.x - ga[a][0], p0.y - ga[a][1], p0.z - ga[a][2], p0.w - ga[a][3]};
    float4 g1 = {p1.x - ga[a][4], p1.y - ga[a][5], p1.z - ga[a][6], p1.w - ga[a][7]};
    *(float4*)&Gtg[(size_t)cid * 8192 + d * 64 + ig]     = g0;
    *(float4*)&Gtg[(size_t)cid * 8192 + d * 64 + ig + 4] = g1;
  }
}

// ---------------------------------------------------------------------------
// scan_S v2: 64 blocks = 16 heads x 4 col-slices (cols independent!).
// Block mapping puts all 4 slices of a head on one XCD (flat%8 == hv%8).
// M frags load straight to VGPRs (prefetched one chunk ahead); S slice
// (128x32) double-buffered hi/lo in XOR-swizzled LDS; one barrier/step.
// ---------------------------------------------------------------------------
__global__ __launch_bounds__(256) void scan_S(
    const u16* __restrict__ Mhi, const u16* __restrict__ Mlo,
    const float* __restrict__ Bg, float* __restrict__ Sg) {
  const int flat = blockIdx.x;
  const int hv = (flat & 7) + 8 * (flat >> 5);          // flat%8 + 8*(flat/32)
  const int vs = (flat >> 3) & 3;
  const int tid = threadIdx.x;
  const int wave = tid >> 6, lane = tid & 63;
  const int fr = lane & 15, fq = lane >> 4;
  const int wr = wave * 32;       // this wave's output-row block (d of S_new)
  const int m0 = vs * 32;         // block's col slice base (global m)

  __shared__ u16 Sh[2][4096];     // [m 32][k 128] bf16-hi, 16B-granule XOR swz
  __shared__ u16 Sl[2][4096];

  for (int i = tid; i < 4096; i += 256) { Sh[0][i] = 0; Sl[0][i] = 0; }
  {
    float* s0 = Sg + (size_t)hv * 16384 + m0;
#pragma unroll
    for (int it = 0; it < 16; ++it) {
      int idx = it * 256 + tid;
      s0[(size_t)(idx >> 5) * 128 + (idx & 31)] = 0.f;
    }
  }
  __syncthreads();

  bf16x8 MhA[2][4], MlA[2][4], MhB[2][4], MlB[2][4];
  {
    const u16* Mh0 = Mhi + (size_t)hv * 16384;   // chunk 0
    const u16* Ml0 = Mlo + (size_t)hv * 16384;
#pragma unroll
    for (int a = 0; a < 2; ++a)
#pragma unroll
      for (int kt = 0; kt < 4; ++kt) {
        size_t off = (size_t)(wr + a * 16 + fr) * 128 + kt * 32 + fq * 8;
        MhA[a][kt] = *(const bf16x8*)&Mh0[off];
        MlA[a][kt] = *(const bf16x8*)&Ml0[off];
      }
  }
  int p = 0;

  auto step = [&](int c, bf16x8 (&MhC)[2][4], bf16x8 (&MlC)[2][4],
                  bf16x8 (&MhN)[2][4], bf16x8 (&MlN)[2][4]) {
    // prefetch next chunk's M frags (lands during this step's compute)
    if (c + 1 < NC_ - 1) {
      const u16* MhP = Mhi + (size_t)((c + 1) * 16 + hv) * 16384;
      const u16* MlP = Mlo + (size_t)((c + 1) * 16 + hv) * 16384;
#pragma unroll
      for (int a = 0; a < 2; ++a)
#pragma unroll
        for (int kt = 0; kt < 4; ++kt) {
          size_t off = (size_t)(wr + a * 16 + fr) * 128 + kt * 32 + fq * 8;
          MhN[a][kt] = *(const bf16x8*)&MhP[off];
          MlN[a][kt] = *(const bf16x8*)&MlP[off];
        }
    }
    // B_c in acc layout
    const float* Bc = Bg + (size_t)(c * 16 + hv) * 16384 + m0;
    float bv[2][2][4];
#pragma unroll
    for (int a = 0; a < 2; ++a)
#pragma unroll
      for (int b = 0; b < 2; ++b)
#pragma unroll
        for (int j = 0; j < 4; ++j)
          bv[a][b][j] =
              Bc[(size_t)(wr + a * 16 + fq * 4 + j) * 128 + b * 16 + fr];

    // acc = M_c @ S_c  (bf16 hi/lo x3)
    f32x4v acc[2][2] = {};
#pragma unroll
    for (int kt = 0; kt < 4; ++kt) {
      bf16x8 Bh[2], Bl[2];
#pragma unroll
      for (int b = 0; b < 2; ++b) {
        int m = b * 16 + fr;
        int byte = m * 256 + ((kt * 64 + fq * 16) ^ ((m & 7) << 4));
        Bh[b] = *(const bf16x8*)((const char*)&Sh[p][0] + byte);
        Bl[b] = *(const bf16x8*)((const char*)&Sl[p][0] + byte);
      }
#pragma unroll
      for (int a = 0; a < 2; ++a)
#pragma unroll
        for (int b = 0; b < 2; ++b) {
          acc[a][b] = __builtin_amdgcn_mfma_f32_16x16x32_bf16(
              MlC[a][kt], Bh[b], acc[a][b], 0, 0, 0);
          acc[a][b] = __builtin_amdgcn_mfma_f32_16x16x32_bf16(
              MhC[a][kt], Bl[b], acc[a][b], 0, 0, 0);
          acc[a][b] = __builtin_amdgcn_mfma_f32_16x16x32_bf16(
              MhC[a][kt], Bh[b], acc[a][b], 0, 0, 0);
        }
    }
    // S_{c+1} = acc + B; store f32 slice; write hi/lo into buffer p^1
    float* Sn = Sg + (size_t)((c + 1) * 16 + hv) * 16384 + m0;
#pragma unroll
    for (int a = 0; a < 2; ++a)
#pragma unroll
      for (int b = 0; b < 2; ++b) {
        const int k0 = wr + a * 16 + fq * 4;
        const int m = b * 16 + fr;
        us4 h4, l4;
#pragma unroll
        for (int j = 0; j < 4; ++j) {
          float v = acc[a][b][j] + bv[a][b][j];
          Sn[(size_t)(k0 + j) * 128 + m] = v;
          u16 h = f2bf(v);
          h4[j] = h;
          l4[j] = f2bf(v - bf2f(h));
        }
        int byte = m * 256 + (((k0 * 2)) ^ ((m & 7) << 4));
        *(us4*)((char*)&Sh[p ^ 1][0] + byte) = h4;
        *(us4*)((char*)&Sl[p ^ 1][0] + byte) = l4;
      }
    __syncthreads();
    p ^= 1;
  };

  for (int cc = 0; cc < NC_ - 1; cc += 2) {
    step(cc, MhA, MlA, MhB, MlB);
    if (cc + 1 < NC_ - 1) step(cc + 1, MhB, MlB, MhA, MlA);
  }
}

// ---------------------------------------------------------------------------
// chunk_out (parallel, 256 blocks): o = Mq^T U + G*S
// ---------------------------------------------------------------------------
__global__ __launch_bounds__(256) void chunk_out(
    const float* __restrict__ Mqg, const float* __restrict__ Ug,
    const float* __restrict__ Gtg, const float* __restrict__ Sg,
    float* __restrict__ o) {
  const int c = blockIdx.x, hv = blockIdx.y;
  const int cid = c * 16 + hv;
  const int tid = threadIdx.x;
  __shared__ float Mql[64 * 64];
  __shared__ float Ul[64 * 128];
  __shared__ float Gtl[128 * 64];
  __shared__ float Sl[128 * 128];
#pragma unroll
  for (int it = 0; it < 4; ++it) {
    int f = it * 1024 + tid * 4;
    *(float4*)&Mql[f] = *(const float4*)&Mqg[(size_t)cid * 4096 + f];
  }
#pragma unroll
  for (int it = 0; it < 8; ++it) {
    int f = it * 1024 + tid * 4;
    *(float4*)&Ul[f]  = *(const float4*)&Ug[(size_t)cid * 8192 + f];
    *(float4*)&Gtl[f] = *(const float4*)&Gtg[(size_t)cid * 8192 + f];
  }
#pragma unroll
  for (int it = 0; it < 16; ++it) {
    int f = it * 1024 + tid * 4;
    *(float4*)&Sl[f] = *(const float4*)&Sg[(size_t)cid * 16384 + f];
  }
  __syncthreads();

  const int i0 = (tid & 15) * 4, m0 = (tid >> 4) * 8;
  float oa[4][8] = {};
  for (int j = 0; j < 64; ++j) {
    float4 mq = *(const float4*)&Mql[j * 64 + i0];
    float4 u0 = *(const float4*)&Ul[j * 128 + m0];
    float4 u1 = *(const float4*)&Ul[j * 128 + m0 + 4];
    float mv[4] = {mq.x, mq.y, mq.z, mq.w};
    float uv[8] = {u0.x, u0.y, u0.z, u0.w, u1.x, u1.y, u1.z, u1.w};
#pragma unroll
    for (int a = 0; a < 4; ++a)
#pragma unroll
      for (int b = 0; b < 8; ++b) oa[a][b] = fmaf(mv[a], uv[b], oa[a][b]);
  }
  for (int d = 0; d < 128; ++d) {
    float4 gt = *(const float4*)&Gtl[d * 64 + i0];
    float4 s0 = *(const float4*)&Sl[d * 128 + m0];
    float4 s1 = *(const float4*)&Sl[d * 128 + m0 + 4];
    float gv[4] = {gt.x, gt.y, gt.z, gt.w};
    float sv[8] = {s0.x, s0.y, s0.z, s0.w, s1.x, s1.y, s1.z, s1.w};
#pragma unroll
    for (int a = 0; a < 4; ++a)
#pragma unroll
      for (int b = 0; b < 8; ++b) oa[a][b] = fmaf(gv[a], sv[b], oa[a][b]);
  }
#pragma unroll
  for (int a = 0; a < 4; ++a) {
    const int t = c * 64 + i0 + a;
    float4 o0 = {oa[a][0], oa[a][1], oa[a][2], oa[a][3]};
    float4 o1 = {oa[a][4], oa[a][5], oa[a][6], oa[a][7]};
    *(float4*)&o[((size_t)t * HV_ + hv) * 128 + m0]     = o0;
    *(float4*)&o[((size_t)t * HV_ + hv) * 128 + m0 + 4] = o1;
  }
}

// ---------------------------------------------------------------------------
// h = o * silu(z); h *= rsqrt(mean(h^2)+eps); h *= norm_w  -> bf16 out
// ---------------------------------------------------------------------------
__global__ void gated_rmsnorm(const float* __restrict__ o,
                              const float* __restrict__ zbuf,
                              const float* __restrict__ norm_w,
                              u16* __restrict__ h) {
  const int t = blockIdx.x, hv = blockIdx.y, d = threadIdx.x;
  float ov = o[((size_t)t * HV_ + hv) * 128 + d];
  float zv = zbuf[(size_t)t * VD_ + hv * 128 + d];
  float hc = ov * (zv / (1.f + expf(-zv)));
  float ss = hc * hc;
#pragma unroll
  for (int off = 32; off >= 1; off >>= 1) ss += __shfl_xor(ss, off);
  __shared__ float s2[2];
  if ((d & 63) == 0) s2[d >> 6] = ss;
  __syncthreads();
  float tot = s2[0] + s2[1];
  float r = rsqrtf(tot * (1.f / 128.f) + 1e-6f);
  h[(size_t)t * VD_ + hv * 128 + d] = f2bf(hc * r * norm_w[d]);
}

// ---------------------------------------------------------------------------
extern "C" void kernel_launch(void* const* d_in, const int* in_sizes, int n_in,
                              void* d_out, int out_size, void* d_ws, size_t ws_size,
                              hipStream_t stream) {
  const float* x       = (const float*)d_in[0];
  const float* w_qkvz  = (const float*)d_in[1];
  const float* w_ba    = (const float*)d_in[2];
  const float* conv_w  = (const float*)d_in[3];
  const float* conv_b  = (const float*)d_in[4];
  const float* a_log   = (const float*)d_in[5];
  const float* dt_bias = (const float*)d_in[6];
  const float* norm_w  = (const float*)d_in[7];
  const float* w_o     = (const float*)d_in[8];
  float* out = (float*)d_out;

  float* ws = (float*)d_ws;
  float* qkvraw = ws;                  // 4,194,304  (-> Bg)
  float* zbuf   = ws + 4194304;        // 2,097,152
  float* qkvc   = ws + 6291456;        // 4,194,304  (-> Mhi|Mlo, -> wot)
  float* khat   = ws + 10485760;       // 1,048,576  (-> hb)
  float* gbuf   = ws + 11534336;       // 16,384
  float* bbuf   = ws + 11550720;       // 16,384
  float* cgbuf  = ws + 11567104;       // 16,384
  float* obuf   = ws + 11583488;       // 2,097,152  (xb early)
  float* Wtg    = ws + 13680640;       // 2,097,152 ┐ -> Sg (4,194,304)
  float* pQg    = ws + 15777792;       // 2,097,152 ┘
  float* Ug     = ws + 17874944;       // 2,097,152
  float* Mqg    = ws + 19972096;       // 1,048,576
  float* Gtg    = ws + 21020672;       // 2,097,152
  // total 23,117,824 f32 = 92.5 MB

  u16* xb   = (u16*)obuf;      // x bf16 (dead after gemm1)
  u16* wqt  = (u16*)Wtg;       // w_qkvz^T bf16, spans Wtg..Ug (dead after gemm1)
  u16* Mhi  = (u16*)qkvc;      // 4,194,304 u16
  u16* Mlo  = (u16*)(qkvc + 2097152);
  float* Bg = qkvraw;
  float* Sg = Wtg;             // spans Wtg+pQg
  u16* wot  = (u16*)qkvc;      // after scan_S (Mhi dead)
  u16* hb   = (u16*)khat;      // after make_MBG (khat dead)

  // 0) casts
  cast_bf16<<<1024, 256, 0, stream>>>(x, xb, 262144);
  transpose_bf16<<<dim3(32, 96), 256, 0, stream>>>(w_qkvz, wqt, H_, QN_);
  // 1) qkv|z = x @ w_qkvz   (split outputs)
  gemm_bf16<<<dim3(8, 48), 256, 0, stream>>>(xb, wqt, qkvraw, CD_, zbuf, VD_,
                                             CD_, T_, QN_, H_);
  // 2) beta / g
  ba_gbeta<<<T_, 128, 0, stream>>>(x, w_ba, a_log, dt_bias, gbuf, bbuf);
  // 3) conv + silu on q|k|v
  conv_silu<<<dim3(CD_ / 256, T_), 256, 0, stream>>>(qkvraw, conv_w, conv_b, qkvc);
  // 4) k l2norm
  k_prep<<<dim3(T_, HK_), 128, 0, stream>>>(qkvc, khat);
  // 5) chunk-local precompute (parallel)
  chunk_prep<<<dim3(NC_, HV_), 256, 0, stream>>>(
      qkvc, khat, gbuf, bbuf, cgbuf, Wtg, Ug, Mqg, pQg);
  // 6) per-chunk transition/output operators (parallel)
  make_MBG<<<dim3(NC_, HV_), 256, 0, stream>>>(
      Wtg, pQg, Ug, Mqg, khat, cgbuf, Mhi, Mlo, Bg, Gtg);
  // 7) sequential state scan (col-sliced, XCD-grouped, reg-prefetched)
  scan_S<<<64, 256, 0, stream>>>(Mhi, Mlo, Bg, Sg);
  // 8) w_o^T cast (Mhi region now dead)
  transpose_bf16<<<dim3(32, 32), 256, 0, stream>>>(w_o, wot, VD_, H_);
  // 9) per-chunk outputs (parallel)
  chunk_out<<<dim3(NC_, HV_), 256, 0, stream>>>(Mqg, Ug, Gtg, Sg, obuf);
  // 10) gated rmsnorm -> bf16 h
  gated_rmsnorm<<<dim3(T_, HV_), 128, 0, stream>>>(obuf, zbuf, norm_w, hb);
  // 11) out = h @ w_o
  gemm_bf16<<<dim3(8, 16), 256, 0, stream>>>(hb, wot, out, VD_, out, VD_,
                                             VD_, T_, VD_, H_);
}

// Round 6
// 290.168 us; speedup vs baseline: 4.6428x; 1.0723x over previous
//
#include <hip/hip_runtime.h>
#include <math.h>

typedef unsigned short u16;
using us4  = __attribute__((ext_vector_type(4))) unsigned short;
using us8  = __attribute__((ext_vector_type(8))) unsigned short;
using bf16x8 = __attribute__((ext_vector_type(8))) __bf16;
using f32x4v = __attribute__((ext_vector_type(4))) float;

// Problem constants
#define T_    1024
#define H_    2048
#define HK_   8
#define HV_   16
#define KD_   1024
#define VD_   2048
#define CD_   4096
#define QN_   6144   // 2*KD + 2*VD
#define NC_   16     // number of chunks
#define C_    64     // chunk length

__device__ __forceinline__ u16 f2bf(float f) {
  unsigned u = __float_as_uint(f);
  u += 0x7fffu + ((u >> 16) & 1u);   // RNE
  return (u16)(u >> 16);
}
__device__ __forceinline__ float bf2f(u16 h) {
  return __uint_as_float(((unsigned)h) << 16);
}
// bank-conflict-free staging layout: within each 32-elem k-group, 8-elem
// chunk c of row r is stored at chunk position c ^ ((r>>1)&3).
__device__ __forceinline__ int permk(int r, int k) {
  return (k & ~31) | ((((k >> 3) & 3) ^ ((r >> 1) & 3)) << 3) | (k & 7);
}

// ---------------------------------------------------------------------------
// x f32 -> bf16 with chunk permutation (row length 2048)
// ---------------------------------------------------------------------------
__global__ void cast_bf16(const float* __restrict__ in, u16* __restrict__ out,
                          int n8) {
  int i = blockIdx.x * 256 + threadIdx.x;   // 16B-chunk index
  if (i >= n8) return;
  float4 a = ((const float4*)in)[i * 2];
  float4 b = ((const float4*)in)[i * 2 + 1];
  us8 r = {f2bf(a.x), f2bf(a.y), f2bf(a.z), f2bf(a.w),
           f2bf(b.x), f2bf(b.y), f2bf(b.z), f2bf(b.w)};
  const int row = i >> 8;                   // 2048/8 = 256 chunks per row
  const int ip = (i & ~3) | ((i & 3) ^ ((row >> 1) & 3));
  *(us8*)&out[(size_t)ip * 8] = r;
}

// ---------------------------------------------------------------------------
// f32 [R][C] -> bf16 [C][R] transpose + cast + chunk permutation
// ---------------------------------------------------------------------------
__global__ __launch_bounds__(256) void transpose_bf16(
    const float* __restrict__ in, u16* __restrict__ out, int R, int C) {
  __shared__ float tile[64][65];
  const int r0 = blockIdx.x * 64, c0 = blockIdx.y * 64;
  const int t = threadIdx.x;
  const int tr = t >> 4, tc4 = (t & 15) * 4;
#pragma unroll
  for (int i = 0; i < 4; ++i) {
    float4 v = *(const float4*)&in[(size_t)(r0 + tr + i * 16) * C + c0 + tc4];
    tile[tr + i * 16][tc4 + 0] = v.x;
    tile[tr + i * 16][tc4 + 1] = v.y;
    tile[tr + i * 16][tc4 + 2] = v.z;
    tile[tr + i * 16][tc4 + 3] = v.w;
  }
  __syncthreads();
#pragma unroll
  for (int i = 0; i < 4; ++i) {
    int oc = tr + i * 16;
    int row = c0 + oc;
    int k = r0 + tc4;
    us4 w = {f2bf(tile[tc4 + 0][oc]), f2bf(tile[tc4 + 1][oc]),
             f2bf(tile[tc4 + 2][oc]), f2bf(tile[tc4 + 3][oc])};
    *(us4*)&out[(size_t)row * R + permk(row, k)] = w;
  }
}

// ---------------------------------------------------------------------------
// bf16 MFMA GEMM: C = A[M,K] @ Bt[N,K]^T, f32 out. 128x64 tile, BK=32,
// 4 waves (2x2 of 64x32), XCD-grouped 1D block mapping, permuted staging.
// Output routed to Cq (cols < zsplit) or Cz.
// ---------------------------------------------------------------------------
__device__ __forceinline__ void gload_lds16(const void* g, void* l) {
  __builtin_amdgcn_global_load_lds(
      (const __attribute__((address_space(1))) void*)g,
      (__attribute__((address_space(3))) void*)l, 16, 0, 0);
}

__global__ __launch_bounds__(256) void gemm_bf16(
    const u16* __restrict__ A, const u16* __restrict__ Bt,
    float* __restrict__ Cq, int ldq, float* __restrict__ Cz, int ldz,
    int zsplit, int M, int N, int K) {
  __shared__ __align__(16) u16 As[4096];   // [128][32]
  __shared__ __align__(16) u16 Bs[2048];   // [64][32]
  const int tid  = threadIdx.x;
  const int wave = tid >> 6, lane = tid & 63;
  // XCD-grouped mapping: blocks bid%8==x land on XCD x (round-robin dispatch);
  // each XCD owns gy/8 contiguous col-panels, row sweeps slowest.
  const int gy = N >> 6;
  const int ncolpx = gy >> 3;
  const int bid = blockIdx.x;
  const int xcd = bid & 7, idx = bid >> 3;
  const int row0 = (idx / ncolpx) * 128;
  const int col0 = (xcd * ncolpx + idx % ncolpx) * 64;
  const int wr = wave >> 1, wc = wave & 1;
  const int fr = lane & 15, fq = lane >> 4;
  const int ch8 = (fq ^ ((fr >> 1) & 3)) << 3;   // permuted chunk offset

  const int srow = wave * 16 + (lane >> 2);
  const int scol = (lane & 3) * 8;
  const u16* gA0 = A  + (size_t)(row0 + srow) * K + scol;
  const u16* gA1 = gA0 + (size_t)64 * K;
  const u16* gB0 = Bt + (size_t)(col0 + srow) * K + scol;
  u16* lA0 = &As[wave * 512];
  u16* lA1 = &As[2048 + wave * 512];
  u16* lB0 = &Bs[wave * 512];

  f32x4v acc[4][2] = {};

  for (int k0 = 0; k0 < K; k0 += 32) {
    __syncthreads();
    gload_lds16(gA0 + k0, lA0);
    gload_lds16(gA1 + k0, lA1);
    gload_lds16(gB0 + k0, lB0);
    asm volatile("s_waitcnt vmcnt(0)" ::: "memory");
    __syncthreads();

    bf16x8 af[4], bff[2];
#pragma unroll
    for (int mi = 0; mi < 4; ++mi)
      af[mi] = *(const bf16x8*)&As[(wr * 64 + mi * 16 + fr) * 32 + ch8];
#pragma unroll
    for (int ni = 0; ni < 2; ++ni)
      bff[ni] = *(const bf16x8*)&Bs[(wc * 32 + ni * 16 + fr) * 32 + ch8];
#pragma unroll
    for (int mi = 0; mi < 4; ++mi)
#pragma unroll
      for (int ni = 0; ni < 2; ++ni)
        acc[mi][ni] = __builtin_amdgcn_mfma_f32_16x16x32_bf16(
            af[mi], bff[ni], acc[mi][ni], 0, 0, 0);
  }

  float* Cp; int ldc, cb;
  if (col0 < zsplit) { Cp = Cq; ldc = ldq; cb = col0; }
  else               { Cp = Cz; ldc = ldz; cb = col0 - zsplit; }
#pragma unroll
  for (int mi = 0; mi < 4; ++mi)
#pragma unroll
    for (int ni = 0; ni < 2; ++ni) {
      const int r  = row0 + wr * 64 + mi * 16 + fq * 4;
      const int cc = cb + wc * 32 + ni * 16 + fr;
#pragma unroll
      for (int j = 0; j < 4; ++j)
        Cp[(size_t)(r + j) * ldc + cc] = acc[mi][ni][j];
    }
}

// ---------------------------------------------------------------------------
// ba = x @ w_ba -> beta = sigmoid(b), g = -exp(a_log)*softplus(a+dt_bias)
// ---------------------------------------------------------------------------
__global__ void ba_gbeta(const float* __restrict__ x,
                         const float* __restrict__ w_ba,
                         const float* __restrict__ a_log,
                         const float* __restrict__ dt_bias,
                         float* __restrict__ g, float* __restrict__ beta) {
  const int t = blockIdx.x;
  const int tid = threadIdx.x;      // 128
  const int c = tid & 31;
  const int chunk = tid >> 5;
  const float* xr = x + (size_t)t * H_;
  float p = 0.f;
  const int kb = chunk * 512;
  for (int k = kb; k < kb + 512; ++k) p = fmaf(xr[k], w_ba[k * 32 + c], p);
  __shared__ float red[4][32];
  red[chunk][c] = p;
  __syncthreads();
  if (tid < 32) {
    float s = red[0][c] + red[1][c] + red[2][c] + red[3][c];
    if (c < 16) {
      beta[t * 16 + c] = 1.f / (1.f + expf(-s));
    } else {
      int h = c - 16;
      float xx = s + dt_bias[h];
      float sp = xx > 20.f ? xx : log1pf(expf(xx));
      g[t * 16 + h] = -expf(a_log[h]) * sp;
    }
  }
}

// ---------------------------------------------------------------------------
// fused causal depthwise conv1d (K=4) + SiLU + k-l2norm.
// 512 threads/block, 1 block per t. Thread owns 8 channels.
// q (c<1024) and v (c>=2048) -> qkvc ; k (1024..2047) -> khat (normalized).
// ---------------------------------------------------------------------------
__global__ __launch_bounds__(512) void conv_silu_k(
    const float* __restrict__ qkvraw, const float* __restrict__ conv_w,
    const float* __restrict__ conv_b, float* __restrict__ qkvc,
    float* __restrict__ khat) {
  const int t = blockIdx.x;
  const int tid = threadIdx.x;
  const int c0 = tid * 8;
  float acc[8];
  float4 cb0 = *(const float4*)&conv_b[c0];
  float4 cb1 = *(const float4*)&conv_b[c0 + 4];
  acc[0] = cb0.x; acc[1] = cb0.y; acc[2] = cb0.z; acc[3] = cb0.w;
  acc[4] = cb1.x; acc[5] = cb1.y; acc[6] = cb1.z; acc[7] = cb1.w;
  float wv[8][4];
#pragma unroll
  for (int i = 0; i < 8; i += 2) {
    float4 w0 = *(const float4*)&conv_w[(c0 + i) * 4];
    float4 w1 = *(const float4*)&conv_w[(c0 + i + 1) * 4];
    wv[i][0] = w0.x; wv[i][1] = w0.y; wv[i][2] = w0.z; wv[i][3] = w0.w;
    wv[i+1][0] = w1.x; wv[i+1][1] = w1.y; wv[i+1][2] = w1.z; wv[i+1][3] = w1.w;
  }
#pragma unroll
  for (int j = 0; j < 4; ++j) {
    int tt = t - 3 + j;
    if (tt >= 0) {
      float4 a = *(const float4*)&qkvraw[(size_t)tt * CD_ + c0];
      float4 b = *(const float4*)&qkvraw[(size_t)tt * CD_ + c0 + 4];
      float xv[8] = {a.x, a.y, a.z, a.w, b.x, b.y, b.z, b.w};
#pragma unroll
      for (int i = 0; i < 8; ++i) acc[i] = fmaf(xv[i], wv[i][j], acc[i]);
    }
  }
  float y[8];
#pragma unroll
  for (int i = 0; i < 8; ++i) y[i] = acc[i] / (1.f + expf(-acc[i]));

  if (tid < 128 || tid >= 256) {
    float4 o0 = {y[0], y[1], y[2], y[3]};
    float4 o1 = {y[4], y[5], y[6], y[7]};
    *(float4*)&qkvc[(size_t)t * CD_ + c0]     = o0;
    *(float4*)&qkvc[(size_t)t * CD_ + c0 + 4] = o1;
  } else {
    float ss = 0.f;
#pragma unroll
    for (int i = 0; i < 8; ++i) ss = fmaf(y[i], y[i], ss);
#pragma unroll
    for (int off = 1; off < 16; off <<= 1) ss += __shfl_xor(ss, off);
    float rs = rsqrtf(ss + 1e-6f);
    const int head = (c0 - 1024) >> 7;
    const int d0 = (c0 - 1024) & 127;
    float4 o0 = {y[0] * rs, y[1] * rs, y[2] * rs, y[3] * rs};
    float4 o1 = {y[4] * rs, y[5] * rs, y[6] * rs, y[7] * rs};
    float* kout = &khat[((size_t)t * HK_ + head) * 128 + d0];
    *(float4*)&kout[0] = o0;
    *(float4*)&kout[4] = o1;
  }
}

// ---------------------------------------------------------------------------
// Chunked gated delta rule, phase A (parallel over 16 chunks x 16 heads).
// ---------------------------------------------------------------------------
#define SWZ(r) (((r) >> 2) & 7)

__device__ __forceinline__ float4 ldsw4(const float* base, int r, int dblk) {
  return *(const float4*)&base[r * 128 + ((dblk ^ SWZ(r)) << 2)];
}
__device__ __forceinline__ float ldsw1(const float* base, int r, int d) {
  return base[r * 128 + ((((d) >> 2) ^ SWZ(r)) << 2) + ((d) & 3)];
}

__global__ __launch_bounds__(256) void chunk_prep(
    const float* __restrict__ qkvc, const float* __restrict__ khat,
    const float* __restrict__ g, const float* __restrict__ beta,
    float* __restrict__ cgbuf, float* __restrict__ Wtg, float* __restrict__ Ug,
    float* __restrict__ Mqg, float* __restrict__ pQg) {
  const int c = blockIdx.x, hv = blockIdx.y, hk = hv >> 1;
  const int cid = c * 16 + hv;
  const int tid = threadIdx.x;
  __shared__ float Kl[8192], Ql[8192];   // swizzled [64][128]
  __shared__ float AM[8320];             // At[64][65] | Mq[64][65]; later Utr
  __shared__ float cgl[64], bl[64], bp[64], rsl[64];
  float* At = AM;
  float* Mq = AM + 4160;

#pragma unroll
  for (int it = 0; it < 8; ++it) {
    int flat = it * 1024 + tid * 4;
    int row = flat >> 7, d = flat & 127;
    int pb = ((d >> 2) ^ SWZ(row)) << 2;
    int gt = c * 64 + row;
    float4 kv = *(const float4*)&khat[((size_t)gt * HK_ + hk) * 128 + d];
    float4 qv = *(const float4*)&qkvc[(size_t)gt * CD_ + hk * 128 + d];
    *(float4*)&Kl[row * 128 + pb] = kv;
    *(float4*)&Ql[row * 128 + pb] = qv;
  }
  if (tid < 64) {
    float s = g[(size_t)(c * 64 + tid) * HV_ + hv];
#pragma unroll
    for (int off = 1; off < 64; off <<= 1) {
      float t = __shfl_up(s, off);
      if (tid >= off) s += t;
    }
    cgl[tid] = s;
    cgbuf[cid * 64 + tid] = s;
    bl[tid] = beta[(size_t)(c * 64 + tid) * HV_ + hv];
  }
  __syncthreads();
  if (tid < 64) {
    float sq = 0.f;
#pragma unroll
    for (int dblk = 0; dblk < 32; ++dblk) {
      float4 q4 = ldsw4(Ql, tid, dblk);
      sq = fmaf(q4.x, q4.x, sq); sq = fmaf(q4.y, q4.y, sq);
      sq = fmaf(q4.z, q4.z, sq); sq = fmaf(q4.w, q4.w, sq);
    }
    rsl[tid] = rsqrtf(sq + 1e-6f) * 0.08838834764831845f;
    bp[tid] = bl[tid] * expf(cgl[tid]);
  }
  __syncthreads();

  const int i0 = (tid >> 4) * 4, j0 = (tid & 15) * 4;
  float kk[4][4], qk[4][4];
#pragma unroll
  for (int a = 0; a < 4; ++a)
#pragma unroll
    for (int b = 0; b < 4; ++b) { kk[a][b] = 0.f; qk[a][b] = 0.f; }
  for (int dblk = 0; dblk < 32; ++dblk) {
    float4 ka[4], qa[4], kb[4];
#pragma unroll
    for (int a = 0; a < 4; ++a) {
      ka[a] = ldsw4(Kl, i0 + a, dblk);
      qa[a] = ldsw4(Ql, i0 + a, dblk);
    }
#pragma unroll
    for (int b = 0; b < 4; ++b) kb[b] = ldsw4(Kl, j0 + b, dblk);
#pragma unroll
    for (int a = 0; a < 4; ++a)
#pragma unroll
      for (int b = 0; b < 4; ++b) {
        kk[a][b] = fmaf(ka[a].x, kb[b].x, kk[a][b]);
        kk[a][b] = fmaf(ka[a].y, kb[b].y, kk[a][b]);
        kk[a][b] = fmaf(ka[a].z, kb[b].z, kk[a][b]);
        kk[a][b] = fmaf(ka[a].w, kb[b].w, kk[a][b]);
        qk[a][b] = fmaf(qa[a].x, kb[b].x, qk[a][b]);
        qk[a][b] = fmaf(qa[a].y, kb[b].y, qk[a][b]);
        qk[a][b] = fmaf(qa[a].z, kb[b].z, qk[a][b]);
        qk[a][b] = fmaf(qa[a].w, kb[b].w, qk[a][b]);
      }
  }
#pragma unroll
  for (int a = 0; a < 4; ++a)
#pragma unroll
    for (int b = 0; b < 4; ++b) {
      int i = i0 + a, j = j0 + b;
      float e = expf(cgl[i] - cgl[j]);
      At[j * 65 + i] = (j < i) ? (-bl[i] * e * kk[a][b]) : 0.f;
      Mq[j * 65 + i] = (j <= i) ? (rsl[i] * e * qk[a][b]) : 0.f;
    }
  __syncthreads();

  float X[64];
  if (tid < 128) {
#pragma unroll
    for (int j = 0; j < 64; ++j) X[j] = bp[j] * ldsw1(Kl, j, tid);
  } else {
    const int m = tid - 128;
#pragma unroll
    for (int j = 0; j < 64; ++j)
      X[j] = bl[j] * qkvc[(size_t)(c * 64 + j) * CD_ + 2 * KD_ + hv * 128 + m];
  }
#pragma unroll
  for (int it = 0; it < 16; ++it) {
    int f = it * 256 + tid;
    int j = f >> 6, i = f & 63;
    Mqg[(size_t)cid * 4096 + f] = Mq[j * 65 + i];
  }
#pragma unroll
  for (int j = 0; j < 63; ++j) {
    float xj = X[j];
#pragma unroll
    for (int i = j + 1; i < 64; ++i) X[i] = fmaf(At[j * 65 + i], xj, X[i]);
  }
  __syncthreads();

  if (tid < 128) {
    size_t baseo = ((size_t)cid * 128 + tid) * 64;
#pragma unroll
    for (int j4 = 0; j4 < 16; ++j4) {
      float4 v = {X[j4 * 4], X[j4 * 4 + 1], X[j4 * 4 + 2], X[j4 * 4 + 3]};
      *(float4*)&Wtg[baseo + j4 * 4] = v;
    }
  } else {
    const int m = tid - 128;
    float* Utr = AM;
#pragma unroll
    for (int j = 0; j < 64; ++j) Utr[j * 128 + m] = X[j];
  }
  __syncthreads();
  {
    const float* Utr = AM;
#pragma unroll
    for (int it = 0; it < 8; ++it) {
      int flat = it * 1024 + tid * 4;
      *(float4*)&Ug[(size_t)cid * 8192 + flat] = *(const float4*)&Utr[flat];
    }
    const int i = tid & 63;
    const float ei = expf(cgl[i]) * rsl[i];
#pragma unroll
    for (int it = 0; it < 32; ++it) {
      int d = it * 4 + (tid >> 6);
      pQg[(size_t)cid * 8192 + d * 64 + i] = ei * ldsw1(Ql, i, d);
    }
  }
}

// ---------------------------------------------------------------------------
// make_MBG (parallel, 256 blocks)
// ---------------------------------------------------------------------------
__global__ __launch_bounds__(256) void make_MBG(
    const float* __restrict__ Wtg, const float* __restrict__ pQg,
    const float* __restrict__ Ug, const float* __restrict__ Mqg,
    const float* __restrict__ khat, const float* __restrict__ cgbuf,
    u16* __restrict__ Mhi, u16* __restrict__ Mlo,
    float* __restrict__ Bg, float* __restrict__ Gtg) {
  const int c = blockIdx.x, hv = blockIdx.y, hk = hv >> 1;
  const int cid = c * 16 + hv;
  const int tid = threadIdx.x;
  __shared__ float Wl[64 * 128];   // W[j][d]
  __shared__ float Kel[64 * 128];  // esc_j * khat_j[d]
  __shared__ float Ul[64 * 128];
  __shared__ float Mql[64 * 64];
  const float cg63 = cgbuf[cid * 64 + 63];
  const float pC = expf(cg63);
#pragma unroll
  for (int it = 0; it < 8; ++it) {
    int f = it * 1024 + tid * 4;       // f = d*64 + j
    int d = f >> 6, j = f & 63;
    float4 w = *(const float4*)&Wtg[(size_t)cid * 8192 + f];
    Wl[(j + 0) * 128 + d] = w.x;
    Wl[(j + 1) * 128 + d] = w.y;
    Wl[(j + 2) * 128 + d] = w.z;
    Wl[(j + 3) * 128 + d] = w.w;
  }
#pragma unroll
  for (int it = 0; it < 8; ++it) {
    int f = it * 1024 + tid * 4;       // f = j*128 + d
    int j = f >> 7, d = f & 127;
    float esc = expf(cg63 - cgbuf[cid * 64 + j]);
    float4 kv = *(const float4*)&khat[((size_t)(c * 64 + j) * HK_ + hk) * 128 + d];
    float4 uv = *(const float4*)&Ug[(size_t)cid * 8192 + f];
    kv.x *= esc; kv.y *= esc; kv.z *= esc; kv.w *= esc;
    *(float4*)&Kel[f] = kv;
    *(float4*)&Ul[f] = uv;
  }
#pragma unroll
  for (int it = 0; it < 4; ++it) {
    int f = it * 1024 + tid * 4;
    *(float4*)&Mql[f] = *(const float4*)&Mqg[(size_t)cid * 4096 + f];
  }
  __syncthreads();

  const int d0 = (tid & 15) * 8, n0 = (tid >> 4) * 8;
  float ma[8][8] = {}, ba[8][8] = {};
  for (int j = 0; j < 64; ++j) {
    float4 k0 = *(const float4*)&Kel[j * 128 + d0];
    float4 k1 = *(const float4*)&Kel[j * 128 + d0 + 4];
    float4 w0 = *(const float4*)&Wl[j * 128 + n0];
    float4 w1 = *(const float4*)&Wl[j * 128 + n0 + 4];
    float4 u0 = *(const float4*)&Ul[j * 128 + n0];
    float4 u1 = *(const float4*)&Ul[j * 128 + n0 + 4];
    float ke[8] = {k0.x, k0.y, k0.z, k0.w, k1.x, k1.y, k1.z, k1.w};
    float wv[8] = {w0.x, w0.y, w0.z, w0.w, w1.x, w1.y, w1.z, w1.w};
    float uv[8] = {u0.x, u0.y, u0.z, u0.w, u1.x, u1.y, u1.z, u1.w};
#pragma unroll
    for (int a = 0; a < 8; ++a)
#pragma unroll
      for (int b = 0; b < 8; ++b) {
        ma[a][b] = fmaf(ke[a], wv[b], ma[a][b]);
        ba[a][b] = fmaf(ke[a], uv[b], ba[a][b]);
      }
  }
#pragma unroll
  for (int a = 0; a < 8; ++a) {
    const int d = d0 + a;
    us8 hi, lo;
#pragma unroll
    for (int b = 0; b < 8; ++b) {
      float m = ((d == n0 + b) ? pC : 0.f) - ma[a][b];
      u16 h = f2bf(m);
      hi[b] = h;
      lo[b] = f2bf(m - bf2f(h));
    }
    *(us8*)&Mhi[(size_t)cid * 16384 + d * 128 + n0] = hi;
    *(us8*)&Mlo[(size_t)cid * 16384 + d * 128 + n0] = lo;
    float4 b0 = {ba[a][0], ba[a][1], ba[a][2], ba[a][3]};
    float4 b1 = {ba[a][4], ba[a][5], ba[a][6], ba[a][7]};
    *(float4*)&Bg[(size_t)cid * 16384 + d * 128 + n0]     = b0;
    *(float4*)&Bg[(size_t)cid * 16384 + d * 128 + n0 + 4] = b1;
  }

  const int dg = (tid & 31) * 4, ig = (tid >> 5) * 8;
  float ga[4][8] = {};
  for (int j = 0; j < 64; ++j) {
    float4 w4 = *(const float4*)&Wl[j * 128 + dg];
    float4 m0 = *(const float4*)&Mql[j * 64 + ig];
    float4 m1 = *(const float4*)&Mql[j * 64 + ig + 4];
    float wv[4] = {w4.x, w4.y, w4.z, w4.w};
    float mv[8] = {m0.x, m0.y, m0.z, m0.w, m1.x, m1.y, m1.z, m1.w};
#pragma unroll
    for (int a = 0; a < 4; ++a)
#pragma unroll
      for (int b = 0; b < 8; ++b) ga[a][b] = fmaf(wv[a], mv[b], ga[a][b]);
  }
#pragma unroll
  for (int a = 0; a < 4; ++a) {
    const int d = dg + a;
    float4 p0 = *(const float4*)&pQg[(size_t)cid * 8192 + d * 64 + ig];
    float4 p1 = *(const float4*)&pQg[(size_t)cid * 8192 + d * 64 + ig + 4];
    float4 g0 = {p0.x - ga[a][0], p0.y - ga[a][1], p0.z - ga[a][2], p0.w - ga[a][3]};
    float4 g1 = {p1.x - ga[a][4], p1.y - ga[a][5], p1.z - ga[a][6], p1.w - ga[a][7]};
    *(float4*)&Gtg[(size_t)cid * 8192 + d * 64 + ig]     = g0;
    *(float4*)&Gtg[(size_t)cid * 8192 + d * 64 + ig + 4] = g1;
  }
}

// ---------------------------------------------------------------------------
// scan_S: 64 blocks = 16 heads x 4 col-slices, XCD-grouped.
// ---------------------------------------------------------------------------
__global__ __launch_bounds__(256) void scan_S(
    const u16* __restrict__ Mhi, const u16* __restrict__ Mlo,
    const float* __restrict__ Bg, float* __restrict__ Sg) {
  const int flat = blockIdx.x;
  const int hv = (flat & 7) + 8 * (flat >> 5);
  const int vs = (flat >> 3) & 3;
  const int tid = threadIdx.x;
  const int wave = tid >> 6, lane = tid & 63;
  const int fr = lane & 15, fq = lane >> 4;
  const int wr = wave * 32;
  const int m0 = vs * 32;

  __shared__ u16 Sh[2][4096];
  __shared__ u16 Sl[2][4096];

  for (int i = tid; i < 4096; i += 256) { Sh[0][i] = 0; Sl[0][i] = 0; }
  {
    float* s0 = Sg + (size_t)hv * 16384 + m0;
#pragma unroll
    for (int it = 0; it < 16; ++it) {
      int idx = it * 256 + tid;
      s0[(size_t)(idx >> 5) * 128 + (idx & 31)] = 0.f;
    }
  }
  __syncthreads();

  bf16x8 MhA[2][4], MlA[2][4], MhB[2][4], MlB[2][4];
  {
    const u16* Mh0 = Mhi + (size_t)hv * 16384;
    const u16* Ml0 = Mlo + (size_t)hv * 16384;
#pragma unroll
    for (int a = 0; a < 2; ++a)
#pragma unroll
      for (int kt = 0; kt < 4; ++kt) {
        size_t off = (size_t)(wr + a * 16 + fr) * 128 + kt * 32 + fq * 8;
        MhA[a][kt] = *(const bf16x8*)&Mh0[off];
        MlA[a][kt] = *(const bf16x8*)&Ml0[off];
      }
  }
  int p = 0;

  auto step = [&](int c, bf16x8 (&MhC)[2][4], bf16x8 (&MlC)[2][4],
                  bf16x8 (&MhN)[2][4], bf16x8 (&MlN)[2][4]) {
    if (c + 1 < NC_ - 1) {
      const u16* MhP = Mhi + (size_t)((c + 1) * 16 + hv) * 16384;
      const u16* MlP = Mlo + (size_t)((c + 1) * 16 + hv) * 16384;
#pragma unroll
      for (int a = 0; a < 2; ++a)
#pragma unroll
        for (int kt = 0; kt < 4; ++kt) {
          size_t off = (size_t)(wr + a * 16 + fr) * 128 + kt * 32 + fq * 8;
          MhN[a][kt] = *(const bf16x8*)&MhP[off];
          MlN[a][kt] = *(const bf16x8*)&MlP[off];
        }
    }
    const float* Bc = Bg + (size_t)(c * 16 + hv) * 16384 + m0;
    float bv[2][2][4];
#pragma unroll
    for (int a = 0; a < 2; ++a)
#pragma unroll
      for (int b = 0; b < 2; ++b)
#pragma unroll
        for (int j = 0; j < 4; ++j)
          bv[a][b][j] =
              Bc[(size_t)(wr + a * 16 + fq * 4 + j) * 128 + b * 16 + fr];

    f32x4v acc[2][2] = {};
#pragma unroll
    for (int kt = 0; kt < 4; ++kt) {
      bf16x8 Bh[2], Bl[2];
#pragma unroll
      for (int b = 0; b < 2; ++b) {
        int m = b * 16 + fr;
        int byte = m * 256 + ((kt * 64 + fq * 16) ^ ((m & 7) << 4));
        Bh[b] = *(const bf16x8*)((const char*)&Sh[p][0] + byte);
        Bl[b] = *(const bf16x8*)((const char*)&Sl[p][0] + byte);
      }
#pragma unroll
      for (int a = 0; a < 2; ++a)
#pragma unroll
        for (int b = 0; b < 2; ++b) {
          acc[a][b] = __builtin_amdgcn_mfma_f32_16x16x32_bf16(
              MlC[a][kt], Bh[b], acc[a][b], 0, 0, 0);
          acc[a][b] = __builtin_amdgcn_mfma_f32_16x16x32_bf16(
              MhC[a][kt], Bl[b], acc[a][b], 0, 0, 0);
          acc[a][b] = __builtin_amdgcn_mfma_f32_16x16x32_bf16(
              MhC[a][kt], Bh[b], acc[a][b], 0, 0, 0);
        }
    }
    float* Sn = Sg + (size_t)((c + 1) * 16 + hv) * 16384 + m0;
#pragma unroll
    for (int a = 0; a < 2; ++a)
#pragma unroll
      for (int b = 0; b < 2; ++b) {
        const int k0 = wr + a * 16 + fq * 4;
        const int m = b * 16 + fr;
        us4 h4, l4;
#pragma unroll
        for (int j = 0; j < 4; ++j) {
          float v = acc[a][b][j] + bv[a][b][j];
          Sn[(size_t)(k0 + j) * 128 + m] = v;
          u16 h = f2bf(v);
          h4[j] = h;
          l4[j] = f2bf(v - bf2f(h));
        }
        int byte = m * 256 + (((k0 * 2)) ^ ((m & 7) << 4));
        *(us4*)((char*)&Sh[p ^ 1][0] + byte) = h4;
        *(us4*)((char*)&Sl[p ^ 1][0] + byte) = l4;
      }
    __syncthreads();
    p ^= 1;
  };

  for (int cc = 0; cc < NC_ - 1; cc += 2) {
    step(cc, MhA, MlA, MhB, MlB);
    if (cc + 1 < NC_ - 1) step(cc + 1, MhB, MlB, MhA, MlA);
  }
}

// ---------------------------------------------------------------------------
// chunk_out (parallel, 256 blocks): o = Mq^T U + G*S
// ---------------------------------------------------------------------------
__global__ __launch_bounds__(256) void chunk_out(
    const float* __restrict__ Mqg, const float* __restrict__ Ug,
    const float* __restrict__ Gtg, const float* __restrict__ Sg,
    float* __restrict__ o) {
  const int c = blockIdx.x, hv = blockIdx.y;
  const int cid = c * 16 + hv;
  const int tid = threadIdx.x;
  __shared__ float Mql[64 * 64];
  __shared__ float Ul[64 * 128];
  __shared__ float Gtl[128 * 64];
  __shared__ float Sl[128 * 128];
#pragma unroll
  for (int it = 0; it < 4; ++it) {
    int f = it * 1024 + tid * 4;
    *(float4*)&Mql[f] = *(const float4*)&Mqg[(size_t)cid * 4096 + f];
  }
#pragma unroll
  for (int it = 0; it < 8; ++it) {
    int f = it * 1024 + tid * 4;
    *(float4*)&Ul[f]  = *(const float4*)&Ug[(size_t)cid * 8192 + f];
    *(float4*)&Gtl[f] = *(const float4*)&Gtg[(size_t)cid * 8192 + f];
  }
#pragma unroll
  for (int it = 0; it < 16; ++it) {
    int f = it * 1024 + tid * 4;
    *(float4*)&Sl[f] = *(const float4*)&Sg[(size_t)cid * 16384 + f];
  }
  __syncthreads();

  const int i0 = (tid & 15) * 4, m0 = (tid >> 4) * 8;
  float oa[4][8] = {};
  for (int j = 0; j < 64; ++j) {
    float4 mq = *(const float4*)&Mql[j * 64 + i0];
    float4 u0 = *(const float4*)&Ul[j * 128 + m0];
    float4 u1 = *(const float4*)&Ul[j * 128 + m0 + 4];
    float mv[4] = {mq.x, mq.y, mq.z, mq.w};
    float uv[8] = {u0.x, u0.y, u0.z, u0.w, u1.x, u1.y, u1.z, u1.w};
#pragma unroll
    for (int a = 0; a < 4; ++a)
#pragma unroll
      for (int b = 0; b < 8; ++b) oa[a][b] = fmaf(mv[a], uv[b], oa[a][b]);
  }
  for (int d = 0; d < 128; ++d) {
    float4 gt = *(const float4*)&Gtl[d * 64 + i0];
    float4 s0 = *(const float4*)&Sl[d * 128 + m0];
    float4 s1 = *(const float4*)&Sl[d * 128 + m0 + 4];
    float gv[4] = {gt.x, gt.y, gt.z, gt.w};
    float sv[8] = {s0.x, s0.y, s0.z, s0.w, s1.x, s1.y, s1.z, s1.w};
#pragma unroll
    for (int a = 0; a < 4; ++a)
#pragma unroll
      for (int b = 0; b < 8; ++b) oa[a][b] = fmaf(gv[a], sv[b], oa[a][b]);
  }
#pragma unroll
  for (int a = 0; a < 4; ++a) {
    const int t = c * 64 + i0 + a;
    float4 o0 = {oa[a][0], oa[a][1], oa[a][2], oa[a][3]};
    float4 o1 = {oa[a][4], oa[a][5], oa[a][6], oa[a][7]};
    *(float4*)&o[((size_t)t * HV_ + hv) * 128 + m0]     = o0;
    *(float4*)&o[((size_t)t * HV_ + hv) * 128 + m0 + 4] = o1;
  }
}

// ---------------------------------------------------------------------------
// h = o * silu(z); rmsnorm; -> bf16 (permuted staging layout for gemm2)
// ---------------------------------------------------------------------------
__global__ void gated_rmsnorm(const float* __restrict__ o,
                              const float* __restrict__ zbuf,
                              const float* __restrict__ norm_w,
                              u16* __restrict__ h) {
  const int t = blockIdx.x, hv = blockIdx.y, d = threadIdx.x;
  float ov = o[((size_t)t * HV_ + hv) * 128 + d];
  float zv = zbuf[(size_t)t * VD_ + hv * 128 + d];
  float hc = ov * (zv / (1.f + expf(-zv)));
  float ss = hc * hc;
#pragma unroll
  for (int off = 32; off >= 1; off >>= 1) ss += __shfl_xor(ss, off);
  __shared__ float s2[2];
  if ((d & 63) == 0) s2[d >> 6] = ss;
  __syncthreads();
  float tot = s2[0] + s2[1];
  float r = rsqrtf(tot * (1.f / 128.f) + 1e-6f);
  const int k = hv * 128 + d;
  h[(size_t)t * VD_ + permk(t, k)] = f2bf(hc * r * norm_w[d]);
}

// ---------------------------------------------------------------------------
extern "C" void kernel_launch(void* const* d_in, const int* in_sizes, int n_in,
                              void* d_out, int out_size, void* d_ws, size_t ws_size,
                              hipStream_t stream) {
  const float* x       = (const float*)d_in[0];
  const float* w_qkvz  = (const float*)d_in[1];
  const float* w_ba    = (const float*)d_in[2];
  const float* conv_w  = (const float*)d_in[3];
  const float* conv_b  = (const float*)d_in[4];
  const float* a_log   = (const float*)d_in[5];
  const float* dt_bias = (const float*)d_in[6];
  const float* norm_w  = (const float*)d_in[7];
  const float* w_o     = (const float*)d_in[8];
  float* out = (float*)d_out;

  float* ws = (float*)d_ws;
  float* qkvraw = ws;                  // 4,194,304  (-> Bg)
  float* zbuf   = ws + 4194304;        // 2,097,152
  float* qkvc   = ws + 6291456;        // 4,194,304  (-> Mhi|Mlo, -> wot)
  float* khat   = ws + 10485760;       // 1,048,576  (-> hb)
  float* gbuf   = ws + 11534336;       // 16,384
  float* bbuf   = ws + 11550720;       // 16,384
  float* cgbuf  = ws + 11567104;       // 16,384
  float* obuf   = ws + 11583488;       // 2,097,152  (xb early)
  float* Wtg    = ws + 13680640;       // 2,097,152 ┐ -> Sg (4,194,304)
  float* pQg    = ws + 15777792;       // 2,097,152 ┘
  float* Ug     = ws + 17874944;       // 2,097,152
  float* Mqg    = ws + 19972096;       // 1,048,576
  float* Gtg    = ws + 21020672;       // 2,097,152

  u16* xb   = (u16*)obuf;      // x bf16 (dead after gemm1)
  u16* wqt  = (u16*)Wtg;       // w_qkvz^T bf16 (dead after gemm1)
  u16* Mhi  = (u16*)qkvc;
  u16* Mlo  = (u16*)(qkvc + 2097152);
  float* Bg = qkvraw;
  float* Sg = Wtg;
  u16* wot  = (u16*)qkvc;      // after scan_S (Mhi dead)
  u16* hb   = (u16*)khat;      // after make_MBG (khat dead)

  // 0) casts (permuted staging layout)
  cast_bf16<<<1024, 256, 0, stream>>>(x, xb, 262144);
  transpose_bf16<<<dim3(32, 96), 256, 0, stream>>>(w_qkvz, wqt, H_, QN_);
  // 1) qkv|z = x @ w_qkvz
  gemm_bf16<<<768, 256, 0, stream>>>(xb, wqt, qkvraw, CD_, zbuf, VD_,
                                     CD_, T_, QN_, H_);
  // 2) beta / g
  ba_gbeta<<<T_, 128, 0, stream>>>(x, w_ba, a_log, dt_bias, gbuf, bbuf);
  // 3) fused conv + silu + k-l2norm
  conv_silu_k<<<T_, 512, 0, stream>>>(qkvraw, conv_w, conv_b, qkvc, khat);
  // 4) chunk-local precompute (parallel)
  chunk_prep<<<dim3(NC_, HV_), 256, 0, stream>>>(
      qkvc, khat, gbuf, bbuf, cgbuf, Wtg, Ug, Mqg, pQg);
  // 5) per-chunk transition/output operators (parallel)
  make_MBG<<<dim3(NC_, HV_), 256, 0, stream>>>(
      Wtg, pQg, Ug, Mqg, khat, cgbuf, Mhi, Mlo, Bg, Gtg);
  // 6) sequential state scan
  scan_S<<<64, 256, 0, stream>>>(Mhi, Mlo, Bg, Sg);
  // 7) w_o^T cast (Mhi region now dead)
  transpose_bf16<<<dim3(32, 32), 256, 0, stream>>>(w_o, wot, VD_, H_);
  // 8) per-chunk outputs (parallel)
  chunk_out<<<dim3(NC_, HV_), 256, 0, stream>>>(Mqg, Ug, Gtg, Sg, obuf);
  // 9) gated rmsnorm -> bf16 h (permuted)
  gated_rmsnorm<<<dim3(T_, HV_), 128, 0, stream>>>(obuf, zbuf, norm_w, hb);
  // 10) out = h @ w_o
  gemm_bf16<<<256, 256, 0, stream>>>(hb, wot, out, VD_, out, VD_,
                                     VD_, T_, VD_, H_);
}

// Round 7
// 267.746 us; speedup vs baseline: 5.0316x; 1.0837x over previous
//
#include <hip/hip_runtime.h>
#include <math.h>

typedef unsigned short u16;
using us4  = __attribute__((ext_vector_type(4))) unsigned short;
using us8  = __attribute__((ext_vector_type(8))) unsigned short;
using bf16x8 = __attribute__((ext_vector_type(8))) __bf16;
using f32x4v = __attribute__((ext_vector_type(4))) float;

// Problem constants
#define T_    1024
#define H_    2048
#define HK_   8
#define HV_   16
#define KD_   1024
#define VD_   2048
#define CD_   4096
#define QN_   6144   // 2*KD + 2*VD
#define NC_   16     // number of chunks
#define C_    64     // chunk length

__device__ __forceinline__ u16 f2bf(float f) {
  unsigned u = __float_as_uint(f);
  u += 0x7fffu + ((u >> 16) & 1u);   // RNE
  return (u16)(u >> 16);
}
__device__ __forceinline__ float bf2f(u16 h) {
  return __uint_as_float(((unsigned)h) << 16);
}
// staging layout for gemm: within each 64-elem k-group, 8-elem chunk c of
// row r is stored at chunk position c ^ (r&7)  (conflict-free at 128B row
// stride for ds_read_b128 fragment loads).
__device__ __forceinline__ int permk3(int r, int k) {
  return (k & ~63) | ((((k >> 3) & 7) ^ (r & 7)) << 3) | (k & 7);
}

// ---------------------------------------------------------------------------
// x f32 -> bf16 with chunk permutation (row length 2048)
// ---------------------------------------------------------------------------
__global__ void cast_bf16(const float* __restrict__ in, u16* __restrict__ out,
                          int n8) {
  int i = blockIdx.x * 256 + threadIdx.x;   // 16B-chunk index
  if (i >= n8) return;
  float4 a = ((const float4*)in)[i * 2];
  float4 b = ((const float4*)in)[i * 2 + 1];
  us8 r = {f2bf(a.x), f2bf(a.y), f2bf(a.z), f2bf(a.w),
           f2bf(b.x), f2bf(b.y), f2bf(b.z), f2bf(b.w)};
  const int row = i >> 8;                   // 2048/8 = 256 chunks per row
  const int ip = (i & ~7) | ((i & 7) ^ (row & 7));
  *(us8*)&out[(size_t)ip * 8] = r;
}

// ---------------------------------------------------------------------------
// f32 [R][C] -> bf16 [C][R] transpose + cast + chunk permutation
// ---------------------------------------------------------------------------
__global__ __launch_bounds__(256) void transpose_bf16(
    const float* __restrict__ in, u16* __restrict__ out, int R, int C) {
  __shared__ float tile[64][65];
  const int r0 = blockIdx.x * 64, c0 = blockIdx.y * 64;
  const int t = threadIdx.x;
  const int tr = t >> 4, tc4 = (t & 15) * 4;
#pragma unroll
  for (int i = 0; i < 4; ++i) {
    float4 v = *(const float4*)&in[(size_t)(r0 + tr + i * 16) * C + c0 + tc4];
    tile[tr + i * 16][tc4 + 0] = v.x;
    tile[tr + i * 16][tc4 + 1] = v.y;
    tile[tr + i * 16][tc4 + 2] = v.z;
    tile[tr + i * 16][tc4 + 3] = v.w;
  }
  __syncthreads();
#pragma unroll
  for (int i = 0; i < 4; ++i) {
    int oc = tr + i * 16;
    int row = c0 + oc;
    int k = r0 + tc4;
    us4 w = {f2bf(tile[tc4 + 0][oc]), f2bf(tile[tc4 + 1][oc]),
             f2bf(tile[tc4 + 2][oc]), f2bf(tile[tc4 + 3][oc])};
    *(us4*)&out[(size_t)row * R + permk3(row, k)] = w;
  }
}

// ---------------------------------------------------------------------------
// bf16 MFMA GEMM: C = A[M,K] @ Bt[N,K]^T, f32 out. 128x64 tile, BK=64,
// 2-phase double-buffered LDS pipeline, XCD-grouped 1D block mapping,
// 3-bit permuted staging. Output routed to Cq (cols < zsplit) or Cz.
// ---------------------------------------------------------------------------
__device__ __forceinline__ void gload_lds16(const void* g, void* l) {
  __builtin_amdgcn_global_load_lds(
      (const __attribute__((address_space(1))) void*)g,
      (__attribute__((address_space(3))) void*)l, 16, 0, 0);
}

__global__ __launch_bounds__(256) void gemm_bf16(
    const u16* __restrict__ A, const u16* __restrict__ Bt,
    float* __restrict__ Cq, int ldq, float* __restrict__ Cz, int ldz,
    int zsplit, int M, int N, int K) {
  __shared__ __align__(16) u16 As[2][8192];   // [128][64]
  __shared__ __align__(16) u16 Bs[2][4096];   // [64][64]
  const int tid  = threadIdx.x;
  const int wave = tid >> 6, lane = tid & 63;
  // XCD-grouped mapping: blocks bid%8==x land on XCD x; each XCD owns
  // contiguous col-panels, row sweeps slowest.
  const int gy = N >> 6;
  const int ncolpx = gy >> 3;
  const int bid = blockIdx.x;
  const int xcd = bid & 7, idx = bid >> 3;
  const int row0 = (idx / ncolpx) * 128;
  const int col0 = (xcd * ncolpx + idx % ncolpx) * 64;
  const int wr = wave >> 1, wc = wave & 1;
  const int fr = lane & 15, fq = lane >> 4;

  // staging coords: one gload call = 8 rows x 64 cols (1KB), lane->linear
  const int sr8 = lane >> 3;           // row within 8-row slab
  const int sc8 = (lane & 7) * 8;      // col offset (u16)
  const u16* gA = A  + (size_t)(row0 + wave * 32 + sr8) * K + sc8;
  const u16* gB = Bt + (size_t)(col0 + wave * 16 + sr8) * K + sc8;

  f32x4v acc[4][2] = {};
  const int nt = K >> 6;

  auto stage = [&](int p, int k0) {
#pragma unroll
    for (int j = 0; j < 4; ++j)
      gload_lds16(gA + (size_t)(j * 8) * K + k0,
                  &As[p][(wave * 32 + j * 8) * 64]);
#pragma unroll
    for (int j = 0; j < 2; ++j)
      gload_lds16(gB + (size_t)(j * 8) * K + k0,
                  &Bs[p][(wave * 16 + j * 8) * 64]);
  };

  stage(0, 0);
  asm volatile("s_waitcnt vmcnt(0)" ::: "memory");
  __syncthreads();

  int p = 0;
  for (int it = 0; it < nt; ++it) {
    if (it + 1 < nt) stage(p ^ 1, (it + 1) * 64);
#pragma unroll
    for (int kt = 0; kt < 2; ++kt) {
      bf16x8 af[4], bff[2];
#pragma unroll
      for (int mi = 0; mi < 4; ++mi) {
        const int r = wr * 64 + mi * 16 + fr;
        af[mi] = *(const bf16x8*)
            &As[p][r * 64 + kt * 32 + (((kt * 4 + fq) ^ (r & 7)) & 3) * 8
                   + ((((kt * 4 + fq) ^ (r & 7)) >> 2) - kt) * 32];
      }
#pragma unroll
      for (int ni = 0; ni < 2; ++ni) {
        const int r = wc * 32 + ni * 16 + fr;
        bff[ni] = *(const bf16x8*)
            &Bs[p][r * 64 + kt * 32 + (((kt * 4 + fq) ^ (r & 7)) & 3) * 8
                   + ((((kt * 4 + fq) ^ (r & 7)) >> 2) - kt) * 32];
      }
#pragma unroll
      for (int mi = 0; mi < 4; ++mi)
#pragma unroll
        for (int ni = 0; ni < 2; ++ni)
          acc[mi][ni] = __builtin_amdgcn_mfma_f32_16x16x32_bf16(
              af[mi], bff[ni], acc[mi][ni], 0, 0, 0);
    }
    if (it + 1 < nt) {
      asm volatile("s_waitcnt vmcnt(0)" ::: "memory");
      __syncthreads();
    }
    p ^= 1;
  }

  float* Cp; int ldc, cb;
  if (col0 < zsplit) { Cp = Cq; ldc = ldq; cb = col0; }
  else               { Cp = Cz; ldc = ldz; cb = col0 - zsplit; }
#pragma unroll
  for (int mi = 0; mi < 4; ++mi)
#pragma unroll
    for (int ni = 0; ni < 2; ++ni) {
      const int r  = row0 + wr * 64 + mi * 16 + fq * 4;
      const int cc = cb + wc * 32 + ni * 16 + fr;
#pragma unroll
      for (int j = 0; j < 4; ++j)
        Cp[(size_t)(r + j) * ldc + cc] = acc[mi][ni][j];
    }
}

// ---------------------------------------------------------------------------
// ba = x @ w_ba -> beta = sigmoid(b), g = -exp(a_log)*softplus(a+dt_bias)
// x row staged in LDS; 256 threads (8 k-chunks x 32 cols).
// ---------------------------------------------------------------------------
__global__ __launch_bounds__(256) void ba_gbeta(
    const float* __restrict__ x, const float* __restrict__ w_ba,
    const float* __restrict__ a_log, const float* __restrict__ dt_bias,
    float* __restrict__ g, float* __restrict__ beta) {
  const int t = blockIdx.x;
  const int tid = threadIdx.x;
  __shared__ float xs[2048];
  __shared__ float red[8][32];
  {
    float4 v = *(const float4*)&x[(size_t)t * H_ + tid * 4];
    *(float4*)&xs[tid * 4] = v;
    float4 w = *(const float4*)&x[(size_t)t * H_ + 1024 + tid * 4];
    *(float4*)&xs[1024 + tid * 4] = w;
  }
  __syncthreads();
  const int c = tid & 31;
  const int chunk = tid >> 5;
  float p = 0.f;
  const int kb = chunk * 256;
#pragma unroll 4
  for (int k = kb; k < kb + 256; ++k) p = fmaf(xs[k], w_ba[k * 32 + c], p);
  red[chunk][c] = p;
  __syncthreads();
  if (tid < 32) {
    float s = 0.f;
#pragma unroll
    for (int i = 0; i < 8; ++i) s += red[i][c];
    if (c < 16) {
      beta[t * 16 + c] = 1.f / (1.f + expf(-s));
    } else {
      int h = c - 16;
      float xx = s + dt_bias[h];
      float sp = xx > 20.f ? xx : log1pf(expf(xx));
      g[t * 16 + h] = -expf(a_log[h]) * sp;
    }
  }
}

// ---------------------------------------------------------------------------
// fused causal depthwise conv1d (K=4) + SiLU + k-l2norm.
// ---------------------------------------------------------------------------
__global__ __launch_bounds__(512) void conv_silu_k(
    const float* __restrict__ qkvraw, const float* __restrict__ conv_w,
    const float* __restrict__ conv_b, float* __restrict__ qkvc,
    float* __restrict__ khat) {
  const int t = blockIdx.x;
  const int tid = threadIdx.x;
  const int c0 = tid * 8;
  float acc[8];
  float4 cb0 = *(const float4*)&conv_b[c0];
  float4 cb1 = *(const float4*)&conv_b[c0 + 4];
  acc[0] = cb0.x; acc[1] = cb0.y; acc[2] = cb0.z; acc[3] = cb0.w;
  acc[4] = cb1.x; acc[5] = cb1.y; acc[6] = cb1.z; acc[7] = cb1.w;
  float wv[8][4];
#pragma unroll
  for (int i = 0; i < 8; i += 2) {
    float4 w0 = *(const float4*)&conv_w[(c0 + i) * 4];
    float4 w1 = *(const float4*)&conv_w[(c0 + i + 1) * 4];
    wv[i][0] = w0.x; wv[i][1] = w0.y; wv[i][2] = w0.z; wv[i][3] = w0.w;
    wv[i+1][0] = w1.x; wv[i+1][1] = w1.y; wv[i+1][2] = w1.z; wv[i+1][3] = w1.w;
  }
#pragma unroll
  for (int j = 0; j < 4; ++j) {
    int tt = t - 3 + j;
    if (tt >= 0) {
      float4 a = *(const float4*)&qkvraw[(size_t)tt * CD_ + c0];
      float4 b = *(const float4*)&qkvraw[(size_t)tt * CD_ + c0 + 4];
      float xv[8] = {a.x, a.y, a.z, a.w, b.x, b.y, b.z, b.w};
#pragma unroll
      for (int i = 0; i < 8; ++i) acc[i] = fmaf(xv[i], wv[i][j], acc[i]);
    }
  }
  float y[8];
#pragma unroll
  for (int i = 0; i < 8; ++i) y[i] = acc[i] / (1.f + expf(-acc[i]));

  if (tid < 128 || tid >= 256) {
    float4 o0 = {y[0], y[1], y[2], y[3]};
    float4 o1 = {y[4], y[5], y[6], y[7]};
    *(float4*)&qkvc[(size_t)t * CD_ + c0]     = o0;
    *(float4*)&qkvc[(size_t)t * CD_ + c0 + 4] = o1;
  } else {
    float ss = 0.f;
#pragma unroll
    for (int i = 0; i < 8; ++i) ss = fmaf(y[i], y[i], ss);
#pragma unroll
    for (int off = 1; off < 16; off <<= 1) ss += __shfl_xor(ss, off);
    float rs = rsqrtf(ss + 1e-6f);
    const int head = (c0 - 1024) >> 7;
    const int d0 = (c0 - 1024) & 127;
    float4 o0 = {y[0] * rs, y[1] * rs, y[2] * rs, y[3] * rs};
    float4 o1 = {y[4] * rs, y[5] * rs, y[6] * rs, y[7] * rs};
    float* kout = &khat[((size_t)t * HK_ + head) * 128 + d0];
    *(float4*)&kout[0] = o0;
    *(float4*)&kout[4] = o1;
  }
}

// ---------------------------------------------------------------------------
// Chunked gated delta rule, phase A (parallel over 16 chunks x 16 heads).
// ---------------------------------------------------------------------------
#define SWZ(r) (((r) >> 2) & 7)

__device__ __forceinline__ float4 ldsw4(const float* base, int r, int dblk) {
  return *(const float4*)&base[r * 128 + ((dblk ^ SWZ(r)) << 2)];
}
__device__ __forceinline__ float ldsw1(const float* base, int r, int d) {
  return base[r * 128 + ((((d) >> 2) ^ SWZ(r)) << 2) + ((d) & 3)];
}

__global__ __launch_bounds__(256) void chunk_prep(
    const float* __restrict__ qkvc, const float* __restrict__ khat,
    const float* __restrict__ g, const float* __restrict__ beta,
    float* __restrict__ cgbuf, float* __restrict__ Wtg, float* __restrict__ Ug,
    float* __restrict__ Mqg, float* __restrict__ pQg) {
  const int c = blockIdx.x, hv = blockIdx.y, hk = hv >> 1;
  const int cid = c * 16 + hv;
  const int tid = threadIdx.x;
  __shared__ float Kl[8192], Ql[8192];   // swizzled [64][128]
  __shared__ float AM[8320];             // At[64][65] | Mq[64][65]; later Utr
  __shared__ float cgl[64], bl[64], bp[64], rsl[64];
  float* At = AM;
  float* Mq = AM + 4160;

#pragma unroll
  for (int it = 0; it < 8; ++it) {
    int flat = it * 1024 + tid * 4;
    int row = flat >> 7, d = flat & 127;
    int pb = ((d >> 2) ^ SWZ(row)) << 2;
    int gt = c * 64 + row;
    float4 kv = *(const float4*)&khat[((size_t)gt * HK_ + hk) * 128 + d];
    float4 qv = *(const float4*)&qkvc[(size_t)gt * CD_ + hk * 128 + d];
    *(float4*)&Kl[row * 128 + pb] = kv;
    *(float4*)&Ql[row * 128 + pb] = qv;
  }
  if (tid < 64) {
    float s = g[(size_t)(c * 64 + tid) * HV_ + hv];
#pragma unroll
    for (int off = 1; off < 64; off <<= 1) {
      float t = __shfl_up(s, off);
      if (tid >= off) s += t;
    }
    cgl[tid] = s;
    cgbuf[cid * 64 + tid] = s;
    bl[tid] = beta[(size_t)(c * 64 + tid) * HV_ + hv];
  }
  __syncthreads();
  if (tid < 64) {
    float sq = 0.f;
#pragma unroll
    for (int dblk = 0; dblk < 32; ++dblk) {
      float4 q4 = ldsw4(Ql, tid, dblk);
      sq = fmaf(q4.x, q4.x, sq); sq = fmaf(q4.y, q4.y, sq);
      sq = fmaf(q4.z, q4.z, sq); sq = fmaf(q4.w, q4.w, sq);
    }
    rsl[tid] = rsqrtf(sq + 1e-6f) * 0.08838834764831845f;
    bp[tid] = bl[tid] * expf(cgl[tid]);
  }
  __syncthreads();

  const int i0 = (tid >> 4) * 4, j0 = (tid & 15) * 4;
  float kk[4][4], qk[4][4];
#pragma unroll
  for (int a = 0; a < 4; ++a)
#pragma unroll
    for (int b = 0; b < 4; ++b) { kk[a][b] = 0.f; qk[a][b] = 0.f; }
  for (int dblk = 0; dblk < 32; ++dblk) {
    float4 ka[4], qa[4], kb[4];
#pragma unroll
    for (int a = 0; a < 4; ++a) {
      ka[a] = ldsw4(Kl, i0 + a, dblk);
      qa[a] = ldsw4(Ql, i0 + a, dblk);
    }
#pragma unroll
    for (int b = 0; b < 4; ++b) kb[b] = ldsw4(Kl, j0 + b, dblk);
#pragma unroll
    for (int a = 0; a < 4; ++a)
#pragma unroll
      for (int b = 0; b < 4; ++b) {
        kk[a][b] = fmaf(ka[a].x, kb[b].x, kk[a][b]);
        kk[a][b] = fmaf(ka[a].y, kb[b].y, kk[a][b]);
        kk[a][b] = fmaf(ka[a].z, kb[b].z, kk[a][b]);
        kk[a][b] = fmaf(ka[a].w, kb[b].w, kk[a][b]);
        qk[a][b] = fmaf(qa[a].x, kb[b].x, qk[a][b]);
        qk[a][b] = fmaf(qa[a].y, kb[b].y, qk[a][b]);
        qk[a][b] = fmaf(qa[a].z, kb[b].z, qk[a][b]);
        qk[a][b] = fmaf(qa[a].w, kb[b].w, qk[a][b]);
      }
  }
#pragma unroll
  for (int a = 0; a < 4; ++a)
#pragma unroll
    for (int b = 0; b < 4; ++b) {
      int i = i0 + a, j = j0 + b;
      float e = expf(cgl[i] - cgl[j]);
      At[j * 65 + i] = (j < i) ? (-bl[i] * e * kk[a][b]) : 0.f;
      Mq[j * 65 + i] = (j <= i) ? (rsl[i] * e * qk[a][b]) : 0.f;
    }
  __syncthreads();

  float X[64];
  if (tid < 128) {
#pragma unroll
    for (int j = 0; j < 64; ++j) X[j] = bp[j] * ldsw1(Kl, j, tid);
  } else {
    const int m = tid - 128;
#pragma unroll
    for (int j = 0; j < 64; ++j)
      X[j] = bl[j] * qkvc[(size_t)(c * 64 + j) * CD_ + 2 * KD_ + hv * 128 + m];
  }
#pragma unroll
  for (int it = 0; it < 16; ++it) {
    int f = it * 256 + tid;
    int j = f >> 6, i = f & 63;
    Mqg[(size_t)cid * 4096 + f] = Mq[j * 65 + i];
  }
#pragma unroll
  for (int j = 0; j < 63; ++j) {
    float xj = X[j];
#pragma unroll
    for (int i = j + 1; i < 64; ++i) X[i] = fmaf(At[j * 65 + i], xj, X[i]);
  }
  __syncthreads();

  if (tid < 128) {
    size_t baseo = ((size_t)cid * 128 + tid) * 64;
#pragma unroll
    for (int j4 = 0; j4 < 16; ++j4) {
      float4 v = {X[j4 * 4], X[j4 * 4 + 1], X[j4 * 4 + 2], X[j4 * 4 + 3]};
      *(float4*)&Wtg[baseo + j4 * 4] = v;
    }
  } else {
    const int m = tid - 128;
    float* Utr = AM;
#pragma unroll
    for (int j = 0; j < 64; ++j) Utr[j * 128 + m] = X[j];
  }
  __syncthreads();
  {
    const float* Utr = AM;
#pragma unroll
    for (int it = 0; it < 8; ++it) {
      int flat = it * 1024 + tid * 4;
      *(float4*)&Ug[(size_t)cid * 8192 + flat] = *(const float4*)&Utr[flat];
    }
    const int i = tid & 63;
    const float ei = expf(cgl[i]) * rsl[i];
#pragma unroll
    for (int it = 0; it < 32; ++it) {
      int d = it * 4 + (tid >> 6);
      pQg[(size_t)cid * 8192 + d * 64 + i] = ei * ldsw1(Ql, i, d);
    }
  }
}

// ---------------------------------------------------------------------------
// make_MBG (parallel, 256 blocks)
// ---------------------------------------------------------------------------
__global__ __launch_bounds__(256) void make_MBG(
    const float* __restrict__ Wtg, const float* __restrict__ pQg,
    const float* __restrict__ Ug, const float* __restrict__ Mqg,
    const float* __restrict__ khat, const float* __restrict__ cgbuf,
    u16* __restrict__ Mhi, u16* __restrict__ Mlo,
    float* __restrict__ Bg, float* __restrict__ Gtg) {
  const int c = blockIdx.x, hv = blockIdx.y, hk = hv >> 1;
  const int cid = c * 16 + hv;
  const int tid = threadIdx.x;
  __shared__ float Wl[64 * 128];   // W[j][d]
  __shared__ float Kel[64 * 128];  // esc_j * khat_j[d]
  __shared__ float Ul[64 * 128];
  __shared__ float Mql[64 * 64];
  const float cg63 = cgbuf[cid * 64 + 63];
  const float pC = expf(cg63);
#pragma unroll
  for (int it = 0; it < 8; ++it) {
    int f = it * 1024 + tid * 4;       // f = d*64 + j
    int d = f >> 6, j = f & 63;
    float4 w = *(const float4*)&Wtg[(size_t)cid * 8192 + f];
    Wl[(j + 0) * 128 + d] = w.x;
    Wl[(j + 1) * 128 + d] = w.y;
    Wl[(j + 2) * 128 + d] = w.z;
    Wl[(j + 3) * 128 + d] = w.w;
  }
#pragma unroll
  for (int it = 0; it < 8; ++it) {
    int f = it * 1024 + tid * 4;       // f = j*128 + d
    int j = f >> 7, d = f & 127;
    float esc = expf(cg63 - cgbuf[cid * 64 + j]);
    float4 kv = *(const float4*)&khat[((size_t)(c * 64 + j) * HK_ + hk) * 128 + d];
    float4 uv = *(const float4*)&Ug[(size_t)cid * 8192 + f];
    kv.x *= esc; kv.y *= esc; kv.z *= esc; kv.w *= esc;
    *(float4*)&Kel[f] = kv;
    *(float4*)&Ul[f] = uv;
  }
#pragma unroll
  for (int it = 0; it < 4; ++it) {
    int f = it * 1024 + tid * 4;
    *(float4*)&Mql[f] = *(const float4*)&Mqg[(size_t)cid * 4096 + f];
  }
  __syncthreads();

  const int d0 = (tid & 15) * 8, n0 = (tid >> 4) * 8;
  float ma[8][8] = {}, ba[8][8] = {};
  for (int j = 0; j < 64; ++j) {
    float4 k0 = *(const float4*)&Kel[j * 128 + d0];
    float4 k1 = *(const float4*)&Kel[j * 128 + d0 + 4];
    float4 w0 = *(const float4*)&Wl[j * 128 + n0];
    float4 w1 = *(const float4*)&Wl[j * 128 + n0 + 4];
    float4 u0 = *(const float4*)&Ul[j * 128 + n0];
    float4 u1 = *(const float4*)&Ul[j * 128 + n0 + 4];
    float ke[8] = {k0.x, k0.y, k0.z, k0.w, k1.x, k1.y, k1.z, k1.w};
    float wv[8] = {w0.x, w0.y, w0.z, w0.w, w1.x, w1.y, w1.z, w1.w};
    float uv[8] = {u0.x, u0.y, u0.z, u0.w, u1.x, u1.y, u1.z, u1.w};
#pragma unroll
    for (int a = 0; a < 8; ++a)
#pragma unroll
      for (int b = 0; b < 8; ++b) {
        ma[a][b] = fmaf(ke[a], wv[b], ma[a][b]);
        ba[a][b] = fmaf(ke[a], uv[b], ba[a][b]);
      }
  }
#pragma unroll
  for (int a = 0; a < 8; ++a) {
    const int d = d0 + a;
    us8 hi, lo;
#pragma unroll
    for (int b = 0; b < 8; ++b) {
      float m = ((d == n0 + b) ? pC : 0.f) - ma[a][b];
      u16 h = f2bf(m);
      hi[b] = h;
      lo[b] = f2bf(m - bf2f(h));
    }
    *(us8*)&Mhi[(size_t)cid * 16384 + d * 128 + n0] = hi;
    *(us8*)&Mlo[(size_t)cid * 16384 + d * 128 + n0] = lo;
    float4 b0 = {ba[a][0], ba[a][1], ba[a][2], ba[a][3]};
    float4 b1 = {ba[a][4], ba[a][5], ba[a][6], ba[a][7]};
    *(float4*)&Bg[(size_t)cid * 16384 + d * 128 + n0]     = b0;
    *(float4*)&Bg[(size_t)cid * 16384 + d * 128 + n0 + 4] = b1;
  }

  const int dg = (tid & 31) * 4, ig = (tid >> 5) * 8;
  float ga[4][8] = {};
  for (int j = 0; j < 64; ++j) {
    float4 w4 = *(const float4*)&Wl[j * 128 + dg];
    float4 m0 = *(const float4*)&Mql[j * 64 + ig];
    float4 m1 = *(const float4*)&Mql[j * 64 + ig + 4];
    float wv[4] = {w4.x, w4.y, w4.z, w4.w};
    float mv[8] = {m0.x, m0.y, m0.z, m0.w, m1.x, m1.y, m1.z, m1.w};
#pragma unroll
    for (int a = 0; a < 4; ++a)
#pragma unroll
      for (int b = 0; b < 8; ++b) ga[a][b] = fmaf(wv[a], mv[b], ga[a][b]);
  }
#pragma unroll
  for (int a = 0; a < 4; ++a) {
    const int d = dg + a;
    float4 p0 = *(const float4*)&pQg[(size_t)cid * 8192 + d * 64 + ig];
    float4 p1 = *(const float4*)&pQg[(size_t)cid * 8192 + d * 64 + ig + 4];
    float4 g0 = {p0.x - ga[a][0], p0.y - ga[a][1], p0.z - ga[a][2], p0.w - ga[a][3]};
    float4 g1 = {p1.x - ga[a][4], p1.y - ga[a][5], p1.z - ga[a][6], p1.w - ga[a][7]};
    *(float4*)&Gtg[(size_t)cid * 8192 + d * 64 + ig]     = g0;
    *(float4*)&Gtg[(size_t)cid * 8192 + d * 64 + ig + 4] = g1;
  }
}

// ---------------------------------------------------------------------------
// scan_S: 64 blocks = 16 heads x 4 col-slices, XCD-grouped.
// ---------------------------------------------------------------------------
__global__ __launch_bounds__(256) void scan_S(
    const u16* __restrict__ Mhi, const u16* __restrict__ Mlo,
    const float* __restrict__ Bg, float* __restrict__ Sg) {
  const int flat = blockIdx.x;
  const int hv = (flat & 7) + 8 * (flat >> 5);
  const int vs = (flat >> 3) & 3;
  const int tid = threadIdx.x;
  const int wave = tid >> 6, lane = tid & 63;
  const int fr = lane & 15, fq = lane >> 4;
  const int wr = wave * 32;
  const int m0 = vs * 32;

  __shared__ u16 Sh[2][4096];
  __shared__ u16 Sl[2][4096];

  for (int i = tid; i < 4096; i += 256) { Sh[0][i] = 0; Sl[0][i] = 0; }
  {
    float* s0 = Sg + (size_t)hv * 16384 + m0;
#pragma unroll
    for (int it = 0; it < 16; ++it) {
      int idx = it * 256 + tid;
      s0[(size_t)(idx >> 5) * 128 + (idx & 31)] = 0.f;
    }
  }
  __syncthreads();

  bf16x8 MhA[2][4], MlA[2][4], MhB[2][4], MlB[2][4];
  {
    const u16* Mh0 = Mhi + (size_t)hv * 16384;
    const u16* Ml0 = Mlo + (size_t)hv * 16384;
#pragma unroll
    for (int a = 0; a < 2; ++a)
#pragma unroll
      for (int kt = 0; kt < 4; ++kt) {
        size_t off = (size_t)(wr + a * 16 + fr) * 128 + kt * 32 + fq * 8;
        MhA[a][kt] = *(const bf16x8*)&Mh0[off];
        MlA[a][kt] = *(const bf16x8*)&Ml0[off];
      }
  }
  int p = 0;

  auto step = [&](int c, bf16x8 (&MhC)[2][4], bf16x8 (&MlC)[2][4],
                  bf16x8 (&MhN)[2][4], bf16x8 (&MlN)[2][4]) {
    if (c + 1 < NC_ - 1) {
      const u16* MhP = Mhi + (size_t)((c + 1) * 16 + hv) * 16384;
      const u16* MlP = Mlo + (size_t)((c + 1) * 16 + hv) * 16384;
#pragma unroll
      for (int a = 0; a < 2; ++a)
#pragma unroll
        for (int kt = 0; kt < 4; ++kt) {
          size_t off = (size_t)(wr + a * 16 + fr) * 128 + kt * 32 + fq * 8;
          MhN[a][kt] = *(const bf16x8*)&MhP[off];
          MlN[a][kt] = *(const bf16x8*)&MlP[off];
        }
    }
    const float* Bc = Bg + (size_t)(c * 16 + hv) * 16384 + m0;
    float bv[2][2][4];
#pragma unroll
    for (int a = 0; a < 2; ++a)
#pragma unroll
      for (int b = 0; b < 2; ++b)
#pragma unroll
        for (int j = 0; j < 4; ++j)
          bv[a][b][j] =
              Bc[(size_t)(wr + a * 16 + fq * 4 + j) * 128 + b * 16 + fr];

    f32x4v acc[2][2] = {};
#pragma unroll
    for (int kt = 0; kt < 4; ++kt) {
      bf16x8 Bh[2], Bl[2];
#pragma unroll
      for (int b = 0; b < 2; ++b) {
        int m = b * 16 + fr;
        int byte = m * 256 + ((kt * 64 + fq * 16) ^ ((m & 7) << 4));
        Bh[b] = *(const bf16x8*)((const char*)&Sh[p][0] + byte);
        Bl[b] = *(const bf16x8*)((const char*)&Sl[p][0] + byte);
      }
#pragma unroll
      for (int a = 0; a < 2; ++a)
#pragma unroll
        for (int b = 0; b < 2; ++b) {
          acc[a][b] = __builtin_amdgcn_mfma_f32_16x16x32_bf16(
              MlC[a][kt], Bh[b], acc[a][b], 0, 0, 0);
          acc[a][b] = __builtin_amdgcn_mfma_f32_16x16x32_bf16(
              MhC[a][kt], Bl[b], acc[a][b], 0, 0, 0);
          acc[a][b] = __builtin_amdgcn_mfma_f32_16x16x32_bf16(
              MhC[a][kt], Bh[b], acc[a][b], 0, 0, 0);
        }
    }
    float* Sn = Sg + (size_t)((c + 1) * 16 + hv) * 16384 + m0;
#pragma unroll
    for (int a = 0; a < 2; ++a)
#pragma unroll
      for (int b = 0; b < 2; ++b) {
        const int k0 = wr + a * 16 + fq * 4;
        const int m = b * 16 + fr;
        us4 h4, l4;
#pragma unroll
        for (int j = 0; j < 4; ++j) {
          float v = acc[a][b][j] + bv[a][b][j];
          Sn[(size_t)(k0 + j) * 128 + m] = v;
          u16 h = f2bf(v);
          h4[j] = h;
          l4[j] = f2bf(v - bf2f(h));
        }
        int byte = m * 256 + (((k0 * 2)) ^ ((m & 7) << 4));
        *(us4*)((char*)&Sh[p ^ 1][0] + byte) = h4;
        *(us4*)((char*)&Sl[p ^ 1][0] + byte) = l4;
      }
    __syncthreads();
    p ^= 1;
  };

  for (int cc = 0; cc < NC_ - 1; cc += 2) {
    step(cc, MhA, MlA, MhB, MlB);
    if (cc + 1 < NC_ - 1) step(cc + 1, MhB, MlB, MhA, MlA);
  }
}

// ---------------------------------------------------------------------------
// chunk_out (parallel, 256 blocks): o = Mq^T U + G*S
// ---------------------------------------------------------------------------
__global__ __launch_bounds__(256) void chunk_out(
    const float* __restrict__ Mqg, const float* __restrict__ Ug,
    const float* __restrict__ Gtg, const float* __restrict__ Sg,
    float* __restrict__ o) {
  const int c = blockIdx.x, hv = blockIdx.y;
  const int cid = c * 16 + hv;
  const int tid = threadIdx.x;
  __shared__ float Mql[64 * 64];
  __shared__ float Ul[64 * 128];
  __shared__ float Gtl[128 * 64];
  __shared__ float Sl[128 * 128];
#pragma unroll
  for (int it = 0; it < 4; ++it) {
    int f = it * 1024 + tid * 4;
    *(float4*)&Mql[f] = *(const float4*)&Mqg[(size_t)cid * 4096 + f];
  }
#pragma unroll
  for (int it = 0; it < 8; ++it) {
    int f = it * 1024 + tid * 4;
    *(float4*)&Ul[f]  = *(const float4*)&Ug[(size_t)cid * 8192 + f];
    *(float4*)&Gtl[f] = *(const float4*)&Gtg[(size_t)cid * 8192 + f];
  }
#pragma unroll
  for (int it = 0; it < 16; ++it) {
    int f = it * 1024 + tid * 4;
    *(float4*)&Sl[f] = *(const float4*)&Sg[(size_t)cid * 16384 + f];
  }
  __syncthreads();

  const int i0 = (tid & 15) * 4, m0 = (tid >> 4) * 8;
  float oa[4][8] = {};
  for (int j = 0; j < 64; ++j) {
    float4 mq = *(const float4*)&Mql[j * 64 + i0];
    float4 u0 = *(const float4*)&Ul[j * 128 + m0];
    float4 u1 = *(const float4*)&Ul[j * 128 + m0 + 4];
    float mv[4] = {mq.x, mq.y, mq.z, mq.w};
    float uv[8] = {u0.x, u0.y, u0.z, u0.w, u1.x, u1.y, u1.z, u1.w};
#pragma unroll
    for (int a = 0; a < 4; ++a)
#pragma unroll
      for (int b = 0; b < 8; ++b) oa[a][b] = fmaf(mv[a], uv[b], oa[a][b]);
  }
  for (int d = 0; d < 128; ++d) {
    float4 gt = *(const float4*)&Gtl[d * 64 + i0];
    float4 s0 = *(const float4*)&Sl[d * 128 + m0];
    float4 s1 = *(const float4*)&Sl[d * 128 + m0 + 4];
    float gv[4] = {gt.x, gt.y, gt.z, gt.w};
    float sv[8] = {s0.x, s0.y, s0.z, s0.w, s1.x, s1.y, s1.z, s1.w};
#pragma unroll
    for (int a = 0; a < 4; ++a)
#pragma unroll
      for (int b = 0; b < 8; ++b) oa[a][b] = fmaf(gv[a], sv[b], oa[a][b]);
  }
#pragma unroll
  for (int a = 0; a < 4; ++a) {
    const int t = c * 64 + i0 + a;
    float4 o0 = {oa[a][0], oa[a][1], oa[a][2], oa[a][3]};
    float4 o1 = {oa[a][4], oa[a][5], oa[a][6], oa[a][7]};
    *(float4*)&o[((size_t)t * HV_ + hv) * 128 + m0]     = o0;
    *(float4*)&o[((size_t)t * HV_ + hv) * 128 + m0 + 4] = o1;
  }
}

// ---------------------------------------------------------------------------
// h = o * silu(z); rmsnorm; -> bf16 (permuted staging layout for gemm2)
// ---------------------------------------------------------------------------
__global__ void gated_rmsnorm(const float* __restrict__ o,
                              const float* __restrict__ zbuf,
                              const float* __restrict__ norm_w,
                              u16* __restrict__ h) {
  const int t = blockIdx.x, hv = blockIdx.y, d = threadIdx.x;
  float ov = o[((size_t)t * HV_ + hv) * 128 + d];
  float zv = zbuf[(size_t)t * VD_ + hv * 128 + d];
  float hc = ov * (zv / (1.f + expf(-zv)));
  float ss = hc * hc;
#pragma unroll
  for (int off = 32; off >= 1; off >>= 1) ss += __shfl_xor(ss, off);
  __shared__ float s2[2];
  if ((d & 63) == 0) s2[d >> 6] = ss;
  __syncthreads();
  float tot = s2[0] + s2[1];
  float r = rsqrtf(tot * (1.f / 128.f) + 1e-6f);
  const int k = hv * 128 + d;
  h[(size_t)t * VD_ + permk3(t, k)] = f2bf(hc * r * norm_w[d]);
}

// ---------------------------------------------------------------------------
extern "C" void kernel_launch(void* const* d_in, const int* in_sizes, int n_in,
                              void* d_out, int out_size, void* d_ws, size_t ws_size,
                              hipStream_t stream) {
  const float* x       = (const float*)d_in[0];
  const float* w_qkvz  = (const float*)d_in[1];
  const float* w_ba    = (const float*)d_in[2];
  const float* conv_w  = (const float*)d_in[3];
  const float* conv_b  = (const float*)d_in[4];
  const float* a_log   = (const float*)d_in[5];
  const float* dt_bias = (const float*)d_in[6];
  const float* norm_w  = (const float*)d_in[7];
  const float* w_o     = (const float*)d_in[8];
  float* out = (float*)d_out;

  float* ws = (float*)d_ws;
  float* qkvraw = ws;                  // 4,194,304  (-> Bg)
  float* zbuf   = ws + 4194304;        // 2,097,152
  float* qkvc   = ws + 6291456;        // 4,194,304  (-> Mhi|Mlo, -> wot)
  float* khat   = ws + 10485760;       // 1,048,576  (-> hb)
  float* gbuf   = ws + 11534336;       // 16,384
  float* bbuf   = ws + 11550720;       // 16,384
  float* cgbuf  = ws + 11567104;       // 16,384
  float* obuf   = ws + 11583488;       // 2,097,152  (xb early)
  float* Wtg    = ws + 13680640;       // 2,097,152 ┐ -> Sg (4,194,304)
  float* pQg    = ws + 15777792;       // 2,097,152 ┘
  float* Ug     = ws + 17874944;       // 2,097,152
  float* Mqg    = ws + 19972096;       // 1,048,576
  float* Gtg    = ws + 21020672;       // 2,097,152

  u16* xb   = (u16*)obuf;      // x bf16 (dead after gemm1)
  u16* wqt  = (u16*)Wtg;       // w_qkvz^T bf16 (dead after gemm1)
  u16* Mhi  = (u16*)qkvc;
  u16* Mlo  = (u16*)(qkvc + 2097152);
  float* Bg = qkvraw;
  float* Sg = Wtg;
  u16* wot  = (u16*)qkvc;      // after scan_S (Mhi dead)
  u16* hb   = (u16*)khat;      // after make_MBG (khat dead)

  // 0) casts (permuted staging layout)
  cast_bf16<<<1024, 256, 0, stream>>>(x, xb, 262144);
  transpose_bf16<<<dim3(32, 96), 256, 0, stream>>>(w_qkvz, wqt, H_, QN_);
  // 1) qkv|z = x @ w_qkvz
  gemm_bf16<<<768, 256, 0, stream>>>(xb, wqt, qkvraw, CD_, zbuf, VD_,
                                     CD_, T_, QN_, H_);
  // 2) beta / g
  ba_gbeta<<<T_, 256, 0, stream>>>(x, w_ba, a_log, dt_bias, gbuf, bbuf);
  // 3) fused conv + silu + k-l2norm
  conv_silu_k<<<T_, 512, 0, stream>>>(qkvraw, conv_w, conv_b, qkvc, khat);
  // 4) chunk-local precompute (parallel)
  chunk_prep<<<dim3(NC_, HV_), 256, 0, stream>>>(
      qkvc, khat, gbuf, bbuf, cgbuf, Wtg, Ug, Mqg, pQg);
  // 5) per-chunk transition/output operators (parallel)
  make_MBG<<<dim3(NC_, HV_), 256, 0, stream>>>(
      Wtg, pQg, Ug, Mqg, khat, cgbuf, Mhi, Mlo, Bg, Gtg);
  // 6) sequential state scan
  scan_S<<<64, 256, 0, stream>>>(Mhi, Mlo, Bg, Sg);
  // 7) w_o^T cast (Mhi region now dead)
  transpose_bf16<<<dim3(32, 32), 256, 0, stream>>>(w_o, wot, VD_, H_);
  // 8) per-chunk outputs (parallel)
  chunk_out<<<dim3(NC_, HV_), 256, 0, stream>>>(Mqg, Ug, Gtg, Sg, obuf);
  // 9) gated rmsnorm -> bf16 h (permuted)
  gated_rmsnorm<<<dim3(T_, HV_), 128, 0, stream>>>(obuf, zbuf, norm_w, hb);
  // 10) out = h @ w_o
  gemm_bf16<<<256, 256, 0, stream>>>(hb, wot, out, VD_, out, VD_,
                                     VD_, T_, VD_, H_);
}

// Round 8
// 259.733 us; speedup vs baseline: 5.1868x; 1.0309x over previous
//
#include <hip/hip_runtime.h>
#include <math.h>

typedef unsigned short u16;
using us4  = __attribute__((ext_vector_type(4))) unsigned short;
using us8  = __attribute__((ext_vector_type(8))) unsigned short;
using bf16x8 = __attribute__((ext_vector_type(8))) __bf16;
using f32x4v = __attribute__((ext_vector_type(4))) float;

// Problem constants
#define T_    1024
#define H_    2048
#define HK_   8
#define HV_   16
#define KD_   1024
#define VD_   2048
#define CD_   4096
#define QN_   6144   // 2*KD + 2*VD
#define NC_   16     // number of chunks
#define C_    64     // chunk length

__device__ __forceinline__ u16 f2bf(float f) {
  unsigned u = __float_as_uint(f);
  u += 0x7fffu + ((u >> 16) & 1u);   // RNE
  return (u16)(u >> 16);
}
__device__ __forceinline__ float bf2f(u16 h) {
  return __uint_as_float(((unsigned)h) << 16);
}
// staging layout for gemm: within each 64-elem k-group, 8-elem chunk c of
// row r is stored at chunk position c ^ (r&7).
__device__ __forceinline__ int permk3(int r, int k) {
  return (k & ~63) | ((((k >> 3) & 7) ^ (r & 7)) << 3) | (k & 7);
}

// ---------------------------------------------------------------------------
// x f32 -> bf16 with chunk permutation (row length 2048)
// ---------------------------------------------------------------------------
__global__ void cast_bf16(const float* __restrict__ in, u16* __restrict__ out,
                          int n8) {
  int i = blockIdx.x * 256 + threadIdx.x;   // 16B-chunk index
  if (i >= n8) return;
  float4 a = ((const float4*)in)[i * 2];
  float4 b = ((const float4*)in)[i * 2 + 1];
  us8 r = {f2bf(a.x), f2bf(a.y), f2bf(a.z), f2bf(a.w),
           f2bf(b.x), f2bf(b.y), f2bf(b.z), f2bf(b.w)};
  const int row = i >> 8;                   // 2048/8 = 256 chunks per row
  const int ip = (i & ~7) | ((i & 7) ^ (row & 7));
  *(us8*)&out[(size_t)ip * 8] = r;
}

// ---------------------------------------------------------------------------
// f32 [R][C] -> bf16 [C][R] transpose + cast + chunk permutation
// ---------------------------------------------------------------------------
__global__ __launch_bounds__(256) void transpose_bf16(
    const float* __restrict__ in, u16* __restrict__ out, int R, int C) {
  __shared__ float tile[64][65];
  const int r0 = blockIdx.x * 64, c0 = blockIdx.y * 64;
  const int t = threadIdx.x;
  const int tr = t >> 4, tc4 = (t & 15) * 4;
#pragma unroll
  for (int i = 0; i < 4; ++i) {
    float4 v = *(const float4*)&in[(size_t)(r0 + tr + i * 16) * C + c0 + tc4];
    tile[tr + i * 16][tc4 + 0] = v.x;
    tile[tr + i * 16][tc4 + 1] = v.y;
    tile[tr + i * 16][tc4 + 2] = v.z;
    tile[tr + i * 16][tc4 + 3] = v.w;
  }
  __syncthreads();
#pragma unroll
  for (int i = 0; i < 4; ++i) {
    int oc = tr + i * 16;
    int row = c0 + oc;
    int k = r0 + tc4;
    us4 w = {f2bf(tile[tc4 + 0][oc]), f2bf(tile[tc4 + 1][oc]),
             f2bf(tile[tc4 + 2][oc]), f2bf(tile[tc4 + 3][oc])};
    *(us4*)&out[(size_t)row * R + permk3(row, k)] = w;
  }
}

// ---------------------------------------------------------------------------
// bf16 MFMA GEMM: C = A[M,K] @ Bt[N,K]^T, f32 out. 128x64 tile, BK=64,
// 2-phase double-buffered LDS pipeline, XCD-grouped 1D block mapping,
// 3-bit permuted staging. Output routed to Cq (cols < zsplit) or Cz.
// ---------------------------------------------------------------------------
__device__ __forceinline__ void gload_lds16(const void* g, void* l) {
  __builtin_amdgcn_global_load_lds(
      (const __attribute__((address_space(1))) void*)g,
      (__attribute__((address_space(3))) void*)l, 16, 0, 0);
}

__global__ __launch_bounds__(256) void gemm_bf16(
    const u16* __restrict__ A, const u16* __restrict__ Bt,
    float* __restrict__ Cq, int ldq, float* __restrict__ Cz, int ldz,
    int zsplit, int M, int N, int K) {
  __shared__ __align__(16) u16 As[2][8192];   // [128][64]
  __shared__ __align__(16) u16 Bs[2][4096];   // [64][64]
  const int tid  = threadIdx.x;
  const int wave = tid >> 6, lane = tid & 63;
  const int gy = N >> 6;
  const int ncolpx = gy >> 3;
  const int bid = blockIdx.x;
  const int xcd = bid & 7, idx = bid >> 3;
  const int row0 = (idx / ncolpx) * 128;
  const int col0 = (xcd * ncolpx + idx % ncolpx) * 64;
  const int wr = wave >> 1, wc = wave & 1;
  const int fr = lane & 15, fq = lane >> 4;

  const int sr8 = lane >> 3;
  const int sc8 = (lane & 7) * 8;
  const u16* gA = A  + (size_t)(row0 + wave * 32 + sr8) * K + sc8;
  const u16* gB = Bt + (size_t)(col0 + wave * 16 + sr8) * K + sc8;

  f32x4v acc[4][2] = {};
  const int nt = K >> 6;

  auto stage = [&](int p, int k0) {
#pragma unroll
    for (int j = 0; j < 4; ++j)
      gload_lds16(gA + (size_t)(j * 8) * K + k0,
                  &As[p][(wave * 32 + j * 8) * 64]);
#pragma unroll
    for (int j = 0; j < 2; ++j)
      gload_lds16(gB + (size_t)(j * 8) * K + k0,
                  &Bs[p][(wave * 16 + j * 8) * 64]);
  };

  stage(0, 0);
  asm volatile("s_waitcnt vmcnt(0)" ::: "memory");
  __syncthreads();

  int p = 0;
  for (int it = 0; it < nt; ++it) {
    if (it + 1 < nt) stage(p ^ 1, (it + 1) * 64);
#pragma unroll
    for (int kt = 0; kt < 2; ++kt) {
      bf16x8 af[4], bff[2];
#pragma unroll
      for (int mi = 0; mi < 4; ++mi) {
        const int r = wr * 64 + mi * 16 + fr;
        af[mi] = *(const bf16x8*)
            &As[p][r * 64 + kt * 32 + (((kt * 4 + fq) ^ (r & 7)) & 3) * 8
                   + ((((kt * 4 + fq) ^ (r & 7)) >> 2) - kt) * 32];
      }
#pragma unroll
      for (int ni = 0; ni < 2; ++ni) {
        const int r = wc * 32 + ni * 16 + fr;
        bff[ni] = *(const bf16x8*)
            &Bs[p][r * 64 + kt * 32 + (((kt * 4 + fq) ^ (r & 7)) & 3) * 8
                   + ((((kt * 4 + fq) ^ (r & 7)) >> 2) - kt) * 32];
      }
#pragma unroll
      for (int mi = 0; mi < 4; ++mi)
#pragma unroll
        for (int ni = 0; ni < 2; ++ni)
          acc[mi][ni] = __builtin_amdgcn_mfma_f32_16x16x32_bf16(
              af[mi], bff[ni], acc[mi][ni], 0, 0, 0);
    }
    if (it + 1 < nt) {
      asm volatile("s_waitcnt vmcnt(0)" ::: "memory");
      __syncthreads();
    }
    p ^= 1;
  }

  float* Cp; int ldc, cb;
  if (col0 < zsplit) { Cp = Cq; ldc = ldq; cb = col0; }
  else               { Cp = Cz; ldc = ldz; cb = col0 - zsplit; }
#pragma unroll
  for (int mi = 0; mi < 4; ++mi)
#pragma unroll
    for (int ni = 0; ni < 2; ++ni) {
      const int r  = row0 + wr * 64 + mi * 16 + fq * 4;
      const int cc = cb + wc * 32 + ni * 16 + fr;
#pragma unroll
      for (int j = 0; j < 4; ++j)
        Cp[(size_t)(r + j) * ldc + cc] = acc[mi][ni][j];
    }
}

// ---------------------------------------------------------------------------
// ba = x @ w_ba -> beta = sigmoid(b), g = -exp(a_log)*softplus(a+dt_bias)
// ---------------------------------------------------------------------------
__global__ __launch_bounds__(256) void ba_gbeta(
    const float* __restrict__ x, const float* __restrict__ w_ba,
    const float* __restrict__ a_log, const float* __restrict__ dt_bias,
    float* __restrict__ g, float* __restrict__ beta) {
  const int t = blockIdx.x;
  const int tid = threadIdx.x;
  __shared__ float xs[2048];
  __shared__ float red[8][32];
  {
    float4 v = *(const float4*)&x[(size_t)t * H_ + tid * 4];
    *(float4*)&xs[tid * 4] = v;
    float4 w = *(const float4*)&x[(size_t)t * H_ + 1024 + tid * 4];
    *(float4*)&xs[1024 + tid * 4] = w;
  }
  __syncthreads();
  const int c = tid & 31;
  const int chunk = tid >> 5;
  float p = 0.f;
  const int kb = chunk * 256;
#pragma unroll 4
  for (int k = kb; k < kb + 256; ++k) p = fmaf(xs[k], w_ba[k * 32 + c], p);
  red[chunk][c] = p;
  __syncthreads();
  if (tid < 32) {
    float s = 0.f;
#pragma unroll
    for (int i = 0; i < 8; ++i) s += red[i][c];
    if (c < 16) {
      beta[t * 16 + c] = 1.f / (1.f + expf(-s));
    } else {
      int h = c - 16;
      float xx = s + dt_bias[h];
      float sp = xx > 20.f ? xx : log1pf(expf(xx));
      g[t * 16 + h] = -expf(a_log[h]) * sp;
    }
  }
}

// ---------------------------------------------------------------------------
// fused causal depthwise conv1d (K=4) + SiLU + k-l2norm.
// ---------------------------------------------------------------------------
__global__ __launch_bounds__(512) void conv_silu_k(
    const float* __restrict__ qkvraw, const float* __restrict__ conv_w,
    const float* __restrict__ conv_b, float* __restrict__ qkvc,
    float* __restrict__ khat) {
  const int t = blockIdx.x;
  const int tid = threadIdx.x;
  const int c0 = tid * 8;
  float acc[8];
  float4 cb0 = *(const float4*)&conv_b[c0];
  float4 cb1 = *(const float4*)&conv_b[c0 + 4];
  acc[0] = cb0.x; acc[1] = cb0.y; acc[2] = cb0.z; acc[3] = cb0.w;
  acc[4] = cb1.x; acc[5] = cb1.y; acc[6] = cb1.z; acc[7] = cb1.w;
  float wv[8][4];
#pragma unroll
  for (int i = 0; i < 8; i += 2) {
    float4 w0 = *(const float4*)&conv_w[(c0 + i) * 4];
    float4 w1 = *(const float4*)&conv_w[(c0 + i + 1) * 4];
    wv[i][0] = w0.x; wv[i][1] = w0.y; wv[i][2] = w0.z; wv[i][3] = w0.w;
    wv[i+1][0] = w1.x; wv[i+1][1] = w1.y; wv[i+1][2] = w1.z; wv[i+1][3] = w1.w;
  }
#pragma unroll
  for (int j = 0; j < 4; ++j) {
    int tt = t - 3 + j;
    if (tt >= 0) {
      float4 a = *(const float4*)&qkvraw[(size_t)tt * CD_ + c0];
      float4 b = *(const float4*)&qkvraw[(size_t)tt * CD_ + c0 + 4];
      float xv[8] = {a.x, a.y, a.z, a.w, b.x, b.y, b.z, b.w};
#pragma unroll
      for (int i = 0; i < 8; ++i) acc[i] = fmaf(xv[i], wv[i][j], acc[i]);
    }
  }
  float y[8];
#pragma unroll
  for (int i = 0; i < 8; ++i) y[i] = acc[i] / (1.f + expf(-acc[i]));

  if (tid < 128 || tid >= 256) {
    float4 o0 = {y[0], y[1], y[2], y[3]};
    float4 o1 = {y[4], y[5], y[6], y[7]};
    *(float4*)&qkvc[(size_t)t * CD_ + c0]     = o0;
    *(float4*)&qkvc[(size_t)t * CD_ + c0 + 4] = o1;
  } else {
    float ss = 0.f;
#pragma unroll
    for (int i = 0; i < 8; ++i) ss = fmaf(y[i], y[i], ss);
#pragma unroll
    for (int off = 1; off < 16; off <<= 1) ss += __shfl_xor(ss, off);
    float rs = rsqrtf(ss + 1e-6f);
    const int head = (c0 - 1024) >> 7;
    const int d0 = (c0 - 1024) & 127;
    float4 o0 = {y[0] * rs, y[1] * rs, y[2] * rs, y[3] * rs};
    float4 o1 = {y[4] * rs, y[5] * rs, y[6] * rs, y[7] * rs};
    float* kout = &khat[((size_t)t * HK_ + head) * 128 + d0];
    *(float4*)&kout[0] = o0;
    *(float4*)&kout[4] = o1;
  }
}

// ---------------------------------------------------------------------------
// Chunked gated delta rule, phase A (parallel over 16 chunks x 16 heads).
// ---------------------------------------------------------------------------
#define SWZ(r) (((r) >> 2) & 7)

__device__ __forceinline__ float4 ldsw4(const float* base, int r, int dblk) {
  return *(const float4*)&base[r * 128 + ((dblk ^ SWZ(r)) << 2)];
}
__device__ __forceinline__ float ldsw1(const float* base, int r, int d) {
  return base[r * 128 + ((((d) >> 2) ^ SWZ(r)) << 2) + ((d) & 3)];
}

__global__ __launch_bounds__(256) void chunk_prep(
    const float* __restrict__ qkvc, const float* __restrict__ khat,
    const float* __restrict__ g, const float* __restrict__ beta,
    float* __restrict__ cgbuf, float* __restrict__ Wtg, float* __restrict__ Ug,
    float* __restrict__ Mqg, float* __restrict__ pQg) {
  const int c = blockIdx.x, hv = blockIdx.y, hk = hv >> 1;
  const int cid = c * 16 + hv;
  const int tid = threadIdx.x;
  __shared__ float Kl[8192], Ql[8192];   // swizzled [64][128]
  __shared__ float AM[8320];             // At[64][65] | Mq[64][65]; later Utr
  __shared__ float cgl[64], bl[64], bp[64], rsl[64];
  float* At = AM;
  float* Mq = AM + 4160;

#pragma unroll
  for (int it = 0; it < 8; ++it) {
    int flat = it * 1024 + tid * 4;
    int row = flat >> 7, d = flat & 127;
    int pb = ((d >> 2) ^ SWZ(row)) << 2;
    int gt = c * 64 + row;
    float4 kv = *(const float4*)&khat[((size_t)gt * HK_ + hk) * 128 + d];
    float4 qv = *(const float4*)&qkvc[(size_t)gt * CD_ + hk * 128 + d];
    *(float4*)&Kl[row * 128 + pb] = kv;
    *(float4*)&Ql[row * 128 + pb] = qv;
  }
  if (tid < 64) {
    float s = g[(size_t)(c * 64 + tid) * HV_ + hv];
#pragma unroll
    for (int off = 1; off < 64; off <<= 1) {
      float t = __shfl_up(s, off);
      if (tid >= off) s += t;
    }
    cgl[tid] = s;
    cgbuf[cid * 64 + tid] = s;
    bl[tid] = beta[(size_t)(c * 64 + tid) * HV_ + hv];
  }
  __syncthreads();
  if (tid < 64) {
    float sq = 0.f;
#pragma unroll
    for (int dblk = 0; dblk < 32; ++dblk) {
      float4 q4 = ldsw4(Ql, tid, dblk);
      sq = fmaf(q4.x, q4.x, sq); sq = fmaf(q4.y, q4.y, sq);
      sq = fmaf(q4.z, q4.z, sq); sq = fmaf(q4.w, q4.w, sq);
    }
    rsl[tid] = rsqrtf(sq + 1e-6f) * 0.08838834764831845f;
    bp[tid] = bl[tid] * expf(cgl[tid]);
  }
  __syncthreads();

  const int i0 = (tid >> 4) * 4, j0 = (tid & 15) * 4;
  float kk[4][4], qk[4][4];
#pragma unroll
  for (int a = 0; a < 4; ++a)
#pragma unroll
    for (int b = 0; b < 4; ++b) { kk[a][b] = 0.f; qk[a][b] = 0.f; }
  for (int dblk = 0; dblk < 32; ++dblk) {
    float4 ka[4], qa[4], kb[4];
#pragma unroll
    for (int a = 0; a < 4; ++a) {
      ka[a] = ldsw4(Kl, i0 + a, dblk);
      qa[a] = ldsw4(Ql, i0 + a, dblk);
    }
#pragma unroll
    for (int b = 0; b < 4; ++b) kb[b] = ldsw4(Kl, j0 + b, dblk);
#pragma unroll
    for (int a = 0; a < 4; ++a)
#pragma unroll
      for (int b = 0; b < 4; ++b) {
        kk[a][b] = fmaf(ka[a].x, kb[b].x, kk[a][b]);
        kk[a][b] = fmaf(ka[a].y, kb[b].y, kk[a][b]);
        kk[a][b] = fmaf(ka[a].z, kb[b].z, kk[a][b]);
        kk[a][b] = fmaf(ka[a].w, kb[b].w, kk[a][b]);
        qk[a][b] = fmaf(qa[a].x, kb[b].x, qk[a][b]);
        qk[a][b] = fmaf(qa[a].y, kb[b].y, qk[a][b]);
        qk[a][b] = fmaf(qa[a].z, kb[b].z, qk[a][b]);
        qk[a][b] = fmaf(qa[a].w, kb[b].w, qk[a][b]);
      }
  }
#pragma unroll
  for (int a = 0; a < 4; ++a)
#pragma unroll
    for (int b = 0; b < 4; ++b) {
      int i = i0 + a, j = j0 + b;
      float e = expf(cgl[i] - cgl[j]);
      At[j * 65 + i] = (j < i) ? (-bl[i] * e * kk[a][b]) : 0.f;
      Mq[j * 65 + i] = (j <= i) ? (rsl[i] * e * qk[a][b]) : 0.f;
    }
  __syncthreads();

  float X[64];
  if (tid < 128) {
#pragma unroll
    for (int j = 0; j < 64; ++j) X[j] = bp[j] * ldsw1(Kl, j, tid);
  } else {
    const int m = tid - 128;
#pragma unroll
    for (int j = 0; j < 64; ++j)
      X[j] = bl[j] * qkvc[(size_t)(c * 64 + j) * CD_ + 2 * KD_ + hv * 128 + m];
  }
#pragma unroll
  for (int it = 0; it < 16; ++it) {
    int f = it * 256 + tid;
    int j = f >> 6, i = f & 63;
    Mqg[(size_t)cid * 4096 + f] = Mq[j * 65 + i];
  }
#pragma unroll
  for (int j = 0; j < 63; ++j) {
    float xj = X[j];
#pragma unroll
    for (int i = j + 1; i < 64; ++i) X[i] = fmaf(At[j * 65 + i], xj, X[i]);
  }
  __syncthreads();

  if (tid < 128) {
    size_t baseo = ((size_t)cid * 128 + tid) * 64;
#pragma unroll
    for (int j4 = 0; j4 < 16; ++j4) {
      float4 v = {X[j4 * 4], X[j4 * 4 + 1], X[j4 * 4 + 2], X[j4 * 4 + 3]};
      *(float4*)&Wtg[baseo + j4 * 4] = v;
    }
  } else {
    const int m = tid - 128;
    float* Utr = AM;
#pragma unroll
    for (int j = 0; j < 64; ++j) Utr[j * 128 + m] = X[j];
  }
  __syncthreads();
  {
    const float* Utr = AM;
#pragma unroll
    for (int it = 0; it < 8; ++it) {
      int flat = it * 1024 + tid * 4;
      *(float4*)&Ug[(size_t)cid * 8192 + flat] = *(const float4*)&Utr[flat];
    }
    const int i = tid & 63;
    const float ei = expf(cgl[i]) * rsl[i];
#pragma unroll
    for (int it = 0; it < 32; ++it) {
      int d = it * 4 + (tid >> 6);
      pQg[(size_t)cid * 8192 + d * 64 + i] = ei * ldsw1(Ql, i, d);
    }
  }
}

// ---------------------------------------------------------------------------
// make_MBG (parallel, 256 blocks)
// ---------------------------------------------------------------------------
__global__ __launch_bounds__(256) void make_MBG(
    const float* __restrict__ Wtg, const float* __restrict__ pQg,
    const float* __restrict__ Ug, const float* __restrict__ Mqg,
    const float* __restrict__ khat, const float* __restrict__ cgbuf,
    u16* __restrict__ Mhi, u16* __restrict__ Mlo,
    float* __restrict__ Bg, float* __restrict__ Gtg) {
  const int c = blockIdx.x, hv = blockIdx.y, hk = hv >> 1;
  const int cid = c * 16 + hv;
  const int tid = threadIdx.x;
  __shared__ float Wl[64 * 128];   // W[j][d]
  __shared__ float Kel[64 * 128];  // esc_j * khat_j[d]
  __shared__ float Ul[64 * 128];
  __shared__ float Mql[64 * 64];
  const float cg63 = cgbuf[cid * 64 + 63];
  const float pC = expf(cg63);
#pragma unroll
  for (int it = 0; it < 8; ++it) {
    int f = it * 1024 + tid * 4;       // f = d*64 + j
    int d = f >> 6, j = f & 63;
    float4 w = *(const float4*)&Wtg[(size_t)cid * 8192 + f];
    Wl[(j + 0) * 128 + d] = w.x;
    Wl[(j + 1) * 128 + d] = w.y;
    Wl[(j + 2) * 128 + d] = w.z;
    Wl[(j + 3) * 128 + d] = w.w;
  }
#pragma unroll
  for (int it = 0; it < 8; ++it) {
    int f = it * 1024 + tid * 4;       // f = j*128 + d
    int j = f >> 7, d = f & 127;
    float esc = expf(cg63 - cgbuf[cid * 64 + j]);
    float4 kv = *(const float4*)&khat[((size_t)(c * 64 + j) * HK_ + hk) * 128 + d];
    float4 uv = *(const float4*)&Ug[(size_t)cid * 8192 + f];
    kv.x *= esc; kv.y *= esc; kv.z *= esc; kv.w *= esc;
    *(float4*)&Kel[f] = kv;
    *(float4*)&Ul[f] = uv;
  }
#pragma unroll
  for (int it = 0; it < 4; ++it) {
    int f = it * 1024 + tid * 4;
    *(float4*)&Mql[f] = *(const float4*)&Mqg[(size_t)cid * 4096 + f];
  }
  __syncthreads();

  const int d0 = (tid & 15) * 8, n0 = (tid >> 4) * 8;
  float ma[8][8] = {}, ba[8][8] = {};
  for (int j = 0; j < 64; ++j) {
    float4 k0 = *(const float4*)&Kel[j * 128 + d0];
    float4 k1 = *(const float4*)&Kel[j * 128 + d0 + 4];
    float4 w0 = *(const float4*)&Wl[j * 128 + n0];
    float4 w1 = *(const float4*)&Wl[j * 128 + n0 + 4];
    float4 u0 = *(const float4*)&Ul[j * 128 + n0];
    float4 u1 = *(const float4*)&Ul[j * 128 + n0 + 4];
    float ke[8] = {k0.x, k0.y, k0.z, k0.w, k1.x, k1.y, k1.z, k1.w};
    float wv[8] = {w0.x, w0.y, w0.z, w0.w, w1.x, w1.y, w1.z, w1.w};
    float uv[8] = {u0.x, u0.y, u0.z, u0.w, u1.x, u1.y, u1.z, u1.w};
#pragma unroll
    for (int a = 0; a < 8; ++a)
#pragma unroll
      for (int b = 0; b < 8; ++b) {
        ma[a][b] = fmaf(ke[a], wv[b], ma[a][b]);
        ba[a][b] = fmaf(ke[a], uv[b], ba[a][b]);
      }
  }
#pragma unroll
  for (int a = 0; a < 8; ++a) {
    const int d = d0 + a;
    us8 hi, lo;
#pragma unroll
    for (int b = 0; b < 8; ++b) {
      float m = ((d == n0 + b) ? pC : 0.f) - ma[a][b];
      u16 h = f2bf(m);
      hi[b] = h;
      lo[b] = f2bf(m - bf2f(h));
    }
    *(us8*)&Mhi[(size_t)cid * 16384 + d * 128 + n0] = hi;
    *(us8*)&Mlo[(size_t)cid * 16384 + d * 128 + n0] = lo;
    float4 b0 = {ba[a][0], ba[a][1], ba[a][2], ba[a][3]};
    float4 b1 = {ba[a][4], ba[a][5], ba[a][6], ba[a][7]};
    *(float4*)&Bg[(size_t)cid * 16384 + d * 128 + n0]     = b0;
    *(float4*)&Bg[(size_t)cid * 16384 + d * 128 + n0 + 4] = b1;
  }

  const int dg = (tid & 31) * 4, ig = (tid >> 5) * 8;
  float ga[4][8] = {};
  for (int j = 0; j < 64; ++j) {
    float4 w4 = *(const float4*)&Wl[j * 128 + dg];
    float4 m0 = *(const float4*)&Mql[j * 64 + ig];
    float4 m1 = *(const float4*)&Mql[j * 64 + ig + 4];
    float wv[4] = {w4.x, w4.y, w4.z, w4.w};
    float mv[8] = {m0.x, m0.y, m0.z, m0.w, m1.x, m1.y, m1.z, m1.w};
#pragma unroll
    for (int a = 0; a < 4; ++a)
#pragma unroll
      for (int b = 0; b < 8; ++b) ga[a][b] = fmaf(wv[a], mv[b], ga[a][b]);
  }
#pragma unroll
  for (int a = 0; a < 4; ++a) {
    const int d = dg + a;
    float4 p0 = *(const float4*)&pQg[(size_t)cid * 8192 + d * 64 + ig];
    float4 p1 = *(const float4*)&pQg[(size_t)cid * 8192 + d * 64 + ig + 4];
    float4 g0 = {p0.x - ga[a][0], p0.y - ga[a][1], p0.z - ga[a][2], p0.w - ga[a][3]};
    float4 g1 = {p1.x - ga[a][4], p1.y - ga[a][5], p1.z - ga[a][6], p1.w - ga[a][7]};
    *(float4*)&Gtg[(size_t)cid * 8192 + d * 64 + ig]     = g0;
    *(float4*)&Gtg[(size_t)cid * 8192 + d * 64 + ig + 4] = g1;
  }
}

// ---------------------------------------------------------------------------
// scan_S v3: 64 blocks = 16 heads x 4 col-slices, XCD-grouped, 512 threads
// (8 waves x 16 M-rows each) so the double-buffered M register prefetch
// fits without spilling (~64 VGPR for M vs 128 at 4 waves).
// ---------------------------------------------------------------------------
__global__ __launch_bounds__(512) void scan_S(
    const u16* __restrict__ Mhi, const u16* __restrict__ Mlo,
    const float* __restrict__ Bg, float* __restrict__ Sg) {
  const int flat = blockIdx.x;
  const int hv = (flat & 7) + 8 * (flat >> 5);
  const int vs = (flat >> 3) & 3;
  const int tid = threadIdx.x;
  const int wave = tid >> 6, lane = tid & 63;
  const int fr = lane & 15, fq = lane >> 4;
  const int wr = wave * 16;       // this wave's 16 output rows
  const int m0 = vs * 32;

  __shared__ u16 Sh[2][4096];
  __shared__ u16 Sl[2][4096];

  for (int i = tid; i < 4096; i += 512) { Sh[0][i] = 0; Sl[0][i] = 0; }
  {
    float* s0 = Sg + (size_t)hv * 16384 + m0;
#pragma unroll
    for (int it = 0; it < 8; ++it) {
      int idx = it * 512 + tid;
      s0[(size_t)(idx >> 5) * 128 + (idx & 31)] = 0.f;
    }
  }
  __syncthreads();

  bf16x8 MhA[4], MlA[4], MhB[4], MlB[4];
  {
    const u16* Mh0 = Mhi + (size_t)hv * 16384;
    const u16* Ml0 = Mlo + (size_t)hv * 16384;
#pragma unroll
    for (int kt = 0; kt < 4; ++kt) {
      size_t off = (size_t)(wr + fr) * 128 + kt * 32 + fq * 8;
      MhA[kt] = *(const bf16x8*)&Mh0[off];
      MlA[kt] = *(const bf16x8*)&Ml0[off];
    }
  }
  int p = 0;

  auto step = [&](int c, bf16x8 (&MhC)[4], bf16x8 (&MlC)[4],
                  bf16x8 (&MhN)[4], bf16x8 (&MlN)[4]) {
    if (c + 1 < NC_ - 1) {
      const u16* MhP = Mhi + (size_t)((c + 1) * 16 + hv) * 16384;
      const u16* MlP = Mlo + (size_t)((c + 1) * 16 + hv) * 16384;
#pragma unroll
      for (int kt = 0; kt < 4; ++kt) {
        size_t off = (size_t)(wr + fr) * 128 + kt * 32 + fq * 8;
        MhN[kt] = *(const bf16x8*)&MhP[off];
        MlN[kt] = *(const bf16x8*)&MlP[off];
      }
    }
    const float* Bc = Bg + (size_t)(c * 16 + hv) * 16384 + m0;
    float bv[2][4];
#pragma unroll
    for (int b = 0; b < 2; ++b)
#pragma unroll
      for (int j = 0; j < 4; ++j)
        bv[b][j] = Bc[(size_t)(wr + fq * 4 + j) * 128 + b * 16 + fr];

    f32x4v acc[2] = {};
#pragma unroll
    for (int kt = 0; kt < 4; ++kt) {
      bf16x8 Bh[2], Bl[2];
#pragma unroll
      for (int b = 0; b < 2; ++b) {
        int m = b * 16 + fr;
        int byte = m * 256 + ((kt * 64 + fq * 16) ^ ((m & 7) << 4));
        Bh[b] = *(const bf16x8*)((const char*)&Sh[p][0] + byte);
        Bl[b] = *(const bf16x8*)((const char*)&Sl[p][0] + byte);
      }
#pragma unroll
      for (int b = 0; b < 2; ++b) {
        acc[b] = __builtin_amdgcn_mfma_f32_16x16x32_bf16(
            MlC[kt], Bh[b], acc[b], 0, 0, 0);
        acc[b] = __builtin_amdgcn_mfma_f32_16x16x32_bf16(
            MhC[kt], Bl[b], acc[b], 0, 0, 0);
        acc[b] = __builtin_amdgcn_mfma_f32_16x16x32_bf16(
            MhC[kt], Bh[b], acc[b], 0, 0, 0);
      }
    }
    float* Sn = Sg + (size_t)((c + 1) * 16 + hv) * 16384 + m0;
#pragma unroll
    for (int b = 0; b < 2; ++b) {
      const int k0 = wr + fq * 4;
      const int m = b * 16 + fr;
      us4 h4, l4;
#pragma unroll
      for (int j = 0; j < 4; ++j) {
        float v = acc[b][j] + bv[b][j];
        Sn[(size_t)(k0 + j) * 128 + m] = v;
        u16 h = f2bf(v);
        h4[j] = h;
        l4[j] = f2bf(v - bf2f(h));
      }
      int byte = m * 256 + (((k0 * 2)) ^ ((m & 7) << 4));
      *(us4*)((char*)&Sh[p ^ 1][0] + byte) = h4;
      *(us4*)((char*)&Sl[p ^ 1][0] + byte) = l4;
    }
    __syncthreads();
    p ^= 1;
  };

  for (int cc = 0; cc < NC_ - 1; cc += 2) {
    step(cc, MhA, MlA, MhB, MlB);
    if (cc + 1 < NC_ - 1) step(cc + 1, MhB, MlB, MhA, MlA);
  }
}

// ---------------------------------------------------------------------------
// chunk_out (parallel, 256 blocks): o = Mq^T U + G*S
// ---------------------------------------------------------------------------
__global__ __launch_bounds__(256) void chunk_out(
    const float* __restrict__ Mqg, const float* __restrict__ Ug,
    const float* __restrict__ Gtg, const float* __restrict__ Sg,
    float* __restrict__ o) {
  const int c = blockIdx.x, hv = blockIdx.y;
  const int cid = c * 16 + hv;
  const int tid = threadIdx.x;
  __shared__ float Mql[64 * 64];
  __shared__ float Ul[64 * 128];
  __shared__ float Gtl[128 * 64];
  __shared__ float Sl[128 * 128];
#pragma unroll
  for (int it = 0; it < 4; ++it) {
    int f = it * 1024 + tid * 4;
    *(float4*)&Mql[f] = *(const float4*)&Mqg[(size_t)cid * 4096 + f];
  }
#pragma unroll
  for (int it = 0; it < 8; ++it) {
    int f = it * 1024 + tid * 4;
    *(float4*)&Ul[f]  = *(const float4*)&Ug[(size_t)cid * 8192 + f];
    *(float4*)&Gtl[f] = *(const float4*)&Gtg[(size_t)cid * 8192 + f];
  }
#pragma unroll
  for (int it = 0; it < 16; ++it) {
    int f = it * 1024 + tid * 4;
    *(float4*)&Sl[f] = *(const float4*)&Sg[(size_t)cid * 16384 + f];
  }
  __syncthreads();

  const int i0 = (tid & 15) * 4, m0 = (tid >> 4) * 8;
  float oa[4][8] = {};
  for (int j = 0; j < 64; ++j) {
    float4 mq = *(const float4*)&Mql[j * 64 + i0];
    float4 u0 = *(const float4*)&Ul[j * 128 + m0];
    float4 u1 = *(const float4*)&Ul[j * 128 + m0 + 4];
    float mv[4] = {mq.x, mq.y, mq.z, mq.w};
    float uv[8] = {u0.x, u0.y, u0.z, u0.w, u1.x, u1.y, u1.z, u1.w};
#pragma unroll
    for (int a = 0; a < 4; ++a)
#pragma unroll
      for (int b = 0; b < 8; ++b) oa[a][b] = fmaf(mv[a], uv[b], oa[a][b]);
  }
  for (int d = 0; d < 128; ++d) {
    float4 gt = *(const float4*)&Gtl[d * 64 + i0];
    float4 s0 = *(const float4*)&Sl[d * 128 + m0];
    float4 s1 = *(const float4*)&Sl[d * 128 + m0 + 4];
    float gv[4] = {gt.x, gt.y, gt.z, gt.w};
    float sv[8] = {s0.x, s0.y, s0.z, s0.w, s1.x, s1.y, s1.z, s1.w};
#pragma unroll
    for (int a = 0; a < 4; ++a)
#pragma unroll
      for (int b = 0; b < 8; ++b) oa[a][b] = fmaf(gv[a], sv[b], oa[a][b]);
  }
#pragma unroll
  for (int a = 0; a < 4; ++a) {
    const int t = c * 64 + i0 + a;
    float4 o0 = {oa[a][0], oa[a][1], oa[a][2], oa[a][3]};
    float4 o1 = {oa[a][4], oa[a][5], oa[a][6], oa[a][7]};
    *(float4*)&o[((size_t)t * HV_ + hv) * 128 + m0]     = o0;
    *(float4*)&o[((size_t)t * HV_ + hv) * 128 + m0 + 4] = o1;
  }
}

// ---------------------------------------------------------------------------
// h = o * silu(z); rmsnorm; -> bf16 (permuted staging layout for gemm2)
// ---------------------------------------------------------------------------
__global__ void gated_rmsnorm(const float* __restrict__ o,
                              const float* __restrict__ zbuf,
                              const float* __restrict__ norm_w,
                              u16* __restrict__ h) {
  const int t = blockIdx.x, hv = blockIdx.y, d = threadIdx.x;
  float ov = o[((size_t)t * HV_ + hv) * 128 + d];
  float zv = zbuf[(size_t)t * VD_ + hv * 128 + d];
  float hc = ov * (zv / (1.f + expf(-zv)));
  float ss = hc * hc;
#pragma unroll
  for (int off = 32; off >= 1; off >>= 1) ss += __shfl_xor(ss, off);
  __shared__ float s2[2];
  if ((d & 63) == 0) s2[d >> 6] = ss;
  __syncthreads();
  float tot = s2[0] + s2[1];
  float r = rsqrtf(tot * (1.f / 128.f) + 1e-6f);
  const int k = hv * 128 + d;
  h[(size_t)t * VD_ + permk3(t, k)] = f2bf(hc * r * norm_w[d]);
}

// ---------------------------------------------------------------------------
extern "C" void kernel_launch(void* const* d_in, const int* in_sizes, int n_in,
                              void* d_out, int out_size, void* d_ws, size_t ws_size,
                              hipStream_t stream) {
  const float* x       = (const float*)d_in[0];
  const float* w_qkvz  = (const float*)d_in[1];
  const float* w_ba    = (const float*)d_in[2];
  const float* conv_w  = (const float*)d_in[3];
  const float* conv_b  = (const float*)d_in[4];
  const float* a_log   = (const float*)d_in[5];
  const float* dt_bias = (const float*)d_in[6];
  const float* norm_w  = (const float*)d_in[7];
  const float* w_o     = (const float*)d_in[8];
  float* out = (float*)d_out;

  float* ws = (float*)d_ws;
  float* qkvraw = ws;                  // 4,194,304  (-> Bg)
  float* zbuf   = ws + 4194304;        // 2,097,152
  float* qkvc   = ws + 6291456;        // 4,194,304  (-> Mhi|Mlo, -> wot)
  float* khat   = ws + 10485760;       // 1,048,576  (-> hb)
  float* gbuf   = ws + 11534336;       // 16,384
  float* bbuf   = ws + 11550720;       // 16,384
  float* cgbuf  = ws + 11567104;       // 16,384
  float* obuf   = ws + 11583488;       // 2,097,152  (xb early)
  float* Wtg    = ws + 13680640;       // 2,097,152 ┐ -> Sg (4,194,304)
  float* pQg    = ws + 15777792;       // 2,097,152 ┘
  float* Ug     = ws + 17874944;       // 2,097,152
  float* Mqg    = ws + 19972096;       // 1,048,576
  float* Gtg    = ws + 21020672;       // 2,097,152

  u16* xb   = (u16*)obuf;      // x bf16 (dead after gemm1)
  u16* wqt  = (u16*)Wtg;       // w_qkvz^T bf16 (dead after gemm1)
  u16* Mhi  = (u16*)qkvc;
  u16* Mlo  = (u16*)(qkvc + 2097152);
  float* Bg = qkvraw;
  float* Sg = Wtg;
  u16* wot  = (u16*)qkvc;      // after scan_S (Mhi dead)
  u16* hb   = (u16*)khat;      // after make_MBG (khat dead)

  // 0) casts (permuted staging layout)
  cast_bf16<<<1024, 256, 0, stream>>>(x, xb, 262144);
  transpose_bf16<<<dim3(32, 96), 256, 0, stream>>>(w_qkvz, wqt, H_, QN_);
  // 1) qkv|z = x @ w_qkvz
  gemm_bf16<<<768, 256, 0, stream>>>(xb, wqt, qkvraw, CD_, zbuf, VD_,
                                     CD_, T_, QN_, H_);
  // 2) beta / g
  ba_gbeta<<<T_, 256, 0, stream>>>(x, w_ba, a_log, dt_bias, gbuf, bbuf);
  // 3) fused conv + silu + k-l2norm
  conv_silu_k<<<T_, 512, 0, stream>>>(qkvraw, conv_w, conv_b, qkvc, khat);
  // 4) chunk-local precompute (parallel)
  chunk_prep<<<dim3(NC_, HV_), 256, 0, stream>>>(
      qkvc, khat, gbuf, bbuf, cgbuf, Wtg, Ug, Mqg, pQg);
  // 5) per-chunk transition/output operators (parallel)
  make_MBG<<<dim3(NC_, HV_), 256, 0, stream>>>(
      Wtg, pQg, Ug, Mqg, khat, cgbuf, Mhi, Mlo, Bg, Gtg);
  // 6) sequential state scan (512 threads: no M-register spill)
  scan_S<<<64, 512, 0, stream>>>(Mhi, Mlo, Bg, Sg);
  // 7) w_o^T cast (Mhi region now dead)
  transpose_bf16<<<dim3(32, 32), 256, 0, stream>>>(w_o, wot, VD_, H_);
  // 8) per-chunk outputs (parallel)
  chunk_out<<<dim3(NC_, HV_), 256, 0, stream>>>(Mqg, Ug, Gtg, Sg, obuf);
  // 9) gated rmsnorm -> bf16 h (permuted)
  gated_rmsnorm<<<dim3(T_, HV_), 128, 0, stream>>>(obuf, zbuf, norm_w, hb);
  // 10) out = h @ w_o
  gemm_bf16<<<256, 256, 0, stream>>>(hb, wot, out, VD_, out, VD_,
                                     VD_, T_, VD_, H_);
}

// Round 9
// 250.867 us; speedup vs baseline: 5.3701x; 1.0353x over previous
//
#include <hip/hip_runtime.h>
#include <math.h>

typedef unsigned short u16;
using us4  = __attribute__((ext_vector_type(4))) unsigned short;
using us8  = __attribute__((ext_vector_type(8))) unsigned short;
using bf16x8 = __attribute__((ext_vector_type(8))) __bf16;
using f32x4v = __attribute__((ext_vector_type(4))) float;

// Problem constants
#define T_    1024
#define H_    2048
#define HK_   8
#define HV_   16
#define KD_   1024
#define VD_   2048
#define CD_   4096
#define QN_   6144   // 2*KD + 2*VD
#define NC_   16     // number of chunks
#define C_    64     // chunk length

__device__ __forceinline__ u16 f2bf(float f) {
  unsigned u = __float_as_uint(f);
  u += 0x7fffu + ((u >> 16) & 1u);   // RNE
  return (u16)(u >> 16);
}
__device__ __forceinline__ float bf2f(u16 h) {
  return __uint_as_float(((unsigned)h) << 16);
}
// staging layout for gemm: within each 64-elem k-group, 8-elem chunk c of
// row r is stored at chunk position c ^ (r&7).
__device__ __forceinline__ int permk3(int r, int k) {
  return (k & ~63) | ((((k >> 3) & 7) ^ (r & 7)) << 3) | (k & 7);
}

// ---------------------------------------------------------------------------
// x f32 -> bf16 with chunk permutation (row length 2048)
// ---------------------------------------------------------------------------
__global__ void cast_bf16(const float* __restrict__ in, u16* __restrict__ out,
                          int n8) {
  int i = blockIdx.x * 256 + threadIdx.x;   // 16B-chunk index
  if (i >= n8) return;
  float4 a = ((const float4*)in)[i * 2];
  float4 b = ((const float4*)in)[i * 2 + 1];
  us8 r = {f2bf(a.x), f2bf(a.y), f2bf(a.z), f2bf(a.w),
           f2bf(b.x), f2bf(b.y), f2bf(b.z), f2bf(b.w)};
  const int row = i >> 8;                   // 2048/8 = 256 chunks per row
  const int ip = (i & ~7) | ((i & 7) ^ (row & 7));
  *(us8*)&out[(size_t)ip * 8] = r;
}

// ---------------------------------------------------------------------------
// f32 [R][C] -> bf16 [C][R] transpose + cast + chunk permutation
// ---------------------------------------------------------------------------
__global__ __launch_bounds__(256) void transpose_bf16(
    const float* __restrict__ in, u16* __restrict__ out, int R, int C) {
  __shared__ float tile[64][65];
  const int r0 = blockIdx.x * 64, c0 = blockIdx.y * 64;
  const int t = threadIdx.x;
  const int tr = t >> 4, tc4 = (t & 15) * 4;
#pragma unroll
  for (int i = 0; i < 4; ++i) {
    float4 v = *(const float4*)&in[(size_t)(r0 + tr + i * 16) * C + c0 + tc4];
    tile[tr + i * 16][tc4 + 0] = v.x;
    tile[tr + i * 16][tc4 + 1] = v.y;
    tile[tr + i * 16][tc4 + 2] = v.z;
    tile[tr + i * 16][tc4 + 3] = v.w;
  }
  __syncthreads();
#pragma unroll
  for (int i = 0; i < 4; ++i) {
    int oc = tr + i * 16;
    int row = c0 + oc;
    int k = r0 + tc4;
    us4 w = {f2bf(tile[tc4 + 0][oc]), f2bf(tile[tc4 + 1][oc]),
             f2bf(tile[tc4 + 2][oc]), f2bf(tile[tc4 + 3][oc])};
    *(us4*)&out[(size_t)row * R + permk3(row, k)] = w;
  }
}

// ---------------------------------------------------------------------------
// bf16 MFMA GEMM: C = A[M,K] @ Bt[N,K]^T, f32 out. 128x64 tile, BK=64,
// 2-phase double-buffered LDS pipeline, XCD-grouped 1D block mapping,
// 3-bit permuted staging. Output routed to Cq (cols < zsplit) or Cz.
// ---------------------------------------------------------------------------
__device__ __forceinline__ void gload_lds16(const void* g, void* l) {
  __builtin_amdgcn_global_load_lds(
      (const __attribute__((address_space(1))) void*)g,
      (__attribute__((address_space(3))) void*)l, 16, 0, 0);
}

__global__ __launch_bounds__(256) void gemm_bf16(
    const u16* __restrict__ A, const u16* __restrict__ Bt,
    float* __restrict__ Cq, int ldq, float* __restrict__ Cz, int ldz,
    int zsplit, int M, int N, int K) {
  __shared__ __align__(16) u16 As[2][8192];   // [128][64]
  __shared__ __align__(16) u16 Bs[2][4096];   // [64][64]
  const int tid  = threadIdx.x;
  const int wave = tid >> 6, lane = tid & 63;
  const int gy = N >> 6;
  const int ncolpx = gy >> 3;
  const int bid = blockIdx.x;
  const int xcd = bid & 7, idx = bid >> 3;
  const int row0 = (idx / ncolpx) * 128;
  const int col0 = (xcd * ncolpx + idx % ncolpx) * 64;
  const int wr = wave >> 1, wc = wave & 1;
  const int fr = lane & 15, fq = lane >> 4;

  const int sr8 = lane >> 3;
  const int sc8 = (lane & 7) * 8;
  const u16* gA = A  + (size_t)(row0 + wave * 32 + sr8) * K + sc8;
  const u16* gB = Bt + (size_t)(col0 + wave * 16 + sr8) * K + sc8;

  f32x4v acc[4][2] = {};
  const int nt = K >> 6;

  auto stage = [&](int p, int k0) {
#pragma unroll
    for (int j = 0; j < 4; ++j)
      gload_lds16(gA + (size_t)(j * 8) * K + k0,
                  &As[p][(wave * 32 + j * 8) * 64]);
#pragma unroll
    for (int j = 0; j < 2; ++j)
      gload_lds16(gB + (size_t)(j * 8) * K + k0,
                  &Bs[p][(wave * 16 + j * 8) * 64]);
  };

  stage(0, 0);
  asm volatile("s_waitcnt vmcnt(0)" ::: "memory");
  __syncthreads();

  int p = 0;
  for (int it = 0; it < nt; ++it) {
    if (it + 1 < nt) stage(p ^ 1, (it + 1) * 64);
#pragma unroll
    for (int kt = 0; kt < 2; ++kt) {
      bf16x8 af[4], bff[2];
#pragma unroll
      for (int mi = 0; mi < 4; ++mi) {
        const int r = wr * 64 + mi * 16 + fr;
        af[mi] = *(const bf16x8*)
            &As[p][r * 64 + kt * 32 + (((kt * 4 + fq) ^ (r & 7)) & 3) * 8
                   + ((((kt * 4 + fq) ^ (r & 7)) >> 2) - kt) * 32];
      }
#pragma unroll
      for (int ni = 0; ni < 2; ++ni) {
        const int r = wc * 32 + ni * 16 + fr;
        bff[ni] = *(const bf16x8*)
            &Bs[p][r * 64 + kt * 32 + (((kt * 4 + fq) ^ (r & 7)) & 3) * 8
                   + ((((kt * 4 + fq) ^ (r & 7)) >> 2) - kt) * 32];
      }
#pragma unroll
      for (int mi = 0; mi < 4; ++mi)
#pragma unroll
        for (int ni = 0; ni < 2; ++ni)
          acc[mi][ni] = __builtin_amdgcn_mfma_f32_16x16x32_bf16(
              af[mi], bff[ni], acc[mi][ni], 0, 0, 0);
    }
    if (it + 1 < nt) {
      asm volatile("s_waitcnt vmcnt(0)" ::: "memory");
      __syncthreads();
    }
    p ^= 1;
  }

  float* Cp; int ldc, cb;
  if (col0 < zsplit) { Cp = Cq; ldc = ldq; cb = col0; }
  else               { Cp = Cz; ldc = ldz; cb = col0 - zsplit; }
#pragma unroll
  for (int mi = 0; mi < 4; ++mi)
#pragma unroll
    for (int ni = 0; ni < 2; ++ni) {
      const int r  = row0 + wr * 64 + mi * 16 + fq * 4;
      const int cc = cb + wc * 32 + ni * 16 + fr;
#pragma unroll
      for (int j = 0; j < 4; ++j)
        Cp[(size_t)(r + j) * ldc + cc] = acc[mi][ni][j];
    }
}

// ---------------------------------------------------------------------------
// ba = x @ w_ba -> beta = sigmoid(b), g = -exp(a_log)*softplus(a+dt_bias)
// ---------------------------------------------------------------------------
__global__ __launch_bounds__(256) void ba_gbeta(
    const float* __restrict__ x, const float* __restrict__ w_ba,
    const float* __restrict__ a_log, const float* __restrict__ dt_bias,
    float* __restrict__ g, float* __restrict__ beta) {
  const int t = blockIdx.x;
  const int tid = threadIdx.x;
  __shared__ float xs[2048];
  __shared__ float red[8][32];
  {
    float4 v = *(const float4*)&x[(size_t)t * H_ + tid * 4];
    *(float4*)&xs[tid * 4] = v;
    float4 w = *(const float4*)&x[(size_t)t * H_ + 1024 + tid * 4];
    *(float4*)&xs[1024 + tid * 4] = w;
  }
  __syncthreads();
  const int c = tid & 31;
  const int chunk = tid >> 5;
  float p = 0.f;
  const int kb = chunk * 256;
#pragma unroll 4
  for (int k = kb; k < kb + 256; ++k) p = fmaf(xs[k], w_ba[k * 32 + c], p);
  red[chunk][c] = p;
  __syncthreads();
  if (tid < 32) {
    float s = 0.f;
#pragma unroll
    for (int i = 0; i < 8; ++i) s += red[i][c];
    if (c < 16) {
      beta[t * 16 + c] = 1.f / (1.f + expf(-s));
    } else {
      int h = c - 16;
      float xx = s + dt_bias[h];
      float sp = xx > 20.f ? xx : log1pf(expf(xx));
      g[t * 16 + h] = -expf(a_log[h]) * sp;
    }
  }
}

// ---------------------------------------------------------------------------
// fused causal depthwise conv1d (K=4) + SiLU + k-l2norm.
// ---------------------------------------------------------------------------
__global__ __launch_bounds__(512) void conv_silu_k(
    const float* __restrict__ qkvraw, const float* __restrict__ conv_w,
    const float* __restrict__ conv_b, float* __restrict__ qkvc,
    float* __restrict__ khat) {
  const int t = blockIdx.x;
  const int tid = threadIdx.x;
  const int c0 = tid * 8;
  float acc[8];
  float4 cb0 = *(const float4*)&conv_b[c0];
  float4 cb1 = *(const float4*)&conv_b[c0 + 4];
  acc[0] = cb0.x; acc[1] = cb0.y; acc[2] = cb0.z; acc[3] = cb0.w;
  acc[4] = cb1.x; acc[5] = cb1.y; acc[6] = cb1.z; acc[7] = cb1.w;
  float wv[8][4];
#pragma unroll
  for (int i = 0; i < 8; i += 2) {
    float4 w0 = *(const float4*)&conv_w[(c0 + i) * 4];
    float4 w1 = *(const float4*)&conv_w[(c0 + i + 1) * 4];
    wv[i][0] = w0.x; wv[i][1] = w0.y; wv[i][2] = w0.z; wv[i][3] = w0.w;
    wv[i+1][0] = w1.x; wv[i+1][1] = w1.y; wv[i+1][2] = w1.z; wv[i+1][3] = w1.w;
  }
#pragma unroll
  for (int j = 0; j < 4; ++j) {
    int tt = t - 3 + j;
    if (tt >= 0) {
      float4 a = *(const float4*)&qkvraw[(size_t)tt * CD_ + c0];
      float4 b = *(const float4*)&qkvraw[(size_t)tt * CD_ + c0 + 4];
      float xv[8] = {a.x, a.y, a.z, a.w, b.x, b.y, b.z, b.w};
#pragma unroll
      for (int i = 0; i < 8; ++i) acc[i] = fmaf(xv[i], wv[i][j], acc[i]);
    }
  }
  float y[8];
#pragma unroll
  for (int i = 0; i < 8; ++i) y[i] = acc[i] / (1.f + expf(-acc[i]));

  if (tid < 128 || tid >= 256) {
    float4 o0 = {y[0], y[1], y[2], y[3]};
    float4 o1 = {y[4], y[5], y[6], y[7]};
    *(float4*)&qkvc[(size_t)t * CD_ + c0]     = o0;
    *(float4*)&qkvc[(size_t)t * CD_ + c0 + 4] = o1;
  } else {
    float ss = 0.f;
#pragma unroll
    for (int i = 0; i < 8; ++i) ss = fmaf(y[i], y[i], ss);
#pragma unroll
    for (int off = 1; off < 16; off <<= 1) ss += __shfl_xor(ss, off);
    float rs = rsqrtf(ss + 1e-6f);
    const int head = (c0 - 1024) >> 7;
    const int d0 = (c0 - 1024) & 127;
    float4 o0 = {y[0] * rs, y[1] * rs, y[2] * rs, y[3] * rs};
    float4 o1 = {y[4] * rs, y[5] * rs, y[6] * rs, y[7] * rs};
    float* kout = &khat[((size_t)t * HK_ + head) * 128 + d0];
    *(float4*)&kout[0] = o0;
    *(float4*)&kout[4] = o1;
  }
}

// ---------------------------------------------------------------------------
// Chunked gated delta rule, phase A (parallel over 16 chunks x 16 heads).
// v2: 512 threads (8 waves). Dot phase 4x2 tiles/thread; during the serial
// forward substitution (waves 0-3), waves 4-7 write Mqg and pQg.
// ---------------------------------------------------------------------------
#define SWZ(r) (((r) >> 2) & 7)

__device__ __forceinline__ float4 ldsw4(const float* base, int r, int dblk) {
  return *(const float4*)&base[r * 128 + ((dblk ^ SWZ(r)) << 2)];
}
__device__ __forceinline__ float ldsw1(const float* base, int r, int d) {
  return base[r * 128 + ((((d) >> 2) ^ SWZ(r)) << 2) + ((d) & 3)];
}

__global__ __launch_bounds__(512) void chunk_prep(
    const float* __restrict__ qkvc, const float* __restrict__ khat,
    const float* __restrict__ g, const float* __restrict__ beta,
    float* __restrict__ cgbuf, float* __restrict__ Wtg, float* __restrict__ Ug,
    float* __restrict__ Mqg, float* __restrict__ pQg) {
  const int c = blockIdx.x, hv = blockIdx.y, hk = hv >> 1;
  const int cid = c * 16 + hv;
  const int tid = threadIdx.x;
  __shared__ float Kl[8192], Ql[8192];   // swizzled [64][128]
  __shared__ float AM[8320];             // At[64][65] | Mq[64][65]; later Utr
  __shared__ float cgl[64], bl[64], bp[64], rsl[64];
  float* At = AM;
  float* Mq = AM + 4160;

#pragma unroll
  for (int it = 0; it < 4; ++it) {
    int flat = it * 2048 + tid * 4;
    int row = flat >> 7, d = flat & 127;
    int pb = ((d >> 2) ^ SWZ(row)) << 2;
    int gt = c * 64 + row;
    float4 kv = *(const float4*)&khat[((size_t)gt * HK_ + hk) * 128 + d];
    float4 qv = *(const float4*)&qkvc[(size_t)gt * CD_ + hk * 128 + d];
    *(float4*)&Kl[row * 128 + pb] = kv;
    *(float4*)&Ql[row * 128 + pb] = qv;
  }
  if (tid < 64) {
    float s = g[(size_t)(c * 64 + tid) * HV_ + hv];
#pragma unroll
    for (int off = 1; off < 64; off <<= 1) {
      float t = __shfl_up(s, off);
      if (tid >= off) s += t;
    }
    cgl[tid] = s;
    cgbuf[cid * 64 + tid] = s;
    bl[tid] = beta[(size_t)(c * 64 + tid) * HV_ + hv];
  }
  __syncthreads();
  if (tid < 64) {
    float sq = 0.f;
#pragma unroll
    for (int dblk = 0; dblk < 32; ++dblk) {
      float4 q4 = ldsw4(Ql, tid, dblk);
      sq = fmaf(q4.x, q4.x, sq); sq = fmaf(q4.y, q4.y, sq);
      sq = fmaf(q4.z, q4.z, sq); sq = fmaf(q4.w, q4.w, sq);
    }
    rsl[tid] = rsqrtf(sq + 1e-6f) * 0.08838834764831845f;
    bp[tid] = bl[tid] * expf(cgl[tid]);
  }
  __syncthreads();

  // dot phase: 4x2 tile of (i,j) pairs per thread (512 threads)
  const int i0 = (tid >> 5) * 4, j0 = (tid & 31) * 2;
  float kk[4][2], qk[4][2];
#pragma unroll
  for (int a = 0; a < 4; ++a)
#pragma unroll
    for (int b = 0; b < 2; ++b) { kk[a][b] = 0.f; qk[a][b] = 0.f; }
  for (int dblk = 0; dblk < 32; ++dblk) {
    float4 ka[4], qa[4], kb[2];
#pragma unroll
    for (int a = 0; a < 4; ++a) {
      ka[a] = ldsw4(Kl, i0 + a, dblk);
      qa[a] = ldsw4(Ql, i0 + a, dblk);
    }
#pragma unroll
    for (int b = 0; b < 2; ++b) kb[b] = ldsw4(Kl, j0 + b, dblk);
#pragma unroll
    for (int a = 0; a < 4; ++a)
#pragma unroll
      for (int b = 0; b < 2; ++b) {
        kk[a][b] = fmaf(ka[a].x, kb[b].x, kk[a][b]);
        kk[a][b] = fmaf(ka[a].y, kb[b].y, kk[a][b]);
        kk[a][b] = fmaf(ka[a].z, kb[b].z, kk[a][b]);
        kk[a][b] = fmaf(ka[a].w, kb[b].w, kk[a][b]);
        qk[a][b] = fmaf(qa[a].x, kb[b].x, qk[a][b]);
        qk[a][b] = fmaf(qa[a].y, kb[b].y, qk[a][b]);
        qk[a][b] = fmaf(qa[a].z, kb[b].z, qk[a][b]);
        qk[a][b] = fmaf(qa[a].w, kb[b].w, qk[a][b]);
      }
  }
#pragma unroll
  for (int a = 0; a < 4; ++a)
#pragma unroll
    for (int b = 0; b < 2; ++b) {
      int i = i0 + a, j = j0 + b;
      float e = expf(cgl[i] - cgl[j]);
      At[j * 65 + i] = (j < i) ? (-bl[i] * e * kk[a][b]) : 0.f;
      Mq[j * 65 + i] = (j <= i) ? (rsl[i] * e * qk[a][b]) : 0.f;
    }
  __syncthreads();

  float X[64];
  if (tid < 256) {
    // ---- waves 0-3: X init + forward substitution ----
    if (tid < 128) {
#pragma unroll
      for (int j = 0; j < 64; ++j) X[j] = bp[j] * ldsw1(Kl, j, tid);
    } else {
      const int m = tid - 128;
#pragma unroll
      for (int j = 0; j < 64; ++j)
        X[j] = bl[j] * qkvc[(size_t)(c * 64 + j) * CD_ + 2 * KD_ + hv * 128 + m];
    }
#pragma unroll
    for (int j = 0; j < 63; ++j) {
      float xj = X[j];
#pragma unroll
      for (int i = j + 1; i < 64; ++i) X[i] = fmaf(At[j * 65 + i], xj, X[i]);
    }
    if (tid < 128) {
      size_t baseo = ((size_t)cid * 128 + tid) * 64;
#pragma unroll
      for (int j4 = 0; j4 < 16; ++j4) {
        float4 v = {X[j4 * 4], X[j4 * 4 + 1], X[j4 * 4 + 2], X[j4 * 4 + 3]};
        *(float4*)&Wtg[baseo + j4 * 4] = v;
      }
    }
  } else {
    // ---- waves 4-7: Mqg + pQg writes (independent of solve) ----
    const int t2 = tid - 256;
#pragma unroll
    for (int it = 0; it < 16; ++it) {
      int f = it * 256 + t2;
      int j = f >> 6, i = f & 63;
      Mqg[(size_t)cid * 4096 + f] = Mq[j * 65 + i];
    }
    const int i = t2 & 63;
    const float ei = expf(cgl[i]) * rsl[i];
#pragma unroll
    for (int it = 0; it < 32; ++it) {
      int d = it * 4 + (t2 >> 6);
      pQg[(size_t)cid * 8192 + d * 64 + i] = ei * ldsw1(Ql, i, d);
    }
  }
  __syncthreads();   // At/Mq dead; X (U cols) ready

  if (tid >= 128 && tid < 256) {
    const int m = tid - 128;
    float* Utr = AM;
#pragma unroll
    for (int j = 0; j < 64; ++j) Utr[j * 128 + m] = X[j];
  }
  __syncthreads();
  {
    const float* Utr = AM;
#pragma unroll
    for (int it = 0; it < 4; ++it) {
      int flat = it * 2048 + tid * 4;
      *(float4*)&Ug[(size_t)cid * 8192 + flat] = *(const float4*)&Utr[flat];
    }
  }
}

// ---------------------------------------------------------------------------
// make_MBG v2 (parallel, 256 blocks, 512 threads)
// ---------------------------------------------------------------------------
__global__ __launch_bounds__(512) void make_MBG(
    const float* __restrict__ Wtg, const float* __restrict__ pQg,
    const float* __restrict__ Ug, const float* __restrict__ Mqg,
    const float* __restrict__ khat, const float* __restrict__ cgbuf,
    u16* __restrict__ Mhi, u16* __restrict__ Mlo,
    float* __restrict__ Bg, float* __restrict__ Gtg) {
  const int c = blockIdx.x, hv = blockIdx.y, hk = hv >> 1;
  const int cid = c * 16 + hv;
  const int tid = threadIdx.x;
  __shared__ float Wl[64 * 128];   // W[j][d]
  __shared__ float Kel[64 * 128];  // esc_j * khat_j[d]
  __shared__ float Ul[64 * 128];
  __shared__ float Mql[64 * 64];
  const float cg63 = cgbuf[cid * 64 + 63];
  const float pC = expf(cg63);
#pragma unroll
  for (int it = 0; it < 4; ++it) {
    int f = it * 2048 + tid * 4;       // f = d*64 + j
    int d = f >> 6, j = f & 63;
    float4 w = *(const float4*)&Wtg[(size_t)cid * 8192 + f];
    Wl[(j + 0) * 128 + d] = w.x;
    Wl[(j + 1) * 128 + d] = w.y;
    Wl[(j + 2) * 128 + d] = w.z;
    Wl[(j + 3) * 128 + d] = w.w;
  }
#pragma unroll
  for (int it = 0; it < 4; ++it) {
    int f = it * 2048 + tid * 4;       // f = j*128 + d
    int j = f >> 7, d = f & 127;
    float esc = expf(cg63 - cgbuf[cid * 64 + j]);
    float4 kv = *(const float4*)&khat[((size_t)(c * 64 + j) * HK_ + hk) * 128 + d];
    float4 uv = *(const float4*)&Ug[(size_t)cid * 8192 + f];
    kv.x *= esc; kv.y *= esc; kv.z *= esc; kv.w *= esc;
    *(float4*)&Kel[f] = kv;
    *(float4*)&Ul[f] = uv;
  }
#pragma unroll
  for (int it = 0; it < 2; ++it) {
    int f = it * 2048 + tid * 4;
    *(float4*)&Mql[f] = *(const float4*)&Mqg[(size_t)cid * 4096 + f];
  }
  __syncthreads();

  // fused M+B: tile rows d0..d0+7, cols n0..n0+3
  const int d0 = (tid & 15) * 8, n0 = (tid >> 4) * 4;
  float ma[8][4] = {}, ba[8][4] = {};
  for (int j = 0; j < 64; ++j) {
    float4 k0 = *(const float4*)&Kel[j * 128 + d0];
    float4 k1 = *(const float4*)&Kel[j * 128 + d0 + 4];
    float4 w0 = *(const float4*)&Wl[j * 128 + n0];
    float4 u0 = *(const float4*)&Ul[j * 128 + n0];
    float ke[8] = {k0.x, k0.y, k0.z, k0.w, k1.x, k1.y, k1.z, k1.w};
    float wv[4] = {w0.x, w0.y, w0.z, w0.w};
    float uv[4] = {u0.x, u0.y, u0.z, u0.w};
#pragma unroll
    for (int a = 0; a < 8; ++a)
#pragma unroll
      for (int b = 0; b < 4; ++b) {
        ma[a][b] = fmaf(ke[a], wv[b], ma[a][b]);
        ba[a][b] = fmaf(ke[a], uv[b], ba[a][b]);
      }
  }
#pragma unroll
  for (int a = 0; a < 8; ++a) {
    const int d = d0 + a;
    us4 hi, lo;
#pragma unroll
    for (int b = 0; b < 4; ++b) {
      float m = ((d == n0 + b) ? pC : 0.f) - ma[a][b];
      u16 h = f2bf(m);
      hi[b] = h;
      lo[b] = f2bf(m - bf2f(h));
    }
    *(us4*)&Mhi[(size_t)cid * 16384 + d * 128 + n0] = hi;
    *(us4*)&Mlo[(size_t)cid * 16384 + d * 128 + n0] = lo;
    float4 b0 = {ba[a][0], ba[a][1], ba[a][2], ba[a][3]};
    *(float4*)&Bg[(size_t)cid * 16384 + d * 128 + n0] = b0;
  }

  // G phase: Gt[d][i] tile 4d x 4i
  const int dg = (tid & 31) * 4, ig = (tid >> 5) * 4;
  float ga[4][4] = {};
  for (int j = 0; j < 64; ++j) {
    float4 w4 = *(const float4*)&Wl[j * 128 + dg];
    float4 m0 = *(const float4*)&Mql[j * 64 + ig];
    float wv[4] = {w4.x, w4.y, w4.z, w4.w};
    float mv[4] = {m0.x, m0.y, m0.z, m0.w};
#pragma unroll
    for (int a = 0; a < 4; ++a)
#pragma unroll
      for (int b = 0; b < 4; ++b) ga[a][b] = fmaf(wv[a], mv[b], ga[a][b]);
  }
#pragma unroll
  for (int a = 0; a < 4; ++a) {
    const int d = dg + a;
    float4 p0 = *(const float4*)&pQg[(size_t)cid * 8192 + d * 64 + ig];
    float4 g0 = {p0.x - ga[a][0], p0.y - ga[a][1], p0.z - ga[a][2], p0.w - ga[a][3]};
    *(float4*)&Gtg[(size_t)cid * 8192 + d * 64 + ig] = g0;
  }
}

// ---------------------------------------------------------------------------
// scan_S: 64 blocks = 16 heads x 4 col-slices, XCD-grouped, 512 threads.
// ---------------------------------------------------------------------------
__global__ __launch_bounds__(512) void scan_S(
    const u16* __restrict__ Mhi, const u16* __restrict__ Mlo,
    const float* __restrict__ Bg, float* __restrict__ Sg) {
  const int flat = blockIdx.x;
  const int hv = (flat & 7) + 8 * (flat >> 5);
  const int vs = (flat >> 3) & 3;
  const int tid = threadIdx.x;
  const int wave = tid >> 6, lane = tid & 63;
  const int fr = lane & 15, fq = lane >> 4;
  const int wr = wave * 16;       // this wave's 16 output rows
  const int m0 = vs * 32;

  __shared__ u16 Sh[2][4096];
  __shared__ u16 Sl[2][4096];

  for (int i = tid; i < 4096; i += 512) { Sh[0][i] = 0; Sl[0][i] = 0; }
  {
    float* s0 = Sg + (size_t)hv * 16384 + m0;
#pragma unroll
    for (int it = 0; it < 8; ++it) {
      int idx = it * 512 + tid;
      s0[(size_t)(idx >> 5) * 128 + (idx & 31)] = 0.f;
    }
  }
  __syncthreads();

  bf16x8 MhA[4], MlA[4], MhB[4], MlB[4];
  {
    const u16* Mh0 = Mhi + (size_t)hv * 16384;
    const u16* Ml0 = Mlo + (size_t)hv * 16384;
#pragma unroll
    for (int kt = 0; kt < 4; ++kt) {
      size_t off = (size_t)(wr + fr) * 128 + kt * 32 + fq * 8;
      MhA[kt] = *(const bf16x8*)&Mh0[off];
      MlA[kt] = *(const bf16x8*)&Ml0[off];
    }
  }
  int p = 0;

  auto step = [&](int c, bf16x8 (&MhC)[4], bf16x8 (&MlC)[4],
                  bf16x8 (&MhN)[4], bf16x8 (&MlN)[4]) {
    if (c + 1 < NC_ - 1) {
      const u16* MhP = Mhi + (size_t)((c + 1) * 16 + hv) * 16384;
      const u16* MlP = Mlo + (size_t)((c + 1) * 16 + hv) * 16384;
#pragma unroll
      for (int kt = 0; kt < 4; ++kt) {
        size_t off = (size_t)(wr + fr) * 128 + kt * 32 + fq * 8;
        MhN[kt] = *(const bf16x8*)&MhP[off];
        MlN[kt] = *(const bf16x8*)&MlP[off];
      }
    }
    const float* Bc = Bg + (size_t)(c * 16 + hv) * 16384 + m0;
    float bv[2][4];
#pragma unroll
    for (int b = 0; b < 2; ++b)
#pragma unroll
      for (int j = 0; j < 4; ++j)
        bv[b][j] = Bc[(size_t)(wr + fq * 4 + j) * 128 + b * 16 + fr];

    f32x4v acc[2] = {};
#pragma unroll
    for (int kt = 0; kt < 4; ++kt) {
      bf16x8 Bh[2], Bl[2];
#pragma unroll
      for (int b = 0; b < 2; ++b) {
        int m = b * 16 + fr;
        int byte = m * 256 + ((kt * 64 + fq * 16) ^ ((m & 7) << 4));
        Bh[b] = *(const bf16x8*)((const char*)&Sh[p][0] + byte);
        Bl[b] = *(const bf16x8*)((const char*)&Sl[p][0] + byte);
      }
#pragma unroll
      for (int b = 0; b < 2; ++b) {
        acc[b] = __builtin_amdgcn_mfma_f32_16x16x32_bf16(
            MlC[kt], Bh[b], acc[b], 0, 0, 0);
        acc[b] = __builtin_amdgcn_mfma_f32_16x16x32_bf16(
            MhC[kt], Bl[b], acc[b], 0, 0, 0);
        acc[b] = __builtin_amdgcn_mfma_f32_16x16x32_bf16(
            MhC[kt], Bh[b], acc[b], 0, 0, 0);
      }
    }
    float* Sn = Sg + (size_t)((c + 1) * 16 + hv) * 16384 + m0;
#pragma unroll
    for (int b = 0; b < 2; ++b) {
      const int k0 = wr + fq * 4;
      const int m = b * 16 + fr;
      us4 h4, l4;
#pragma unroll
      for (int j = 0; j < 4; ++j) {
        float v = acc[b][j] + bv[b][j];
        Sn[(size_t)(k0 + j) * 128 + m] = v;
        u16 h = f2bf(v);
        h4[j] = h;
        l4[j] = f2bf(v - bf2f(h));
      }
      int byte = m * 256 + (((k0 * 2)) ^ ((m & 7) << 4));
      *(us4*)((char*)&Sh[p ^ 1][0] + byte) = h4;
      *(us4*)((char*)&Sl[p ^ 1][0] + byte) = l4;
    }
    __syncthreads();
    p ^= 1;
  };

  for (int cc = 0; cc < NC_ - 1; cc += 2) {
    step(cc, MhA, MlA, MhB, MlB);
    if (cc + 1 < NC_ - 1) step(cc + 1, MhB, MlB, MhA, MlA);
  }
}

// ---------------------------------------------------------------------------
// chunk_out (parallel, 256 blocks): o = Mq^T U + G*S
// ---------------------------------------------------------------------------
__global__ __launch_bounds__(256) void chunk_out(
    const float* __restrict__ Mqg, const float* __restrict__ Ug,
    const float* __restrict__ Gtg, const float* __restrict__ Sg,
    float* __restrict__ o) {
  const int c = blockIdx.x, hv = blockIdx.y;
  const int cid = c * 16 + hv;
  const int tid = threadIdx.x;
  __shared__ float Mql[64 * 64];
  __shared__ float Ul[64 * 128];
  __shared__ float Gtl[128 * 64];
  __shared__ float Sl[128 * 128];
#pragma unroll
  for (int it = 0; it < 4; ++it) {
    int f = it * 1024 + tid * 4;
    *(float4*)&Mql[f] = *(const float4*)&Mqg[(size_t)cid * 4096 + f];
  }
#pragma unroll
  for (int it = 0; it < 8; ++it) {
    int f = it * 1024 + tid * 4;
    *(float4*)&Ul[f]  = *(const float4*)&Ug[(size_t)cid * 8192 + f];
    *(float4*)&Gtl[f] = *(const float4*)&Gtg[(size_t)cid * 8192 + f];
  }
#pragma unroll
  for (int it = 0; it < 16; ++it) {
    int f = it * 1024 + tid * 4;
    *(float4*)&Sl[f] = *(const float4*)&Sg[(size_t)cid * 16384 + f];
  }
  __syncthreads();

  const int i0 = (tid & 15) * 4, m0 = (tid >> 4) * 8;
  float oa[4][8] = {};
  for (int j = 0; j < 64; ++j) {
    float4 mq = *(const float4*)&Mql[j * 64 + i0];
    float4 u0 = *(const float4*)&Ul[j * 128 + m0];
    float4 u1 = *(const float4*)&Ul[j * 128 + m0 + 4];
    float mv[4] = {mq.x, mq.y, mq.z, mq.w};
    float uv[8] = {u0.x, u0.y, u0.z, u0.w, u1.x, u1.y, u1.z, u1.w};
#pragma unroll
    for (int a = 0; a < 4; ++a)
#pragma unroll
      for (int b = 0; b < 8; ++b) oa[a][b] = fmaf(mv[a], uv[b], oa[a][b]);
  }
  for (int d = 0; d < 128; ++d) {
    float4 gt = *(const float4*)&Gtl[d * 64 + i0];
    float4 s0 = *(const float4*)&Sl[d * 128 + m0];
    float4 s1 = *(const float4*)&Sl[d * 128 + m0 + 4];
    float gv[4] = {gt.x, gt.y, gt.z, gt.w};
    float sv[8] = {s0.x, s0.y, s0.z, s0.w, s1.x, s1.y, s1.z, s1.w};
#pragma unroll
    for (int a = 0; a < 4; ++a)
#pragma unroll
      for (int b = 0; b < 8; ++b) oa[a][b] = fmaf(gv[a], sv[b], oa[a][b]);
  }
#pragma unroll
  for (int a = 0; a < 4; ++a) {
    const int t = c * 64 + i0 + a;
    float4 o0 = {oa[a][0], oa[a][1], oa[a][2], oa[a][3]};
    float4 o1 = {oa[a][4], oa[a][5], oa[a][6], oa[a][7]};
    *(float4*)&o[((size_t)t * HV_ + hv) * 128 + m0]     = o0;
    *(float4*)&o[((size_t)t * HV_ + hv) * 128 + m0 + 4] = o1;
  }
}

// ---------------------------------------------------------------------------
// h = o * silu(z); rmsnorm; -> bf16 (permuted staging layout for gemm2)
// ---------------------------------------------------------------------------
__global__ void gated_rmsnorm(const float* __restrict__ o,
                              const float* __restrict__ zbuf,
                              const float* __restrict__ norm_w,
                              u16* __restrict__ h) {
  const int t = blockIdx.x, hv = blockIdx.y, d = threadIdx.x;
  float ov = o[((size_t)t * HV_ + hv) * 128 + d];
  float zv = zbuf[(size_t)t * VD_ + hv * 128 + d];
  float hc = ov * (zv / (1.f + expf(-zv)));
  float ss = hc * hc;
#pragma unroll
  for (int off = 32; off >= 1; off >>= 1) ss += __shfl_xor(ss, off);
  __shared__ float s2[2];
  if ((d & 63) == 0) s2[d >> 6] = ss;
  __syncthreads();
  float tot = s2[0] + s2[1];
  float r = rsqrtf(tot * (1.f / 128.f) + 1e-6f);
  const int k = hv * 128 + d;
  h[(size_t)t * VD_ + permk3(t, k)] = f2bf(hc * r * norm_w[d]);
}

// ---------------------------------------------------------------------------
extern "C" void kernel_launch(void* const* d_in, const int* in_sizes, int n_in,
                              void* d_out, int out_size, void* d_ws, size_t ws_size,
                              hipStream_t stream) {
  const float* x       = (const float*)d_in[0];
  const float* w_qkvz  = (const float*)d_in[1];
  const float* w_ba    = (const float*)d_in[2];
  const float* conv_w  = (const float*)d_in[3];
  const float* conv_b  = (const float*)d_in[4];
  const float* a_log   = (const float*)d_in[5];
  const float* dt_bias = (const float*)d_in[6];
  const float* norm_w  = (const float*)d_in[7];
  const float* w_o     = (const float*)d_in[8];
  float* out = (float*)d_out;

  float* ws = (float*)d_ws;
  float* qkvraw = ws;                  // 4,194,304  (-> Bg)
  float* zbuf   = ws + 4194304;        // 2,097,152
  float* qkvc   = ws + 6291456;        // 4,194,304  (-> Mhi|Mlo, -> wot)
  float* khat   = ws + 10485760;       // 1,048,576  (-> hb)
  float* gbuf   = ws + 11534336;       // 16,384
  float* bbuf   = ws + 11550720;       // 16,384
  float* cgbuf  = ws + 11567104;       // 16,384
  float* obuf   = ws + 11583488;       // 2,097,152  (xb early)
  float* Wtg    = ws + 13680640;       // 2,097,152 ┐ -> Sg (4,194,304)
  float* pQg    = ws + 15777792;       // 2,097,152 ┘
  float* Ug     = ws + 17874944;       // 2,097,152
  float* Mqg    = ws + 19972096;       // 1,048,576
  float* Gtg    = ws + 21020672;       // 2,097,152

  u16* xb   = (u16*)obuf;      // x bf16 (dead after gemm1)
  u16* wqt  = (u16*)Wtg;       // w_qkvz^T bf16 (dead after gemm1)
  u16* Mhi  = (u16*)qkvc;
  u16* Mlo  = (u16*)(qkvc + 2097152);
  float* Bg = qkvraw;
  float* Sg = Wtg;
  u16* wot  = (u16*)qkvc;      // after scan_S (Mhi dead)
  u16* hb   = (u16*)khat;      // after make_MBG (khat dead)

  // 0) casts (permuted staging layout)
  cast_bf16<<<1024, 256, 0, stream>>>(x, xb, 262144);
  transpose_bf16<<<dim3(32, 96), 256, 0, stream>>>(w_qkvz, wqt, H_, QN_);
  // 1) qkv|z = x @ w_qkvz
  gemm_bf16<<<768, 256, 0, stream>>>(xb, wqt, qkvraw, CD_, zbuf, VD_,
                                     CD_, T_, QN_, H_);
  // 2) beta / g
  ba_gbeta<<<T_, 256, 0, stream>>>(x, w_ba, a_log, dt_bias, gbuf, bbuf);
  // 3) fused conv + silu + k-l2norm
  conv_silu_k<<<T_, 512, 0, stream>>>(qkvraw, conv_w, conv_b, qkvc, khat);
  // 4) chunk-local precompute (parallel, 512 thr)
  chunk_prep<<<dim3(NC_, HV_), 512, 0, stream>>>(
      qkvc, khat, gbuf, bbuf, cgbuf, Wtg, Ug, Mqg, pQg);
  // 5) per-chunk transition/output operators (parallel, 512 thr)
  make_MBG<<<dim3(NC_, HV_), 512, 0, stream>>>(
      Wtg, pQg, Ug, Mqg, khat, cgbuf, Mhi, Mlo, Bg, Gtg);
  // 6) sequential state scan
  scan_S<<<64, 512, 0, stream>>>(Mhi, Mlo, Bg, Sg);
  // 7) w_o^T cast (Mhi region now dead)
  transpose_bf16<<<dim3(32, 32), 256, 0, stream>>>(w_o, wot, VD_, H_);
  // 8) per-chunk outputs (parallel)
  chunk_out<<<dim3(NC_, HV_), 256, 0, stream>>>(Mqg, Ug, Gtg, Sg, obuf);
  // 9) gated rmsnorm -> bf16 h (permuted)
  gated_rmsnorm<<<dim3(T_, HV_), 128, 0, stream>>>(obuf, zbuf, norm_w, hb);
  // 10) out = h @ w_o
  gemm_bf16<<<256, 256, 0, stream>>>(hb, wot, out, VD_, out, VD_,
                                     VD_, T_, VD_, H_);
}

// Round 10
// 246.520 us; speedup vs baseline: 5.4648x; 1.0176x over previous
//
#include <hip/hip_runtime.h>
#include <math.h>

typedef unsigned short u16;
using us4  = __attribute__((ext_vector_type(4))) unsigned short;
using us8  = __attribute__((ext_vector_type(8))) unsigned short;
using bf16x8 = __attribute__((ext_vector_type(8))) __bf16;
using f32x4v = __attribute__((ext_vector_type(4))) float;

// Problem constants
#define T_    1024
#define H_    2048
#define HK_   8
#define HV_   16
#define KD_   1024
#define VD_   2048
#define CD_   4096
#define QN_   6144   // 2*KD + 2*VD
#define NC_   16     // number of chunks
#define C_    64     // chunk length

__device__ __forceinline__ u16 f2bf(float f) {
  unsigned u = __float_as_uint(f);
  u += 0x7fffu + ((u >> 16) & 1u);   // RNE
  return (u16)(u >> 16);
}
__device__ __forceinline__ float bf2f(u16 h) {
  return __uint_as_float(((unsigned)h) << 16);
}
// staging layout for gemm: within each 64-elem k-group, 8-elem chunk c of
// row r is stored at chunk position c ^ (r&7).
__device__ __forceinline__ int permk3(int r, int k) {
  return (k & ~63) | ((((k >> 3) & 7) ^ (r & 7)) << 3) | (k & 7);
}

// ---------------------------------------------------------------------------
// x f32 -> bf16 with chunk permutation (row length 2048)
// ---------------------------------------------------------------------------
__global__ void cast_bf16(const float* __restrict__ in, u16* __restrict__ out,
                          int n8) {
  int i = blockIdx.x * 256 + threadIdx.x;   // 16B-chunk index
  if (i >= n8) return;
  float4 a = ((const float4*)in)[i * 2];
  float4 b = ((const float4*)in)[i * 2 + 1];
  us8 r = {f2bf(a.x), f2bf(a.y), f2bf(a.z), f2bf(a.w),
           f2bf(b.x), f2bf(b.y), f2bf(b.z), f2bf(b.w)};
  const int row = i >> 8;                   // 2048/8 = 256 chunks per row
  const int ip = (i & ~7) | ((i & 7) ^ (row & 7));
  *(us8*)&out[(size_t)ip * 8] = r;
}

// ---------------------------------------------------------------------------
// f32 [R][C] -> bf16 [C][R] transpose + cast + chunk permutation
// ---------------------------------------------------------------------------
__global__ __launch_bounds__(256) void transpose_bf16(
    const float* __restrict__ in, u16* __restrict__ out, int R, int C) {
  __shared__ float tile[64][65];
  const int r0 = blockIdx.x * 64, c0 = blockIdx.y * 64;
  const int t = threadIdx.x;
  const int tr = t >> 4, tc4 = (t & 15) * 4;
#pragma unroll
  for (int i = 0; i < 4; ++i) {
    float4 v = *(const float4*)&in[(size_t)(r0 + tr + i * 16) * C + c0 + tc4];
    tile[tr + i * 16][tc4 + 0] = v.x;
    tile[tr + i * 16][tc4 + 1] = v.y;
    tile[tr + i * 16][tc4 + 2] = v.z;
    tile[tr + i * 16][tc4 + 3] = v.w;
  }
  __syncthreads();
#pragma unroll
  for (int i = 0; i < 4; ++i) {
    int oc = tr + i * 16;
    int row = c0 + oc;
    int k = r0 + tc4;
    us4 w = {f2bf(tile[tc4 + 0][oc]), f2bf(tile[tc4 + 1][oc]),
             f2bf(tile[tc4 + 2][oc]), f2bf(tile[tc4 + 3][oc])};
    *(us4*)&out[(size_t)row * R + permk3(row, k)] = w;
  }
}

// ---------------------------------------------------------------------------
// bf16 MFMA GEMM: C = A[M,K] @ Bt[N,K]^T, f32 out. 128x64 tile, BK=64,
// 2-phase double-buffered LDS pipeline, XCD-grouped 1D block mapping,
// 3-bit permuted staging. Output routed to Cq (cols < zsplit) or Cz.
// ---------------------------------------------------------------------------
__device__ __forceinline__ void gload_lds16(const void* g, void* l) {
  __builtin_amdgcn_global_load_lds(
      (const __attribute__((address_space(1))) void*)g,
      (__attribute__((address_space(3))) void*)l, 16, 0, 0);
}

__global__ __launch_bounds__(256) void gemm_bf16(
    const u16* __restrict__ A, const u16* __restrict__ Bt,
    float* __restrict__ Cq, int ldq, float* __restrict__ Cz, int ldz,
    int zsplit, int M, int N, int K) {
  __shared__ __align__(16) u16 As[2][8192];   // [128][64]
  __shared__ __align__(16) u16 Bs[2][4096];   // [64][64]
  const int tid  = threadIdx.x;
  const int wave = tid >> 6, lane = tid & 63;
  const int gy = N >> 6;
  const int ncolpx = gy >> 3;
  const int bid = blockIdx.x;
  const int xcd = bid & 7, idx = bid >> 3;
  const int row0 = (idx / ncolpx) * 128;
  const int col0 = (xcd * ncolpx + idx % ncolpx) * 64;
  const int wr = wave >> 1, wc = wave & 1;
  const int fr = lane & 15, fq = lane >> 4;

  const int sr8 = lane >> 3;
  const int sc8 = (lane & 7) * 8;
  const u16* gA = A  + (size_t)(row0 + wave * 32 + sr8) * K + sc8;
  const u16* gB = Bt + (size_t)(col0 + wave * 16 + sr8) * K + sc8;

  f32x4v acc[4][2] = {};
  const int nt = K >> 6;

  auto stage = [&](int p, int k0) {
#pragma unroll
    for (int j = 0; j < 4; ++j)
      gload_lds16(gA + (size_t)(j * 8) * K + k0,
                  &As[p][(wave * 32 + j * 8) * 64]);
#pragma unroll
    for (int j = 0; j < 2; ++j)
      gload_lds16(gB + (size_t)(j * 8) * K + k0,
                  &Bs[p][(wave * 16 + j * 8) * 64]);
  };

  stage(0, 0);
  asm volatile("s_waitcnt vmcnt(0)" ::: "memory");
  __syncthreads();

  int p = 0;
  for (int it = 0; it < nt; ++it) {
    if (it + 1 < nt) stage(p ^ 1, (it + 1) * 64);
#pragma unroll
    for (int kt = 0; kt < 2; ++kt) {
      bf16x8 af[4], bff[2];
#pragma unroll
      for (int mi = 0; mi < 4; ++mi) {
        const int r = wr * 64 + mi * 16 + fr;
        af[mi] = *(const bf16x8*)
            &As[p][r * 64 + kt * 32 + (((kt * 4 + fq) ^ (r & 7)) & 3) * 8
                   + ((((kt * 4 + fq) ^ (r & 7)) >> 2) - kt) * 32];
      }
#pragma unroll
      for (int ni = 0; ni < 2; ++ni) {
        const int r = wc * 32 + ni * 16 + fr;
        bff[ni] = *(const bf16x8*)
            &Bs[p][r * 64 + kt * 32 + (((kt * 4 + fq) ^ (r & 7)) & 3) * 8
                   + ((((kt * 4 + fq) ^ (r & 7)) >> 2) - kt) * 32];
      }
#pragma unroll
      for (int mi = 0; mi < 4; ++mi)
#pragma unroll
        for (int ni = 0; ni < 2; ++ni)
          acc[mi][ni] = __builtin_amdgcn_mfma_f32_16x16x32_bf16(
              af[mi], bff[ni], acc[mi][ni], 0, 0, 0);
    }
    if (it + 1 < nt) {
      asm volatile("s_waitcnt vmcnt(0)" ::: "memory");
      __syncthreads();
    }
    p ^= 1;
  }

  float* Cp; int ldc, cb;
  if (col0 < zsplit) { Cp = Cq; ldc = ldq; cb = col0; }
  else               { Cp = Cz; ldc = ldz; cb = col0 - zsplit; }
#pragma unroll
  for (int mi = 0; mi < 4; ++mi)
#pragma unroll
    for (int ni = 0; ni < 2; ++ni) {
      const int r  = row0 + wr * 64 + mi * 16 + fq * 4;
      const int cc = cb + wc * 32 + ni * 16 + fr;
#pragma unroll
      for (int j = 0; j < 4; ++j)
        Cp[(size_t)(r + j) * ldc + cc] = acc[mi][ni][j];
    }
}

// ---------------------------------------------------------------------------
// ba = x @ w_ba -> beta = sigmoid(b), g = -exp(a_log)*softplus(a+dt_bias)
// ---------------------------------------------------------------------------
__global__ __launch_bounds__(256) void ba_gbeta(
    const float* __restrict__ x, const float* __restrict__ w_ba,
    const float* __restrict__ a_log, const float* __restrict__ dt_bias,
    float* __restrict__ g, float* __restrict__ beta) {
  const int t = blockIdx.x;
  const int tid = threadIdx.x;
  __shared__ float xs[2048];
  __shared__ float red[8][32];
  {
    float4 v = *(const float4*)&x[(size_t)t * H_ + tid * 4];
    *(float4*)&xs[tid * 4] = v;
    float4 w = *(const float4*)&x[(size_t)t * H_ + 1024 + tid * 4];
    *(float4*)&xs[1024 + tid * 4] = w;
  }
  __syncthreads();
  const int c = tid & 31;
  const int chunk = tid >> 5;
  float p = 0.f;
  const int kb = chunk * 256;
#pragma unroll 4
  for (int k = kb; k < kb + 256; ++k) p = fmaf(xs[k], w_ba[k * 32 + c], p);
  red[chunk][c] = p;
  __syncthreads();
  if (tid < 32) {
    float s = 0.f;
#pragma unroll
    for (int i = 0; i < 8; ++i) s += red[i][c];
    if (c < 16) {
      beta[t * 16 + c] = 1.f / (1.f + expf(-s));
    } else {
      int h = c - 16;
      float xx = s + dt_bias[h];
      float sp = xx > 20.f ? xx : log1pf(expf(xx));
      g[t * 16 + h] = -expf(a_log[h]) * sp;
    }
  }
}

// ---------------------------------------------------------------------------
// fused causal depthwise conv1d (K=4) + SiLU + k-l2norm.
// ---------------------------------------------------------------------------
__global__ __launch_bounds__(512) void conv_silu_k(
    const float* __restrict__ qkvraw, const float* __restrict__ conv_w,
    const float* __restrict__ conv_b, float* __restrict__ qkvc,
    float* __restrict__ khat) {
  const int t = blockIdx.x;
  const int tid = threadIdx.x;
  const int c0 = tid * 8;
  float acc[8];
  float4 cb0 = *(const float4*)&conv_b[c0];
  float4 cb1 = *(const float4*)&conv_b[c0 + 4];
  acc[0] = cb0.x; acc[1] = cb0.y; acc[2] = cb0.z; acc[3] = cb0.w;
  acc[4] = cb1.x; acc[5] = cb1.y; acc[6] = cb1.z; acc[7] = cb1.w;
  float wv[8][4];
#pragma unroll
  for (int i = 0; i < 8; i += 2) {
    float4 w0 = *(const float4*)&conv_w[(c0 + i) * 4];
    float4 w1 = *(const float4*)&conv_w[(c0 + i + 1) * 4];
    wv[i][0] = w0.x; wv[i][1] = w0.y; wv[i][2] = w0.z; wv[i][3] = w0.w;
    wv[i+1][0] = w1.x; wv[i+1][1] = w1.y; wv[i+1][2] = w1.z; wv[i+1][3] = w1.w;
  }
#pragma unroll
  for (int j = 0; j < 4; ++j) {
    int tt = t - 3 + j;
    if (tt >= 0) {
      float4 a = *(const float4*)&qkvraw[(size_t)tt * CD_ + c0];
      float4 b = *(const float4*)&qkvraw[(size_t)tt * CD_ + c0 + 4];
      float xv[8] = {a.x, a.y, a.z, a.w, b.x, b.y, b.z, b.w};
#pragma unroll
      for (int i = 0; i < 8; ++i) acc[i] = fmaf(xv[i], wv[i][j], acc[i]);
    }
  }
  float y[8];
#pragma unroll
  for (int i = 0; i < 8; ++i) y[i] = acc[i] / (1.f + expf(-acc[i]));

  if (tid < 128 || tid >= 256) {
    float4 o0 = {y[0], y[1], y[2], y[3]};
    float4 o1 = {y[4], y[5], y[6], y[7]};
    *(float4*)&qkvc[(size_t)t * CD_ + c0]     = o0;
    *(float4*)&qkvc[(size_t)t * CD_ + c0 + 4] = o1;
  } else {
    float ss = 0.f;
#pragma unroll
    for (int i = 0; i < 8; ++i) ss = fmaf(y[i], y[i], ss);
#pragma unroll
    for (int off = 1; off < 16; off <<= 1) ss += __shfl_xor(ss, off);
    float rs = rsqrtf(ss + 1e-6f);
    const int head = (c0 - 1024) >> 7;
    const int d0 = (c0 - 1024) & 127;
    float4 o0 = {y[0] * rs, y[1] * rs, y[2] * rs, y[3] * rs};
    float4 o1 = {y[4] * rs, y[5] * rs, y[6] * rs, y[7] * rs};
    float* kout = &khat[((size_t)t * HK_ + head) * 128 + d0];
    *(float4*)&kout[0] = o0;
    *(float4*)&kout[4] = o1;
  }
}

// ---------------------------------------------------------------------------
// Chunked gated delta rule, phase A (parallel over 16 chunks x 16 heads).
// 512 threads (8 waves). Dot phase 4x2 tiles/thread; during the serial
// forward substitution (waves 0-3), waves 4-7 write Mqg and pQg.
// ---------------------------------------------------------------------------
#define SWZ(r) (((r) >> 2) & 7)

__device__ __forceinline__ float4 ldsw4(const float* base, int r, int dblk) {
  return *(const float4*)&base[r * 128 + ((dblk ^ SWZ(r)) << 2)];
}
__device__ __forceinline__ float ldsw1(const float* base, int r, int d) {
  return base[r * 128 + ((((d) >> 2) ^ SWZ(r)) << 2) + ((d) & 3)];
}

__global__ __launch_bounds__(512) void chunk_prep(
    const float* __restrict__ qkvc, const float* __restrict__ khat,
    const float* __restrict__ g, const float* __restrict__ beta,
    float* __restrict__ cgbuf, float* __restrict__ Wtg, float* __restrict__ Ug,
    float* __restrict__ Mqg, float* __restrict__ pQg) {
  const int c = blockIdx.x, hv = blockIdx.y, hk = hv >> 1;
  const int cid = c * 16 + hv;
  const int tid = threadIdx.x;
  __shared__ float Kl[8192], Ql[8192];   // swizzled [64][128]
  __shared__ float AM[8320];             // At[64][65] | Mq[64][65]; later Utr
  __shared__ float cgl[64], bl[64], bp[64], rsl[64];
  float* At = AM;
  float* Mq = AM + 4160;

#pragma unroll
  for (int it = 0; it < 4; ++it) {
    int flat = it * 2048 + tid * 4;
    int row = flat >> 7, d = flat & 127;
    int pb = ((d >> 2) ^ SWZ(row)) << 2;
    int gt = c * 64 + row;
    float4 kv = *(const float4*)&khat[((size_t)gt * HK_ + hk) * 128 + d];
    float4 qv = *(const float4*)&qkvc[(size_t)gt * CD_ + hk * 128 + d];
    *(float4*)&Kl[row * 128 + pb] = kv;
    *(float4*)&Ql[row * 128 + pb] = qv;
  }
  if (tid < 64) {
    float s = g[(size_t)(c * 64 + tid) * HV_ + hv];
#pragma unroll
    for (int off = 1; off < 64; off <<= 1) {
      float t = __shfl_up(s, off);
      if (tid >= off) s += t;
    }
    cgl[tid] = s;
    cgbuf[cid * 64 + tid] = s;
    bl[tid] = beta[(size_t)(c * 64 + tid) * HV_ + hv];
  }
  __syncthreads();
  if (tid < 64) {
    float sq = 0.f;
#pragma unroll
    for (int dblk = 0; dblk < 32; ++dblk) {
      float4 q4 = ldsw4(Ql, tid, dblk);
      sq = fmaf(q4.x, q4.x, sq); sq = fmaf(q4.y, q4.y, sq);
      sq = fmaf(q4.z, q4.z, sq); sq = fmaf(q4.w, q4.w, sq);
    }
    rsl[tid] = rsqrtf(sq + 1e-6f) * 0.08838834764831845f;
    bp[tid] = bl[tid] * expf(cgl[tid]);
  }
  __syncthreads();

  // dot phase: 4x2 tile of (i,j) pairs per thread (512 threads)
  const int i0 = (tid >> 5) * 4, j0 = (tid & 31) * 2;
  float kk[4][2], qk[4][2];
#pragma unroll
  for (int a = 0; a < 4; ++a)
#pragma unroll
    for (int b = 0; b < 2; ++b) { kk[a][b] = 0.f; qk[a][b] = 0.f; }
  for (int dblk = 0; dblk < 32; ++dblk) {
    float4 ka[4], qa[4], kb[2];
#pragma unroll
    for (int a = 0; a < 4; ++a) {
      ka[a] = ldsw4(Kl, i0 + a, dblk);
      qa[a] = ldsw4(Ql, i0 + a, dblk);
    }
#pragma unroll
    for (int b = 0; b < 2; ++b) kb[b] = ldsw4(Kl, j0 + b, dblk);
#pragma unroll
    for (int a = 0; a < 4; ++a)
#pragma unroll
      for (int b = 0; b < 2; ++b) {
        kk[a][b] = fmaf(ka[a].x, kb[b].x, kk[a][b]);
        kk[a][b] = fmaf(ka[a].y, kb[b].y, kk[a][b]);
        kk[a][b] = fmaf(ka[a].z, kb[b].z, kk[a][b]);
        kk[a][b] = fmaf(ka[a].w, kb[b].w, kk[a][b]);
        qk[a][b] = fmaf(qa[a].x, kb[b].x, qk[a][b]);
        qk[a][b] = fmaf(qa[a].y, kb[b].y, qk[a][b]);
        qk[a][b] = fmaf(qa[a].z, kb[b].z, qk[a][b]);
        qk[a][b] = fmaf(qa[a].w, kb[b].w, qk[a][b]);
      }
  }
#pragma unroll
  for (int a = 0; a < 4; ++a)
#pragma unroll
    for (int b = 0; b < 2; ++b) {
      int i = i0 + a, j = j0 + b;
      float e = expf(cgl[i] - cgl[j]);
      At[j * 65 + i] = (j < i) ? (-bl[i] * e * kk[a][b]) : 0.f;
      Mq[j * 65 + i] = (j <= i) ? (rsl[i] * e * qk[a][b]) : 0.f;
    }
  __syncthreads();

  float X[64];
  if (tid < 256) {
    // ---- waves 0-3: X init + forward substitution ----
    if (tid < 128) {
#pragma unroll
      for (int j = 0; j < 64; ++j) X[j] = bp[j] * ldsw1(Kl, j, tid);
    } else {
      const int m = tid - 128;
#pragma unroll
      for (int j = 0; j < 64; ++j)
        X[j] = bl[j] * qkvc[(size_t)(c * 64 + j) * CD_ + 2 * KD_ + hv * 128 + m];
    }
#pragma unroll
    for (int j = 0; j < 63; ++j) {
      float xj = X[j];
#pragma unroll
      for (int i = j + 1; i < 64; ++i) X[i] = fmaf(At[j * 65 + i], xj, X[i]);
    }
    if (tid < 128) {
      size_t baseo = ((size_t)cid * 128 + tid) * 64;
#pragma unroll
      for (int j4 = 0; j4 < 16; ++j4) {
        float4 v = {X[j4 * 4], X[j4 * 4 + 1], X[j4 * 4 + 2], X[j4 * 4 + 3]};
        *(float4*)&Wtg[baseo + j4 * 4] = v;
      }
    }
  } else {
    // ---- waves 4-7: Mqg + pQg writes (independent of solve) ----
    const int t2 = tid - 256;
#pragma unroll
    for (int it = 0; it < 16; ++it) {
      int f = it * 256 + t2;
      int j = f >> 6, i = f & 63;
      Mqg[(size_t)cid * 4096 + f] = Mq[j * 65 + i];
    }
    const int i = t2 & 63;
    const float ei = expf(cgl[i]) * rsl[i];
#pragma unroll
    for (int it = 0; it < 32; ++it) {
      int d = it * 4 + (t2 >> 6);
      pQg[(size_t)cid * 8192 + d * 64 + i] = ei * ldsw1(Ql, i, d);
    }
  }
  __syncthreads();   // At/Mq dead; X (U cols) ready

  if (tid >= 128 && tid < 256) {
    const int m = tid - 128;
    float* Utr = AM;
#pragma unroll
    for (int j = 0; j < 64; ++j) Utr[j * 128 + m] = X[j];
  }
  __syncthreads();
  {
    const float* Utr = AM;
#pragma unroll
    for (int it = 0; it < 4; ++it) {
      int flat = it * 2048 + tid * 4;
      *(float4*)&Ug[(size_t)cid * 8192 + flat] = *(const float4*)&Utr[flat];
    }
  }
}

// ---------------------------------------------------------------------------
// make_MBG (parallel, 256 blocks, 512 threads)
// ---------------------------------------------------------------------------
__global__ __launch_bounds__(512) void make_MBG(
    const float* __restrict__ Wtg, const float* __restrict__ pQg,
    const float* __restrict__ Ug, const float* __restrict__ Mqg,
    const float* __restrict__ khat, const float* __restrict__ cgbuf,
    u16* __restrict__ Mhi, u16* __restrict__ Mlo,
    float* __restrict__ Bg, float* __restrict__ Gtg) {
  const int c = blockIdx.x, hv = blockIdx.y, hk = hv >> 1;
  const int cid = c * 16 + hv;
  const int tid = threadIdx.x;
  __shared__ float Wl[64 * 128];   // W[j][d]
  __shared__ float Kel[64 * 128];  // esc_j * khat_j[d]
  __shared__ float Ul[64 * 128];
  __shared__ float Mql[64 * 64];
  const float cg63 = cgbuf[cid * 64 + 63];
  const float pC = expf(cg63);
#pragma unroll
  for (int it = 0; it < 4; ++it) {
    int f = it * 2048 + tid * 4;       // f = d*64 + j
    int d = f >> 6, j = f & 63;
    float4 w = *(const float4*)&Wtg[(size_t)cid * 8192 + f];
    Wl[(j + 0) * 128 + d] = w.x;
    Wl[(j + 1) * 128 + d] = w.y;
    Wl[(j + 2) * 128 + d] = w.z;
    Wl[(j + 3) * 128 + d] = w.w;
  }
#pragma unroll
  for (int it = 0; it < 4; ++it) {
    int f = it * 2048 + tid * 4;       // f = j*128 + d
    int j = f >> 7, d = f & 127;
    float esc = expf(cg63 - cgbuf[cid * 64 + j]);
    float4 kv = *(const float4*)&khat[((size_t)(c * 64 + j) * HK_ + hk) * 128 + d];
    float4 uv = *(const float4*)&Ug[(size_t)cid * 8192 + f];
    kv.x *= esc; kv.y *= esc; kv.z *= esc; kv.w *= esc;
    *(float4*)&Kel[f] = kv;
    *(float4*)&Ul[f] = uv;
  }
#pragma unroll
  for (int it = 0; it < 2; ++it) {
    int f = it * 2048 + tid * 4;
    *(float4*)&Mql[f] = *(const float4*)&Mqg[(size_t)cid * 4096 + f];
  }
  __syncthreads();

  // fused M+B: tile rows d0..d0+7, cols n0..n0+3
  const int d0 = (tid & 15) * 8, n0 = (tid >> 4) * 4;
  float ma[8][4] = {}, ba[8][4] = {};
  for (int j = 0; j < 64; ++j) {
    float4 k0 = *(const float4*)&Kel[j * 128 + d0];
    float4 k1 = *(const float4*)&Kel[j * 128 + d0 + 4];
    float4 w0 = *(const float4*)&Wl[j * 128 + n0];
    float4 u0 = *(const float4*)&Ul[j * 128 + n0];
    float ke[8] = {k0.x, k0.y, k0.z, k0.w, k1.x, k1.y, k1.z, k1.w};
    float wv[4] = {w0.x, w0.y, w0.z, w0.w};
    float uv[4] = {u0.x, u0.y, u0.z, u0.w};
#pragma unroll
    for (int a = 0; a < 8; ++a)
#pragma unroll
      for (int b = 0; b < 4; ++b) {
        ma[a][b] = fmaf(ke[a], wv[b], ma[a][b]);
        ba[a][b] = fmaf(ke[a], uv[b], ba[a][b]);
      }
  }
#pragma unroll
  for (int a = 0; a < 8; ++a) {
    const int d = d0 + a;
    us4 hi, lo;
#pragma unroll
    for (int b = 0; b < 4; ++b) {
      float m = ((d == n0 + b) ? pC : 0.f) - ma[a][b];
      u16 h = f2bf(m);
      hi[b] = h;
      lo[b] = f2bf(m - bf2f(h));
    }
    *(us4*)&Mhi[(size_t)cid * 16384 + d * 128 + n0] = hi;
    *(us4*)&Mlo[(size_t)cid * 16384 + d * 128 + n0] = lo;
    float4 b0 = {ba[a][0], ba[a][1], ba[a][2], ba[a][3]};
    *(float4*)&Bg[(size_t)cid * 16384 + d * 128 + n0] = b0;
  }

  // G phase: Gt[d][i] tile 4d x 4i
  const int dg = (tid & 31) * 4, ig = (tid >> 5) * 4;
  float ga[4][4] = {};
  for (int j = 0; j < 64; ++j) {
    float4 w4 = *(const float4*)&Wl[j * 128 + dg];
    float4 m0 = *(const float4*)&Mql[j * 64 + ig];
    float wv[4] = {w4.x, w4.y, w4.z, w4.w};
    float mv[4] = {m0.x, m0.y, m0.z, m0.w};
#pragma unroll
    for (int a = 0; a < 4; ++a)
#pragma unroll
      for (int b = 0; b < 4; ++b) ga[a][b] = fmaf(wv[a], mv[b], ga[a][b]);
  }
#pragma unroll
  for (int a = 0; a < 4; ++a) {
    const int d = dg + a;
    float4 p0 = *(const float4*)&pQg[(size_t)cid * 8192 + d * 64 + ig];
    float4 g0 = {p0.x - ga[a][0], p0.y - ga[a][1], p0.z - ga[a][2], p0.w - ga[a][3]};
    *(float4*)&Gtg[(size_t)cid * 8192 + d * 64 + ig] = g0;
  }
}

// ---------------------------------------------------------------------------
// scan_S v4: 128 blocks = 16 heads x 8 col-slices of 16, XCD-grouped
// (flat%8 == hv%8 so all 8 slices of a head share one L2 copy of M).
// M AND B both register-prefetched one chunk ahead (named double buffers).
// ---------------------------------------------------------------------------
__global__ __launch_bounds__(512) void scan_S(
    const u16* __restrict__ Mhi, const u16* __restrict__ Mlo,
    const float* __restrict__ Bg, float* __restrict__ Sg) {
  const int flat = blockIdx.x;
  const int hv = (flat & 7) + 8 * (flat >> 6);
  const int vs = (flat >> 3) & 7;
  const int tid = threadIdx.x;
  const int wave = tid >> 6, lane = tid & 63;
  const int fr = lane & 15, fq = lane >> 4;
  const int wr = wave * 16;       // this wave's 16 output rows
  const int m0 = vs * 16;         // col-slice base

  __shared__ u16 Sh[2][2048];     // [16 m][128 k] bf16-hi, XOR-swizzled
  __shared__ u16 Sl[2][2048];

  for (int i = tid; i < 2048; i += 512) { Sh[0][i] = 0; Sl[0][i] = 0; }
  {
    float* s0 = Sg + (size_t)hv * 16384 + m0;
#pragma unroll
    for (int it = 0; it < 4; ++it) {
      int idx = it * 512 + tid;          // 2048 = 128 d x 16 m
      s0[(size_t)(idx >> 4) * 128 + (idx & 15)] = 0.f;
    }
  }
  __syncthreads();

  bf16x8 MhA[4], MlA[4], MhB[4], MlB[4];
  float bvA[4], bvB[4];
  {
    const u16* Mh0 = Mhi + (size_t)hv * 16384;
    const u16* Ml0 = Mlo + (size_t)hv * 16384;
#pragma unroll
    for (int kt = 0; kt < 4; ++kt) {
      size_t off = (size_t)(wr + fr) * 128 + kt * 32 + fq * 8;
      MhA[kt] = *(const bf16x8*)&Mh0[off];
      MlA[kt] = *(const bf16x8*)&Ml0[off];
    }
    const float* Bc = Bg + (size_t)hv * 16384 + m0;
#pragma unroll
    for (int j = 0; j < 4; ++j)
      bvA[j] = Bc[(size_t)(wr + fq * 4 + j) * 128 + fr];
  }
  int p = 0;

  auto step = [&](int c, bf16x8 (&MhC)[4], bf16x8 (&MlC)[4], float (&bvC)[4],
                  bf16x8 (&MhN)[4], bf16x8 (&MlN)[4], float (&bvN)[4]) {
    // prefetch next chunk's M frags + B values (consumed next step)
    if (c + 1 < NC_ - 1) {
      const u16* MhP = Mhi + (size_t)((c + 1) * 16 + hv) * 16384;
      const u16* MlP = Mlo + (size_t)((c + 1) * 16 + hv) * 16384;
#pragma unroll
      for (int kt = 0; kt < 4; ++kt) {
        size_t off = (size_t)(wr + fr) * 128 + kt * 32 + fq * 8;
        MhN[kt] = *(const bf16x8*)&MhP[off];
        MlN[kt] = *(const bf16x8*)&MlP[off];
      }
      const float* BcN = Bg + (size_t)((c + 1) * 16 + hv) * 16384 + m0;
#pragma unroll
      for (int j = 0; j < 4; ++j)
        bvN[j] = BcN[(size_t)(wr + fq * 4 + j) * 128 + fr];
    }

    // acc = M_c @ S_c  (bf16 hi/lo x3), 16-col slice: single B fragment
    f32x4v acc = {};
#pragma unroll
    for (int kt = 0; kt < 4; ++kt) {
      const int m = fr;
      const int byte = m * 256 + ((kt * 64 + fq * 16) ^ ((m & 7) << 4));
      bf16x8 BhF = *(const bf16x8*)((const char*)&Sh[p][0] + byte);
      bf16x8 BlF = *(const bf16x8*)((const char*)&Sl[p][0] + byte);
      acc = __builtin_amdgcn_mfma_f32_16x16x32_bf16(MlC[kt], BhF, acc, 0, 0, 0);
      acc = __builtin_amdgcn_mfma_f32_16x16x32_bf16(MhC[kt], BlF, acc, 0, 0, 0);
      acc = __builtin_amdgcn_mfma_f32_16x16x32_bf16(MhC[kt], BhF, acc, 0, 0, 0);
    }

    // S_{c+1} = acc + B (B from registers, prefetched last step)
    float* Sn = Sg + (size_t)((c + 1) * 16 + hv) * 16384 + m0;
    const int k0 = wr + fq * 4;
    const int m = fr;
    us4 h4, l4;
#pragma unroll
    for (int j = 0; j < 4; ++j) {
      float v = acc[j] + bvC[j];
      Sn[(size_t)(k0 + j) * 128 + m] = v;
      u16 h = f2bf(v);
      h4[j] = h;
      l4[j] = f2bf(v - bf2f(h));
    }
    const int wbyte = m * 256 + ((k0 * 2) ^ ((m & 7) << 4));
    *(us4*)((char*)&Sh[p ^ 1][0] + wbyte) = h4;
    *(us4*)((char*)&Sl[p ^ 1][0] + wbyte) = l4;
    __syncthreads();
    p ^= 1;
  };

  for (int cc = 0; cc < NC_ - 1; cc += 2) {
    step(cc, MhA, MlA, bvA, MhB, MlB, bvB);
    if (cc + 1 < NC_ - 1) step(cc + 1, MhB, MlB, bvB, MhA, MlA, bvA);
  }
}

// ---------------------------------------------------------------------------
// chunk_out (parallel, 256 blocks): o = Mq^T U + G*S
// ---------------------------------------------------------------------------
__global__ __launch_bounds__(256) void chunk_out(
    const float* __restrict__ Mqg, const float* __restrict__ Ug,
    const float* __restrict__ Gtg, const float* __restrict__ Sg,
    float* __restrict__ o) {
  const int c = blockIdx.x, hv = blockIdx.y;
  const int cid = c * 16 + hv;
  const int tid = threadIdx.x;
  __shared__ float Mql[64 * 64];
  __shared__ float Ul[64 * 128];
  __shared__ float Gtl[128 * 64];
  __shared__ float Sl[128 * 128];
#pragma unroll
  for (int it = 0; it < 4; ++it) {
    int f = it * 1024 + tid * 4;
    *(float4*)&Mql[f] = *(const float4*)&Mqg[(size_t)cid * 4096 + f];
  }
#pragma unroll
  for (int it = 0; it < 8; ++it) {
    int f = it * 1024 + tid * 4;
    *(float4*)&Ul[f]  = *(const float4*)&Ug[(size_t)cid * 8192 + f];
    *(float4*)&Gtl[f] = *(const float4*)&Gtg[(size_t)cid * 8192 + f];
  }
#pragma unroll
  for (int it = 0; it < 16; ++it) {
    int f = it * 1024 + tid * 4;
    *(float4*)&Sl[f] = *(const float4*)&Sg[(size_t)cid * 16384 + f];
  }
  __syncthreads();

  const int i0 = (tid & 15) * 4, m0 = (tid >> 4) * 8;
  float oa[4][8] = {};
  for (int j = 0; j < 64; ++j) {
    float4 mq = *(const float4*)&Mql[j * 64 + i0];
    float4 u0 = *(const float4*)&Ul[j * 128 + m0];
    float4 u1 = *(const float4*)&Ul[j * 128 + m0 + 4];
    float mv[4] = {mq.x, mq.y, mq.z, mq.w};
    float uv[8] = {u0.x, u0.y, u0.z, u0.w, u1.x, u1.y, u1.z, u1.w};
#pragma unroll
    for (int a = 0; a < 4; ++a)
#pragma unroll
      for (int b = 0; b < 8; ++b) oa[a][b] = fmaf(mv[a], uv[b], oa[a][b]);
  }
  for (int d = 0; d < 128; ++d) {
    float4 gt = *(const float4*)&Gtl[d * 64 + i0];
    float4 s0 = *(const float4*)&Sl[d * 128 + m0];
    float4 s1 = *(const float4*)&Sl[d * 128 + m0 + 4];
    float gv[4] = {gt.x, gt.y, gt.z, gt.w};
    float sv[8] = {s0.x, s0.y, s0.z, s0.w, s1.x, s1.y, s1.z, s1.w};
#pragma unroll
    for (int a = 0; a < 4; ++a)
#pragma unroll
      for (int b = 0; b < 8; ++b) oa[a][b] = fmaf(gv[a], sv[b], oa[a][b]);
  }
#pragma unroll
  for (int a = 0; a < 4; ++a) {
    const int t = c * 64 + i0 + a;
    float4 o0 = {oa[a][0], oa[a][1], oa[a][2], oa[a][3]};
    float4 o1 = {oa[a][4], oa[a][5], oa[a][6], oa[a][7]};
    *(float4*)&o[((size_t)t * HV_ + hv) * 128 + m0]     = o0;
    *(float4*)&o[((size_t)t * HV_ + hv) * 128 + m0 + 4] = o1;
  }
}

// ---------------------------------------------------------------------------
// h = o * silu(z); rmsnorm; -> bf16 (permuted staging layout for gemm2)
// ---------------------------------------------------------------------------
__global__ void gated_rmsnorm(const float* __restrict__ o,
                              const float* __restrict__ zbuf,
                              const float* __restrict__ norm_w,
                              u16* __restrict__ h) {
  const int t = blockIdx.x, hv = blockIdx.y, d = threadIdx.x;
  float ov = o[((size_t)t * HV_ + hv) * 128 + d];
  float zv = zbuf[(size_t)t * VD_ + hv * 128 + d];
  float hc = ov * (zv / (1.f + expf(-zv)));
  float ss = hc * hc;
#pragma unroll
  for (int off = 32; off >= 1; off >>= 1) ss += __shfl_xor(ss, off);
  __shared__ float s2[2];
  if ((d & 63) == 0) s2[d >> 6] = ss;
  __syncthreads();
  float tot = s2[0] + s2[1];
  float r = rsqrtf(tot * (1.f / 128.f) + 1e-6f);
  const int k = hv * 128 + d;
  h[(size_t)t * VD_ + permk3(t, k)] = f2bf(hc * r * norm_w[d]);
}

// ---------------------------------------------------------------------------
extern "C" void kernel_launch(void* const* d_in, const int* in_sizes, int n_in,
                              void* d_out, int out_size, void* d_ws, size_t ws_size,
                              hipStream_t stream) {
  const float* x       = (const float*)d_in[0];
  const float* w_qkvz  = (const float*)d_in[1];
  const float* w_ba    = (const float*)d_in[2];
  const float* conv_w  = (const float*)d_in[3];
  const float* conv_b  = (const float*)d_in[4];
  const float* a_log   = (const float*)d_in[5];
  const float* dt_bias = (const float*)d_in[6];
  const float* norm_w  = (const float*)d_in[7];
  const float* w_o     = (const float*)d_in[8];
  float* out = (float*)d_out;

  float* ws = (float*)d_ws;
  float* qkvraw = ws;                  // 4,194,304  (-> Bg)
  float* zbuf   = ws + 4194304;        // 2,097,152
  float* qkvc   = ws + 6291456;        // 4,194,304  (-> Mhi|Mlo, -> wot)
  float* khat   = ws + 10485760;       // 1,048,576  (-> hb)
  float* gbuf   = ws + 11534336;       // 16,384
  float* bbuf   = ws + 11550720;       // 16,384
  float* cgbuf  = ws + 11567104;       // 16,384
  float* obuf   = ws + 11583488;       // 2,097,152  (xb early)
  float* Wtg    = ws + 13680640;       // 2,097,152 ┐ -> Sg (4,194,304)
  float* pQg    = ws + 15777792;       // 2,097,152 ┘
  float* Ug     = ws + 17874944;       // 2,097,152
  float* Mqg    = ws + 19972096;       // 1,048,576
  float* Gtg    = ws + 21020672;       // 2,097,152

  u16* xb   = (u16*)obuf;      // x bf16 (dead after gemm1)
  u16* wqt  = (u16*)Wtg;       // w_qkvz^T bf16 (dead after gemm1)
  u16* Mhi  = (u16*)qkvc;
  u16* Mlo  = (u16*)(qkvc + 2097152);
  float* Bg = qkvraw;
  float* Sg = Wtg;
  u16* wot  = (u16*)qkvc;      // after scan_S (Mhi dead)
  u16* hb   = (u16*)khat;      // after make_MBG (khat dead)

  // 0) casts (permuted staging layout)
  cast_bf16<<<1024, 256, 0, stream>>>(x, xb, 262144);
  transpose_bf16<<<dim3(32, 96), 256, 0, stream>>>(w_qkvz, wqt, H_, QN_);
  // 1) qkv|z = x @ w_qkvz
  gemm_bf16<<<768, 256, 0, stream>>>(xb, wqt, qkvraw, CD_, zbuf, VD_,
                                     CD_, T_, QN_, H_);
  // 2) beta / g
  ba_gbeta<<<T_, 256, 0, stream>>>(x, w_ba, a_log, dt_bias, gbuf, bbuf);
  // 3) fused conv + silu + k-l2norm
  conv_silu_k<<<T_, 512, 0, stream>>>(qkvraw, conv_w, conv_b, qkvc, khat);
  // 4) chunk-local precompute (parallel, 512 thr)
  chunk_prep<<<dim3(NC_, HV_), 512, 0, stream>>>(
      qkvc, khat, gbuf, bbuf, cgbuf, Wtg, Ug, Mqg, pQg);
  // 5) per-chunk transition/output operators (parallel, 512 thr)
  make_MBG<<<dim3(NC_, HV_), 512, 0, stream>>>(
      Wtg, pQg, Ug, Mqg, khat, cgbuf, Mhi, Mlo, Bg, Gtg);
  // 6) sequential state scan (128 blocks, M+B reg-prefetched)
  scan_S<<<128, 512, 0, stream>>>(Mhi, Mlo, Bg, Sg);
  // 7) w_o^T cast (Mhi region now dead)
  transpose_bf16<<<dim3(32, 32), 256, 0, stream>>>(w_o, wot, VD_, H_);
  // 8) per-chunk outputs (parallel)
  chunk_out<<<dim3(NC_, HV_), 256, 0, stream>>>(Mqg, Ug, Gtg, Sg, obuf);
  // 9) gated rmsnorm -> bf16 h (permuted)
  gated_rmsnorm<<<dim3(T_, HV_), 128, 0, stream>>>(obuf, zbuf, norm_w, hb);
  // 10) out = h @ w_o
  gemm_bf16<<<256, 256, 0, stream>>>(hb, wot, out, VD_, out, VD_,
                                     VD_, T_, VD_, H_);
}